// Round 2
// baseline (5318.808 us; speedup 1.0000x reference)
//
#include <hip/hip_runtime.h>
#include <stdint.h>

#define HD  128
#define DIN 64
#define DE  32
#define CAT 160   // HD + DE

typedef unsigned int u32; typedef unsigned short u16; typedef unsigned char u8;

__device__ __forceinline__ float lrelu(float x){ return x > 0.f ? x : 0.01f*x; }
__device__ __forceinline__ float sigmoidf_(float x){ return 1.f/(1.f + __expf(-x)); }
__device__ __forceinline__ float tanhf_(float x){
    float t = fminf(fmaxf(x, -15.f), 15.f);
    float e = __expf(2.f*t);
    return (e - 1.f)/(e + 1.f);
}
__device__ __forceinline__ float eluf_(float x){ return x > 0.f ? x : expm1f(x); }

__device__ __forceinline__ u16 f32_to_bf16(float x){
    u32 u = __float_as_uint(x);
    u += 0x7FFFu + ((u >> 16) & 1u);
    return (u16)(u >> 16);
}
__device__ __forceinline__ float bf16_to_f32(u16 h){ return __uint_as_float(((u32)h) << 16); }
__device__ __forceinline__ u32 pk2(float a, float b){
    return (u32)f32_to_bf16(a) | ((u32)f32_to_bf16(b) << 16);
}
// custom e4m3 with exponent bias 13: normal range [2^-12, 7.5]; all 256 codes ours.
__device__ __forceinline__ u8 f32_to_f8(float x){
    u32 u = __float_as_uint(x);
    u32 s = (u >> 24) & 0x80u;
    u &= 0x7FFFFFFFu;
    u += 0x0007FFFFu + ((u >> 20) & 1u);      // RNE to 3-bit mantissa
    int e = (int)(u >> 23) - 114;             // 127 - 13
    if (e <= 0)  return (u8)s;
    if (e > 15)  return (u8)(s | 0x7F);
    return (u8)(s | ((u32)e << 3) | ((u >> 20) & 7u));
}
__device__ __forceinline__ float f8_to_f32(u32 b){
    u32 e = (b >> 3) & 0xFu;
    u32 u = ((b & 0x80u) << 24) | ((e + 114u) << 23) | ((b & 7u) << 20);
    float f = __uint_as_float(u);
    return e ? f : 0.f;
}
__device__ __forceinline__ u32 f8x4(float a, float b, float c, float d){
    return (u32)f32_to_f8(a) | ((u32)f32_to_f8(b) << 8) |
           ((u32)f32_to_f8(c) << 16) | ((u32)f32_to_f8(d) << 24);
}

// m-row codec: store one 64-value half-row from acc[], load 2 channels per lane
template<typename MT> struct MC;
template<> struct MC<u16>{
    static __device__ __forceinline__ void store(u16* base, const float* acc){
        uint4* o = (uint4*)base;
        #pragma unroll
        for (int q = 0; q < 8; ++q){
            uint4 t;
            t.x = pk2(acc[8*q+0], acc[8*q+1]);
            t.y = pk2(acc[8*q+2], acc[8*q+3]);
            t.z = pk2(acc[8*q+4], acc[8*q+5]);
            t.w = pk2(acc[8*q+6], acc[8*q+7]);
            o[q] = t;
        }
    }
    static __device__ __forceinline__ float2 load2(const u16* row, int lane){
        u32 u = *(const u32*)(row + 2*lane);
        float2 r; r.x = bf16_to_f32((u16)(u & 0xFFFFu)); r.y = bf16_to_f32((u16)(u >> 16));
        return r;
    }
};
template<> struct MC<u8>{
    static __device__ __forceinline__ void store(u8* base, const float* acc){
        uint4* o = (uint4*)base;
        #pragma unroll
        for (int q = 0; q < 4; ++q){
            uint4 t;
            t.x = f8x4(acc[16*q+ 0], acc[16*q+ 1], acc[16*q+ 2], acc[16*q+ 3]);
            t.y = f8x4(acc[16*q+ 4], acc[16*q+ 5], acc[16*q+ 6], acc[16*q+ 7]);
            t.z = f8x4(acc[16*q+ 8], acc[16*q+ 9], acc[16*q+10], acc[16*q+11]);
            t.w = f8x4(acc[16*q+12], acc[16*q+13], acc[16*q+14], acc[16*q+15]);
            o[q] = t;
        }
    }
    static __device__ __forceinline__ float2 load2(const u8* row, int lane){
        u32 u = *(const u16*)(row + 2*lane);
        float2 r; r.x = f8_to_f32(u & 0xFFu); r.y = f8_to_f32((u >> 8) & 0xFFu);
        return r;
    }
};

__device__ __forceinline__ float wave_max(float v){
    #pragma unroll
    for (int o = 32; o > 0; o >>= 1) v = fmaxf(v, __shfl_xor(v, o, 64));
    return v;
}
__device__ __forceinline__ float wave_sum(float v){
    #pragma unroll
    for (int o = 32; o > 0; o >>= 1) v += __shfl_xor(v, o, 64);
    return v;
}

// ---------------- init ----------------
__global__ void k_zero2(int* __restrict__ a, int* __restrict__ b, int n){
    int i = blockIdx.x*256 + threadIdx.x;
    if (i < n){ a[i] = 0; b[i] = 0; }
}

// ---------------- K1: xe = bf16(leaky(x @ W^T + b)); r[n] = xe_row · att_r ----------------
__global__ __launch_bounds__(256) void k_enter(
    const float* __restrict__ x, const float* __restrict__ W, const float* __restrict__ b,
    const float* __restrict__ att_r, u16* __restrict__ xe, float* __restrict__ r_out, int N)
{
    int n = blockIdx.x*256 + threadIdx.x;
    if (n >= N) return;
    const float4* xrow = (const float4*)(x + (size_t)n*DIN);
    float rpart = 0.f;
    #pragma unroll 1
    for (int p = 0; p < 2; ++p){
        float acc[64];
        #pragma unroll
        for (int j = 0; j < 64; ++j) acc[j] = b[p*64 + j];
        for (int i4 = 0; i4 < DIN/4; ++i4){
            float4 v = xrow[i4];
            #pragma unroll
            for (int j = 0; j < 64; ++j){
                const float* wr = W + (size_t)(p*64 + j)*DIN + 4*i4;
                acc[j] = fmaf(wr[0], v.x, acc[j]);
                acc[j] = fmaf(wr[1], v.y, acc[j]);
                acc[j] = fmaf(wr[2], v.z, acc[j]);
                acc[j] = fmaf(wr[3], v.w, acc[j]);
            }
        }
        #pragma unroll
        for (int j = 0; j < 64; ++j){
            float o = lrelu(acc[j]);
            rpart = fmaf(o, att_r[p*64 + j], rpart);
            acc[j] = o;
        }
        uint4* xo = (uint4*)(xe + (size_t)n*HD + p*64);
        #pragma unroll
        for (int q = 0; q < 8; ++q){
            uint4 t;
            t.x = pk2(acc[8*q+0], acc[8*q+1]);
            t.y = pk2(acc[8*q+2], acc[8*q+3]);
            t.z = pk2(acc[8*q+4], acc[8*q+5]);
            t.w = pk2(acc[8*q+6], acc[8*q+7]);
            xo[q] = t;
        }
    }
    r_out[n] = rpart;
}

// ---------------- CSR build ----------------
__global__ void k_hist(const int* __restrict__ dst, int* __restrict__ deg, int E){
    int e = blockIdx.x*256 + threadIdx.x;
    if (e < E) atomicAdd(&deg[dst[e]], 1);
}

__global__ __launch_bounds__(256) void k_scan_a(
    const int* __restrict__ deg, int* __restrict__ rs, int* __restrict__ btot, int N)
{
    __shared__ int sd[256];
    int b = blockIdx.x, t = threadIdx.x;
    int base = b*1024 + t*4;
    int d0 = deg[base], d1 = deg[base+1], d2 = deg[base+2], d3 = deg[base+3];
    int s = d0 + d1 + d2 + d3;
    sd[t] = s; __syncthreads();
    for (int o = 1; o < 256; o <<= 1){
        int v = (t >= o) ? sd[t-o] : 0;
        __syncthreads();
        sd[t] += v;
        __syncthreads();
    }
    int ex = sd[t] - s;
    rs[base]   = ex;
    rs[base+1] = ex + d0;
    rs[base+2] = ex + d0 + d1;
    rs[base+3] = ex + d0 + d1 + d2;
    if (t == 0) btot[b] = sd[255];
}

__global__ __launch_bounds__(256) void k_scan_b(const int* __restrict__ btot, int* __restrict__ bbase){
    __shared__ int sd[256];
    int t = threadIdx.x;
    int s = btot[t];
    sd[t] = s; __syncthreads();
    for (int o = 1; o < 256; o <<= 1){
        int v = (t >= o) ? sd[t-o] : 0;
        __syncthreads();
        sd[t] += v;
        __syncthreads();
    }
    bbase[t] = sd[t] - s;
}

__global__ void k_scan_c(int* __restrict__ rs, const int* __restrict__ bbase, int N, int E){
    int i = blockIdx.x*256 + threadIdx.x;
    if (i < N) rs[i] += bbase[i >> 10];
    if (i == 0) rs[N] = E;
}

__global__ void k_scatter(const int* __restrict__ dst, const int* __restrict__ rs,
                          int* __restrict__ cnt, int* __restrict__ esort, int E){
    int e = blockIdx.x*256 + threadIdx.x;
    if (e >= E) return;
    int d = dst[e];
    int pos = rs[d] + atomicAdd(&cnt[d], 1);
    esort[pos] = e;
}

// ---------------- K2: m = leaky(W1 @ [xe[src], ea]); alpha = leaky(m·att_l + r[dst]) ----------------
template<typename MT>
__global__ __launch_bounds__(256) void k_edge(
    const u16* __restrict__ xe, const float* __restrict__ ea,
    const float* __restrict__ W1, const float* __restrict__ att_l,
    const float* __restrict__ r_dst, const int* __restrict__ src, const int* __restrict__ dst,
    MT* __restrict__ m_out, float* __restrict__ alpha_out, int E)
{
    int e = blockIdx.x*256 + threadIdx.x;
    if (e >= E) return;
    int sn = src[e];
    const uint4*  xrow  = (const uint4*)(xe + (size_t)sn*HD);
    const float4* earow = (const float4*)(ea + (size_t)e*DE);
    float lpart = 0.f;
    #pragma unroll 1
    for (int p = 0; p < 2; ++p){
        float acc[64];
        #pragma unroll
        for (int j = 0; j < 64; ++j) acc[j] = 0.f;
        for (int c = 0; c < 16; ++c){
            uint4 u = xrow[c];
            float f0 = bf16_to_f32((u16)(u.x & 0xFFFFu)), f1 = bf16_to_f32((u16)(u.x >> 16));
            float f2 = bf16_to_f32((u16)(u.y & 0xFFFFu)), f3 = bf16_to_f32((u16)(u.y >> 16));
            float f4 = bf16_to_f32((u16)(u.z & 0xFFFFu)), f5 = bf16_to_f32((u16)(u.z >> 16));
            float f6 = bf16_to_f32((u16)(u.w & 0xFFFFu)), f7 = bf16_to_f32((u16)(u.w >> 16));
            #pragma unroll
            for (int j = 0; j < 64; ++j){
                const float* wr = W1 + (size_t)(p*64 + j)*CAT + 8*c;
                acc[j] = fmaf(wr[0], f0, acc[j]); acc[j] = fmaf(wr[1], f1, acc[j]);
                acc[j] = fmaf(wr[2], f2, acc[j]); acc[j] = fmaf(wr[3], f3, acc[j]);
                acc[j] = fmaf(wr[4], f4, acc[j]); acc[j] = fmaf(wr[5], f5, acc[j]);
                acc[j] = fmaf(wr[6], f6, acc[j]); acc[j] = fmaf(wr[7], f7, acc[j]);
            }
        }
        for (int c = 0; c < 8; ++c){
            float4 v = earow[c];
            #pragma unroll
            for (int j = 0; j < 64; ++j){
                const float* wr = W1 + (size_t)(p*64 + j)*CAT + 128 + 4*c;
                acc[j] = fmaf(wr[0], v.x, acc[j]);
                acc[j] = fmaf(wr[1], v.y, acc[j]);
                acc[j] = fmaf(wr[2], v.z, acc[j]);
                acc[j] = fmaf(wr[3], v.w, acc[j]);
            }
        }
        #pragma unroll
        for (int j = 0; j < 64; ++j){
            float mv = lrelu(acc[j]);
            lpart = fmaf(mv, att_l[p*64 + j], lpart);
            acc[j] = mv;
        }
        MC<MT>::store(m_out + (size_t)e*HD + p*64, acc);
    }
    float a = lpart + r_dst[dst[e]];
    alpha_out[e] = lrelu(a);
}

// ---------------- K4: per-node segment softmax + weighted sum of m -> a_agg ----------------
template<typename MT>
__global__ __launch_bounds__(256) void k_agg(
    const int* __restrict__ rs, const int* __restrict__ esort,
    const float* __restrict__ alpha, const MT* __restrict__ m,
    float* __restrict__ a_out, int N)
{
    int wid  = (blockIdx.x*256 + threadIdx.x) >> 6;
    int lane = threadIdx.x & 63;
    if (wid >= N) return;
    int s = rs[wid], t = rs[wid+1];
    int deg = t - s;
    float ax = 0.f, ay = 0.f;
    if (deg > 0){
        float mx = -1e38f;
        for (int k = lane; k < deg; k += 64) mx = fmaxf(mx, alpha[esort[s+k]]);
        mx = wave_max(mx);
        float ssum = 0.f;
        for (int k = lane; k < deg; k += 64) ssum += __expf(alpha[esort[s+k]] - mx);
        ssum = wave_sum(ssum);
        float inv = 1.f / ssum;
        for (int k = 0; k < deg; ++k){
            int e = esort[s+k];
            float w = __expf(alpha[e] - mx) * inv;
            float2 mv = MC<MT>::load2(m + (size_t)e*HD, lane);
            ax = fmaf(w, mv.x, ax);
            ay = fmaf(w, mv.y, ay);
        }
    }
    float2 o; o.x = ax; o.y = ay;
    *(float2*)(a_out + (size_t)wid*HD + 2*lane) = o;
}

// ---------------- K5a: h = elu(W2 @ a + b_conv) ----------------
__global__ __launch_bounds__(256) void k_conv2(
    const float* __restrict__ a, const float* __restrict__ W2, const float* __restrict__ bc,
    float* __restrict__ h, int N)
{
    int n = blockIdx.x*256 + threadIdx.x;
    if (n >= N) return;
    const float4* ar = (const float4*)(a + (size_t)n*HD);
    #pragma unroll 1
    for (int p = 0; p < 2; ++p){
        float acc[64];
        #pragma unroll
        for (int j = 0; j < 64; ++j) acc[j] = bc[p*64 + j];
        for (int i4 = 0; i4 < 32; ++i4){
            float4 v = ar[i4];
            #pragma unroll
            for (int j = 0; j < 64; ++j){
                const float* wr = W2 + (size_t)(p*64 + j)*HD + 4*i4;
                acc[j] = fmaf(wr[0], v.x, acc[j]);
                acc[j] = fmaf(wr[1], v.y, acc[j]);
                acc[j] = fmaf(wr[2], v.z, acc[j]);
                acc[j] = fmaf(wr[3], v.w, acc[j]);
            }
        }
        float4* ho = (float4*)(h + (size_t)n*HD + p*64);
        #pragma unroll
        for (int q = 0; q < 16; ++q){
            float4 o;
            o.x = eluf_(acc[4*q+0]); o.y = eluf_(acc[4*q+1]);
            o.z = eluf_(acc[4*q+2]); o.w = eluf_(acc[4*q+3]);
            ho[q] = o;
        }
    }
}

// ---------------- K5b: GRU cell -> x_new + per-node (sum, sumsq) ----------------
__global__ __launch_bounds__(256) void k_gru(
    const float* __restrict__ h, const u16* __restrict__ xe,
    const float* __restrict__ Wih, const float* __restrict__ Whh,
    const float* __restrict__ bih, const float* __restrict__ bhh,
    float* __restrict__ xnew, float* __restrict__ stats, int N)
{
    int n = blockIdx.x*256 + threadIdx.x;
    if (n >= N) return;
    const float4* hrow = (const float4*)(h  + (size_t)n*HD);
    const uint4*  xrow = (const uint4*)(xe + (size_t)n*HD);
    float sum = 0.f, ss = 0.f;
    #pragma unroll 1
    for (int p = 0; p < 4; ++p){
        float ra[32], za[32], ia[32], ha[32];
        #pragma unroll
        for (int j = 0; j < 32; ++j){
            int jr = p*32 + j;
            ra[j] = bih[jr]       + bhh[jr];
            za[j] = bih[128 + jr] + bhh[128 + jr];
            ia[j] = bih[256 + jr];
            ha[j] = bhh[256 + jr];
        }
        for (int c = 0; c < 16; ++c){
            float4 h0 = hrow[2*c], h1 = hrow[2*c+1];
            uint4 xu = xrow[c];
            float hx0 = h0.x, hx1 = h0.y, hx2 = h0.z, hx3 = h0.w;
            float hx4 = h1.x, hx5 = h1.y, hx6 = h1.z, hx7 = h1.w;
            float xv0 = bf16_to_f32((u16)(xu.x & 0xFFFFu)), xv1 = bf16_to_f32((u16)(xu.x >> 16));
            float xv2 = bf16_to_f32((u16)(xu.y & 0xFFFFu)), xv3 = bf16_to_f32((u16)(xu.y >> 16));
            float xv4 = bf16_to_f32((u16)(xu.z & 0xFFFFu)), xv5 = bf16_to_f32((u16)(xu.z >> 16));
            float xv6 = bf16_to_f32((u16)(xu.w & 0xFFFFu)), xv7 = bf16_to_f32((u16)(xu.w >> 16));
            #pragma unroll
            for (int j = 0; j < 32; ++j){
                int jr = p*32 + j;
                const float* wri = Wih + (size_t)jr*HD + 8*c;
                const float* wrh = Whh + (size_t)jr*HD + 8*c;
                const float* wzi = Wih + (size_t)(128 + jr)*HD + 8*c;
                const float* wzh = Whh + (size_t)(128 + jr)*HD + 8*c;
                const float* wni = Wih + (size_t)(256 + jr)*HD + 8*c;
                const float* wnh = Whh + (size_t)(256 + jr)*HD + 8*c;
                ra[j] = fmaf(wri[0], hx0, ra[j]); ra[j] = fmaf(wri[1], hx1, ra[j]);
                ra[j] = fmaf(wri[2], hx2, ra[j]); ra[j] = fmaf(wri[3], hx3, ra[j]);
                ra[j] = fmaf(wri[4], hx4, ra[j]); ra[j] = fmaf(wri[5], hx5, ra[j]);
                ra[j] = fmaf(wri[6], hx6, ra[j]); ra[j] = fmaf(wri[7], hx7, ra[j]);
                ra[j] = fmaf(wrh[0], xv0, ra[j]); ra[j] = fmaf(wrh[1], xv1, ra[j]);
                ra[j] = fmaf(wrh[2], xv2, ra[j]); ra[j] = fmaf(wrh[3], xv3, ra[j]);
                ra[j] = fmaf(wrh[4], xv4, ra[j]); ra[j] = fmaf(wrh[5], xv5, ra[j]);
                ra[j] = fmaf(wrh[6], xv6, ra[j]); ra[j] = fmaf(wrh[7], xv7, ra[j]);
                za[j] = fmaf(wzi[0], hx0, za[j]); za[j] = fmaf(wzi[1], hx1, za[j]);
                za[j] = fmaf(wzi[2], hx2, za[j]); za[j] = fmaf(wzi[3], hx3, za[j]);
                za[j] = fmaf(wzi[4], hx4, za[j]); za[j] = fmaf(wzi[5], hx5, za[j]);
                za[j] = fmaf(wzi[6], hx6, za[j]); za[j] = fmaf(wzi[7], hx7, za[j]);
                za[j] = fmaf(wzh[0], xv0, za[j]); za[j] = fmaf(wzh[1], xv1, za[j]);
                za[j] = fmaf(wzh[2], xv2, za[j]); za[j] = fmaf(wzh[3], xv3, za[j]);
                za[j] = fmaf(wzh[4], xv4, za[j]); za[j] = fmaf(wzh[5], xv5, za[j]);
                za[j] = fmaf(wzh[6], xv6, za[j]); za[j] = fmaf(wzh[7], xv7, za[j]);
                ia[j] = fmaf(wni[0], hx0, ia[j]); ia[j] = fmaf(wni[1], hx1, ia[j]);
                ia[j] = fmaf(wni[2], hx2, ia[j]); ia[j] = fmaf(wni[3], hx3, ia[j]);
                ia[j] = fmaf(wni[4], hx4, ia[j]); ia[j] = fmaf(wni[5], hx5, ia[j]);
                ia[j] = fmaf(wni[6], hx6, ia[j]); ia[j] = fmaf(wni[7], hx7, ia[j]);
                ha[j] = fmaf(wnh[0], xv0, ha[j]); ha[j] = fmaf(wnh[1], xv1, ha[j]);
                ha[j] = fmaf(wnh[2], xv2, ha[j]); ha[j] = fmaf(wnh[3], xv3, ha[j]);
                ha[j] = fmaf(wnh[4], xv4, ha[j]); ha[j] = fmaf(wnh[5], xv5, ha[j]);
                ha[j] = fmaf(wnh[6], xv6, ha[j]); ha[j] = fmaf(wnh[7], xv7, ha[j]);
            }
        }
        float outc[32];
        #pragma unroll
        for (int j = 0; j < 32; ++j){
            float r  = sigmoidf_(ra[j]);
            float z  = sigmoidf_(za[j]);
            float nc = tanhf_(ia[j] + r*ha[j]);
            float xej = bf16_to_f32(xe[(size_t)n*HD + p*32 + j]);
            float v = (1.f - z)*nc + z*xej;
            v = fmaxf(v, 0.f);
            outc[j] = v;
            sum += v;
            ss  = fmaf(v, v, ss);
        }
        float4* xo = (float4*)(xnew + (size_t)n*HD + p*32);
        #pragma unroll
        for (int q = 0; q < 8; ++q){
            float4 o; o.x = outc[4*q]; o.y = outc[4*q+1]; o.z = outc[4*q+2]; o.w = outc[4*q+3];
            xo[q] = o;
        }
    }
    stats[n]     = sum;
    stats[N + n] = ss;
}

// ---------------- K6: LayerNorm (no affine), in-place safe ----------------
__global__ void k_ln(const float* __restrict__ xnew, const float* __restrict__ stats,
                     float* __restrict__ out, int total, int N)
{
    int i4 = blockIdx.x*256 + threadIdx.x;
    if (i4*4 >= total) return;
    float4 v = ((const float4*)xnew)[i4];
    int n = (i4*4) >> 7;
    float mu  = stats[n] * (1.f/128.f);
    float var = stats[N + n] * (1.f/128.f) - mu*mu;
    var = fmaxf(var, 0.f);
    float rsd = rsqrtf(var + 1e-5f);
    float4 o;
    o.x = (v.x - mu)*rsd; o.y = (v.y - mu)*rsd;
    o.z = (v.z - mu)*rsd; o.w = (v.w - mu)*rsd;
    ((float4*)out)[i4] = o;
}

// ---------------- host ----------------
extern "C" void kernel_launch(void* const* d_in, const int* in_sizes, int n_in,
                              void* d_out, int out_size, void* d_ws, size_t ws_size,
                              hipStream_t stream)
{
    const float* x       = (const float*)d_in[0];
    const float* ea      = (const float*)d_in[1];
    const float* W_enter = (const float*)d_in[2];
    const float* b_enter = (const float*)d_in[3];
    const float* W1      = (const float*)d_in[4];
    const float* att_l   = (const float*)d_in[5];
    const float* att_r   = (const float*)d_in[6];
    const float* W2      = (const float*)d_in[7];
    const float* b_conv  = (const float*)d_in[8];
    const float* W_ih    = (const float*)d_in[9];
    const float* W_hh    = (const float*)d_in[10];
    const float* b_ih    = (const float*)d_in[11];
    const float* b_hh    = (const float*)d_in[12];
    const int*   eidx    = (const int*)d_in[13];

    int N = in_sizes[0] / DIN;
    int E = in_sizes[13] / 2;
    const int* src = eidx;
    const int* dst = eidx + E;
    float* out = (float*)d_out;

    size_t off = 0;
    char* base = (char*)d_ws;
    auto alloc = [&](size_t bytes) -> char* {
        char* p = base + off;
        off = (off + bytes + 255) & ~(size_t)255;
        return p;
    };
    u16*   xe    = (u16*)  alloc((size_t)N*HD*2);
    float* r_dst = (float*)alloc((size_t)N*4);
    float* alpha = (float*)alloc((size_t)E*4);
    int*   deg   = (int*)  alloc((size_t)N*4);
    int*   rs    = (int*)  alloc((size_t)(N+1)*4);
    int*   cnt   = (int*)  alloc((size_t)N*4);
    int*   esort = (int*)  alloc((size_t)E*4);
    float* stats = (float*)alloc((size_t)N*2*4);
    int*   btot  = (int*)  alloc(1024);
    int*   bbase = (int*)  alloc(1024);

    // m buffer: bf16 if it fits in the remaining workspace, else custom-fp8.
    size_t m_bf16_bytes = (size_t)E*HD*2;
    bool   big = (ws_size - off) >= m_bf16_bytes;
    void*  mbuf = (void*)(base + off);
    float* hbuf = (float*)mbuf;          // aliases m (dead after k_agg); needs N*HD*4 <= E*HD
    float* a_agg = out;                  // d_out reused (dead before k_gru writes)
    float* xnew  = out;                  // d_out reused, k_ln runs in-place

    k_zero2  <<<(N+255)/256, 256, 0, stream>>>(deg, cnt, N);
    k_enter  <<<(N+255)/256, 256, 0, stream>>>(x, W_enter, b_enter, att_r, xe, r_dst, N);
    k_hist   <<<(E+255)/256, 256, 0, stream>>>(dst, deg, E);
    k_scan_a <<<N/1024, 256, 0, stream>>>(deg, rs, btot, N);
    k_scan_b <<<1, 256, 0, stream>>>(btot, bbase);
    k_scan_c <<<(N+255)/256, 256, 0, stream>>>(rs, bbase, N, E);
    if (big){
        k_edge<u16><<<(E+255)/256, 256, 0, stream>>>(xe, ea, W1, att_l, r_dst, src, dst,
                                                     (u16*)mbuf, alpha, E);
    } else {
        k_edge<u8> <<<(E+255)/256, 256, 0, stream>>>(xe, ea, W1, att_l, r_dst, src, dst,
                                                     (u8*)mbuf, alpha, E);
    }
    k_scatter<<<(E+255)/256, 256, 0, stream>>>(dst, rs, cnt, esort, E);
    if (big){
        k_agg<u16><<<(N+3)/4, 256, 0, stream>>>(rs, esort, alpha, (const u16*)mbuf, a_agg, N);
    } else {
        k_agg<u8> <<<(N+3)/4, 256, 0, stream>>>(rs, esort, alpha, (const u8*)mbuf, a_agg, N);
    }
    k_conv2  <<<(N+255)/256, 256, 0, stream>>>(a_agg, W2, b_conv, hbuf, N);
    k_gru    <<<(N+255)/256, 256, 0, stream>>>(hbuf, xe, W_ih, W_hh, b_ih, b_hh, xnew, stats, N);
    k_ln     <<<((N*HD/4)+255)/256, 256, 0, stream>>>(xnew, stats, out, N*HD, N);
}

// Round 3
// 911.102 us; speedup vs baseline: 5.8378x; 5.8378x over previous
//
#include <hip/hip_runtime.h>
#include <stdint.h>

#define HD  128
#define DIN 64
#define DE  32

typedef unsigned int u32; typedef unsigned short u16; typedef unsigned char u8;
typedef short s16x8 __attribute__((ext_vector_type(8)));
typedef float f32x4 __attribute__((ext_vector_type(4)));

#define MFMA16(a,b,c) __builtin_amdgcn_mfma_f32_16x16x32_bf16((a),(b),(c),0,0,0)

__device__ __forceinline__ float lrelu(float x){ return x > 0.f ? x : 0.01f*x; }
__device__ __forceinline__ float sigmoidf_(float x){ return 1.f/(1.f + __expf(-x)); }
__device__ __forceinline__ float tanhf_(float x){
    float t = fminf(fmaxf(x, -15.f), 15.f);
    float e = __expf(2.f*t);
    return (e - 1.f)/(e + 1.f);
}
__device__ __forceinline__ float eluf_(float x){ return x > 0.f ? x : expm1f(x); }

__device__ __forceinline__ u16 f32_to_bf16(float x){
    u32 u = __float_as_uint(x);
    u += 0x7FFFu + ((u >> 16) & 1u);
    return (u16)(u >> 16);
}
__device__ __forceinline__ float bf16lo(u32 u){ return __uint_as_float((u & 0xFFFFu) << 16); }
__device__ __forceinline__ float bf16hi(u32 u){ return __uint_as_float(u & 0xFFFF0000u); }
__device__ __forceinline__ float bf16f(u16 h){ return __uint_as_float(((u32)h) << 16); }
__device__ __forceinline__ u32 pk2(float a, float b){
    return (u32)f32_to_bf16(a) | ((u32)f32_to_bf16(b) << 16);
}
// custom e4m3, exponent bias 13: normals in [2^-12, 7.5]
__device__ __forceinline__ u8 f32_to_f8(float x){
    u32 u = __float_as_uint(x);
    u32 s = (u >> 24) & 0x80u;
    u &= 0x7FFFFFFFu;
    u += 0x0007FFFFu + ((u >> 20) & 1u);
    int e = (int)(u >> 23) - 114;
    if (e <= 0)  return (u8)s;
    if (e > 15)  return (u8)(s | 0x7F);
    return (u8)(s | ((u32)e << 3) | ((u >> 20) & 7u));
}
__device__ __forceinline__ float f8_to_f32(u32 b){
    u32 e = (b >> 3) & 0xFu;
    u32 u = ((b & 0x80u) << 24) | ((e + 114u) << 23) | ((b & 7u) << 20);
    float f = __uint_as_float(u);
    return e ? f : 0.f;
}

template<typename MT> struct MC;
template<> struct MC<u16>{
    static __device__ __forceinline__ float2 load2(const u16* row, int lane){
        u32 u = *(const u32*)(row + 2*lane);
        float2 r; r.x = bf16lo(u); r.y = bf16hi(u);
        return r;
    }
};
template<> struct MC<u8>{
    static __device__ __forceinline__ float2 load2(const u8* row, int lane){
        u32 u = *(const u16*)(row + 2*lane);
        float2 r; r.x = f8_to_f32(u & 0xFFu); r.y = f8_to_f32((u >> 8) & 0xFFu);
        return r;
    }
};

__device__ __forceinline__ float wave_max(float v){
    #pragma unroll
    for (int o = 32; o > 0; o >>= 1) v = fmaxf(v, __shfl_xor(v, o, 64));
    return v;
}
__device__ __forceinline__ float wave_sum(float v){
    #pragma unroll
    for (int o = 32; o > 0; o >>= 1) v += __shfl_xor(v, o, 64);
    return v;
}
__device__ __forceinline__ float dot8_bf16(uint4 v, const float* __restrict__ al){
    float d = 0.f;
    d = fmaf(bf16lo(v.x), al[0], d); d = fmaf(bf16hi(v.x), al[1], d);
    d = fmaf(bf16lo(v.y), al[2], d); d = fmaf(bf16hi(v.y), al[3], d);
    d = fmaf(bf16lo(v.z), al[4], d); d = fmaf(bf16hi(v.z), al[5], d);
    d = fmaf(bf16lo(v.w), al[6], d); d = fmaf(bf16hi(v.w), al[7], d);
    return d;
}
__device__ __forceinline__ float dot16_f8(uint4 v, const float* __restrict__ al){
    float d = 0.f;
    u32 ws[4] = {v.x, v.y, v.z, v.w};
    #pragma unroll
    for (int i = 0; i < 4; ++i){
        #pragma unroll
        for (int b = 0; b < 4; ++b)
            d = fmaf(f8_to_f32((ws[i] >> (8*b)) & 0xFFu), al[4*i + b], d);
    }
    return d;
}

// ---------------- weight prep: fp32 -> bf16 (+ GRU B-pack) ----------------
__global__ void k_prep(const float* __restrict__ W1, const float* __restrict__ W2,
                       const float* __restrict__ Went,
                       const float* __restrict__ Wih, const float* __restrict__ Whh,
                       u16* __restrict__ W1b, u16* __restrict__ W2b,
                       u16* __restrict__ Wentb, u16* __restrict__ Bg)
{
    int i = blockIdx.x*256 + threadIdx.x;
    if (i < 20480){ W1b[i] = f32_to_bf16(W1[i]); return; }
    i -= 20480;
    if (i < 16384){ W2b[i] = f32_to_bf16(W2[i]); return; }
    i -= 16384;
    if (i < 8192){ Wentb[i] = f32_to_bf16(Went[i]); return; }
    i -= 8192;
    if (i < 131072){
        int col = i >> 8, k = i & 255;
        int g = col >> 7, j = col & 127;
        float v;
        if      (g == 0) v = (k < 128) ? Wih[j*128 + k]        : Whh[j*128 + k - 128];
        else if (g == 1) v = (k < 128) ? Wih[(128+j)*128 + k]  : Whh[(128+j)*128 + k - 128];
        else if (g == 2) v = (k < 128) ? Wih[(256+j)*128 + k]  : 0.f;
        else             v = (k < 128) ? 0.f                   : Whh[(256+j)*128 + k - 128];
        Bg[(size_t)(i - (i & 255)) + (i & 255)] = f32_to_bf16(v);
    }
}

// ---------------- init ----------------
__global__ void k_zero2(int* __restrict__ a, int* __restrict__ b, int n){
    int i = blockIdx.x*256 + threadIdx.x;
    if (i < n){ a[i] = 0; b[i] = 0; }
}

// ---------------- K1 (MFMA): xe-half of Ag = bf16(lrelu(x@W^T+b)); r_dst = xe·att_r ----------------
__global__ __launch_bounds__(256, 2) void k_enter_mfma(
    const float* __restrict__ x, const u16* __restrict__ Wb, const float* __restrict__ be,
    const float* __restrict__ att_r, u16* __restrict__ Ag, float* __restrict__ r_out, int N)
{
    __shared__ __align__(16) u8 sA[64*144];
    __shared__ __align__(16) u8 sO[64*272];
    int t = threadIdx.x, w = t >> 6, lane = t & 63, l15 = lane & 15, l4 = lane >> 4;
    int tile = blockIdx.x;

    s16x8 bfr[2][2];
    #pragma unroll
    for (int kf = 0; kf < 2; ++kf)
        #pragma unroll
        for (int cf = 0; cf < 2; ++cf)
            bfr[kf][cf] = *(const s16x8*)(Wb + (size_t)(w*32 + cf*16 + l15)*64 + kf*32 + l4*8);

    int el = t >> 2, q = t & 3;
    size_t n = (size_t)tile*64 + el;
    {
        const float4* xs = (const float4*)(x + n*64 + q*16);
        float4 f0 = xs[0], f1 = xs[1], f2 = xs[2], f3 = xs[3];
        uint4 o0, o1;
        o0.x = pk2(f0.x,f0.y); o0.y = pk2(f0.z,f0.w); o0.z = pk2(f1.x,f1.y); o0.w = pk2(f1.z,f1.w);
        o1.x = pk2(f2.x,f2.y); o1.y = pk2(f2.z,f2.w); o1.z = pk2(f3.x,f3.y); o1.w = pk2(f3.z,f3.w);
        *(uint4*)(sA + el*144 + q*32)      = o0;
        *(uint4*)(sA + el*144 + q*32 + 16) = o1;
    }
    __syncthreads();

    f32x4 acc[4][2];
    #pragma unroll
    for (int rf = 0; rf < 4; ++rf){ acc[rf][0] = (f32x4)0.f; acc[rf][1] = (f32x4)0.f; }
    #pragma unroll
    for (int kf = 0; kf < 2; ++kf){
        s16x8 a[4];
        #pragma unroll
        for (int rf = 0; rf < 4; ++rf)
            a[rf] = *(const s16x8*)(sA + (rf*16 + l15)*144 + kf*64 + l4*16);
        #pragma unroll
        for (int rf = 0; rf < 4; ++rf){
            acc[rf][0] = MFMA16(a[rf], bfr[kf][0], acc[rf][0]);
            acc[rf][1] = MFMA16(a[rf], bfr[kf][1], acc[rf][1]);
        }
    }
    float b0 = be[w*32 + l15], b1 = be[w*32 + 16 + l15];
    #pragma unroll
    for (int rf = 0; rf < 4; ++rf)
        #pragma unroll
        for (int r = 0; r < 4; ++r){
            int row = rf*16 + l4*4 + r;
            *(u16*)(sO + row*272 + (w*32 + l15)*2)      = f32_to_bf16(lrelu(acc[rf][0][r] + b0));
            *(u16*)(sO + row*272 + (w*32 + 16 + l15)*2) = f32_to_bf16(lrelu(acc[rf][1][r] + b1));
        }
    __syncthreads();

    float dot = 0.f;
    #pragma unroll
    for (int i = 0; i < 4; ++i){
        uint4 v = *(const uint4*)(sO + el*272 + q*64 + 16*i);
        ((uint4*)Ag)[n*32 + 16 + q*4 + i] = v;         // xe half: byte n*512+256
        dot += dot8_bf16(v, att_r + q*32 + 8*i);
    }
    dot += __shfl_xor(dot, 1); dot += __shfl_xor(dot, 2);
    if (q == 0) r_out[n] = dot;
}

// ---------------- CSR build ----------------
__global__ void k_hist(const int* __restrict__ dst, int* __restrict__ deg, int E){
    int e = blockIdx.x*256 + threadIdx.x;
    if (e < E) atomicAdd(&deg[dst[e]], 1);
}
__global__ __launch_bounds__(256) void k_scan_a(
    const int* __restrict__ deg, int* __restrict__ rs, int* __restrict__ btot, int N)
{
    __shared__ int sd[256];
    int b = blockIdx.x, t = threadIdx.x;
    int base = b*1024 + t*4;
    int d0 = deg[base], d1 = deg[base+1], d2 = deg[base+2], d3 = deg[base+3];
    int s = d0 + d1 + d2 + d3;
    sd[t] = s; __syncthreads();
    for (int o = 1; o < 256; o <<= 1){
        int v = (t >= o) ? sd[t-o] : 0;
        __syncthreads();
        sd[t] += v;
        __syncthreads();
    }
    int ex = sd[t] - s;
    rs[base]   = ex;
    rs[base+1] = ex + d0;
    rs[base+2] = ex + d0 + d1;
    rs[base+3] = ex + d0 + d1 + d2;
    if (t == 0) btot[b] = sd[255];
}
__global__ __launch_bounds__(256) void k_scan_b(const int* __restrict__ btot, int* __restrict__ bbase){
    __shared__ int sd[256];
    int t = threadIdx.x;
    int s = btot[t];
    sd[t] = s; __syncthreads();
    for (int o = 1; o < 256; o <<= 1){
        int v = (t >= o) ? sd[t-o] : 0;
        __syncthreads();
        sd[t] += v;
        __syncthreads();
    }
    bbase[t] = sd[t] - s;
}
__global__ void k_scan_c(int* __restrict__ rs, const int* __restrict__ bbase, int N, int E){
    int i = blockIdx.x*256 + threadIdx.x;
    if (i < N) rs[i] += bbase[i >> 10];
    if (i == 0) rs[N] = E;
}
__global__ void k_scatter(const int* __restrict__ dst, const int* __restrict__ rs,
                          int* __restrict__ cnt, int* __restrict__ esort, int E){
    int e = blockIdx.x*256 + threadIdx.x;
    if (e >= E) return;
    int d = dst[e];
    int pos = rs[d] + atomicAdd(&cnt[d], 1);
    esort[pos] = e;
}

// ---------------- K2 (MFMA): m = lrelu(W1@[xe[src],ea]); alpha = lrelu(m·att_l + r[dst]) ----------------
template<typename MT>
__global__ __launch_bounds__(256, 2) void k_edge_mfma(
    const u16* __restrict__ Ag, const float* __restrict__ ea,
    const u16* __restrict__ W1b, const float* __restrict__ att_l,
    const float* __restrict__ r_dst, const int* __restrict__ src, const int* __restrict__ dst,
    MT* __restrict__ m, float* __restrict__ alpha, int ntiles, int E)
{
    __shared__ __align__(16) u8 sA[64*336];
    __shared__ __align__(16) u8 sM[64*272];
    int t = threadIdx.x, w = t >> 6, lane = t & 63, l15 = lane & 15, l4 = lane >> 4;
    constexpr int MS = (sizeof(MT) == 2) ? 272 : 144;

    s16x8 bfr[5][2];
    #pragma unroll
    for (int kf = 0; kf < 5; ++kf)
        #pragma unroll
        for (int cf = 0; cf < 2; ++cf)
            bfr[kf][cf] = *(const s16x8*)(W1b + (size_t)(w*32 + cf*16 + l15)*160 + kf*32 + l4*8);

    int el = t >> 2, q = t & 3;
    for (int tile = blockIdx.x; tile < ntiles; tile += gridDim.x){
        int e = tile*64 + el;
        if (e < E){
            int sn = src[e];
            const uint4* xs = (const uint4*)Ag + (size_t)sn*32 + 16 + q*4;
            uint4 v0 = xs[0], v1 = xs[1], v2 = xs[2], v3 = xs[3];
            uint4* d = (uint4*)(sA + el*336 + q*64);
            d[0] = v0; d[1] = v1; d[2] = v2; d[3] = v3;
            const float4* ef = (const float4*)(ea + (size_t)e*32 + q*8);
            float4 f0 = ef[0], f1 = ef[1];
            uint4 o;
            o.x = pk2(f0.x,f0.y); o.y = pk2(f0.z,f0.w); o.z = pk2(f1.x,f1.y); o.w = pk2(f1.z,f1.w);
            *(uint4*)(sA + el*336 + 256 + q*16) = o;
        }
        __syncthreads();

        f32x4 acc[4][2];
        #pragma unroll
        for (int rf = 0; rf < 4; ++rf){ acc[rf][0] = (f32x4)0.f; acc[rf][1] = (f32x4)0.f; }
        #pragma unroll
        for (int kf = 0; kf < 5; ++kf){
            s16x8 a[4];
            #pragma unroll
            for (int rf = 0; rf < 4; ++rf)
                a[rf] = *(const s16x8*)(sA + (rf*16 + l15)*336 + kf*64 + l4*16);
            #pragma unroll
            for (int rf = 0; rf < 4; ++rf){
                acc[rf][0] = MFMA16(a[rf], bfr[kf][0], acc[rf][0]);
                acc[rf][1] = MFMA16(a[rf], bfr[kf][1], acc[rf][1]);
            }
        }
        #pragma unroll
        for (int rf = 0; rf < 4; ++rf)
            #pragma unroll
            for (int cf = 0; cf < 2; ++cf)
                #pragma unroll
                for (int r = 0; r < 4; ++r){
                    int row = rf*16 + l4*4 + r;
                    int col = w*32 + cf*16 + l15;
                    float vv = lrelu(acc[rf][cf][r]);
                    if (sizeof(MT) == 2) *(u16*)(sM + row*MS + col*2) = f32_to_bf16(vv);
                    else                 sM[row*MS + col] = f32_to_f8(vv);
                }
        __syncthreads();

        if (e < E){
            float dot = 0.f;
            if (sizeof(MT) == 2){
                #pragma unroll
                for (int i = 0; i < 4; ++i){
                    uint4 v = *(const uint4*)(sM + el*272 + q*64 + 16*i);
                    dot += dot8_bf16(v, att_l + q*32 + 8*i);
                    ((uint4*)m)[(size_t)e*16 + q*4 + i] = v;
                }
            } else {
                #pragma unroll
                for (int i = 0; i < 2; ++i){
                    uint4 v = *(const uint4*)(sM + el*144 + q*32 + 16*i);
                    dot += dot16_f8(v, att_l + q*32 + 16*i);
                    ((uint4*)m)[(size_t)e*8 + q*2 + i] = v;
                }
            }
            dot += __shfl_xor(dot, 1); dot += __shfl_xor(dot, 2);
            if (q == 0) alpha[e] = lrelu(dot + r_dst[dst[e]]);
        }
        __syncthreads();
    }
}

// ---------------- K4: per-node segment softmax + weighted sum of m -> a_agg ----------------
template<typename MT>
__global__ __launch_bounds__(256) void k_agg(
    const int* __restrict__ rs, const int* __restrict__ esort,
    const float* __restrict__ alpha, const MT* __restrict__ m,
    float* __restrict__ a_out, int N)
{
    int wid  = (blockIdx.x*256 + threadIdx.x) >> 6;
    int lane = threadIdx.x & 63;
    if (wid >= N) return;
    int s = rs[wid], t = rs[wid+1];
    int deg = t - s;
    float ax = 0.f, ay = 0.f;
    if (deg > 0){
        float mx = -1e38f;
        for (int k = lane; k < deg; k += 64) mx = fmaxf(mx, alpha[esort[s+k]]);
        mx = wave_max(mx);
        float ssum = 0.f;
        for (int k = lane; k < deg; k += 64) ssum += __expf(alpha[esort[s+k]] - mx);
        ssum = wave_sum(ssum);
        float inv = 1.f / ssum;
        for (int k = 0; k < deg; ++k){
            int e = esort[s+k];
            float wgt = __expf(alpha[e] - mx) * inv;
            float2 mv = MC<MT>::load2(m + (size_t)e*HD, lane);
            ax = fmaf(wgt, mv.x, ax);
            ay = fmaf(wgt, mv.y, ay);
        }
    }
    float2 o; o.x = ax; o.y = ay;
    *(float2*)(a_out + (size_t)wid*HD + 2*lane) = o;
}

// ---------------- K5a (MFMA): h-half of Ag = bf16(elu(W2@a + bc)) ----------------
__global__ __launch_bounds__(256, 2) void k_conv2_mfma(
    const float* __restrict__ a, const u16* __restrict__ W2b, const float* __restrict__ bc,
    u16* __restrict__ Ag, int N)
{
    __shared__ __align__(16) u8 sA[64*272];
    __shared__ __align__(16) u8 sO[64*272];
    int t = threadIdx.x, w = t >> 6, lane = t & 63, l15 = lane & 15, l4 = lane >> 4;
    int tile = blockIdx.x;

    s16x8 bfr[4][2];
    #pragma unroll
    for (int kf = 0; kf < 4; ++kf)
        #pragma unroll
        for (int cf = 0; cf < 2; ++cf)
            bfr[kf][cf] = *(const s16x8*)(W2b + (size_t)(w*32 + cf*16 + l15)*128 + kf*32 + l4*8);

    int el = t >> 2, q = t & 3;
    size_t n = (size_t)tile*64 + el;
    {
        const float4* as = (const float4*)(a + n*128 + q*32);
        #pragma unroll
        for (int i = 0; i < 4; ++i){
            float4 f0 = as[2*i], f1 = as[2*i+1];
            uint4 o;
            o.x = pk2(f0.x,f0.y); o.y = pk2(f0.z,f0.w); o.z = pk2(f1.x,f1.y); o.w = pk2(f1.z,f1.w);
            *(uint4*)(sA + el*272 + q*64 + 16*i) = o;
        }
    }
    __syncthreads();

    f32x4 acc[4][2];
    #pragma unroll
    for (int rf = 0; rf < 4; ++rf){ acc[rf][0] = (f32x4)0.f; acc[rf][1] = (f32x4)0.f; }
    #pragma unroll
    for (int kf = 0; kf < 4; ++kf){
        s16x8 av[4];
        #pragma unroll
        for (int rf = 0; rf < 4; ++rf)
            av[rf] = *(const s16x8*)(sA + (rf*16 + l15)*272 + kf*64 + l4*16);
        #pragma unroll
        for (int rf = 0; rf < 4; ++rf){
            acc[rf][0] = MFMA16(av[rf], bfr[kf][0], acc[rf][0]);
            acc[rf][1] = MFMA16(av[rf], bfr[kf][1], acc[rf][1]);
        }
    }
    float b0 = bc[w*32 + l15], b1 = bc[w*32 + 16 + l15];
    #pragma unroll
    for (int rf = 0; rf < 4; ++rf)
        #pragma unroll
        for (int r = 0; r < 4; ++r){
            int row = rf*16 + l4*4 + r;
            *(u16*)(sO + row*272 + (w*32 + l15)*2)      = f32_to_bf16(eluf_(acc[rf][0][r] + b0));
            *(u16*)(sO + row*272 + (w*32 + 16 + l15)*2) = f32_to_bf16(eluf_(acc[rf][1][r] + b1));
        }
    __syncthreads();
    #pragma unroll
    for (int i = 0; i < 4; ++i){
        uint4 v = *(const uint4*)(sO + el*272 + q*64 + 16*i);
        ((uint4*)Ag)[n*32 + q*4 + i] = v;              // h half: byte n*512
    }
}

// ---------------- K5b (MFMA): GRU cell -> xnew (d_out) + per-node stats ----------------
__global__ __launch_bounds__(512, 2) void k_gru_mfma(
    const u16* __restrict__ Ag, const u16* __restrict__ Bg,
    const float* __restrict__ bih, const float* __restrict__ bhh,
    float* __restrict__ out, float* __restrict__ stats, int N, int ntiles)
{
    __shared__ __align__(16) u8 sA[32*528];
    __shared__ float sst[32][2];
    int t = threadIdx.x, w = t >> 6, lane = t & 63, l15 = lane & 15, l4 = lane >> 4;

    s16x8 bfr[8][4];
    #pragma unroll
    for (int g = 0; g < 4; ++g){
        int col = g*128 + w*16 + l15;
        #pragma unroll
        for (int kf = 0; kf < 8; ++kf)
            bfr[kf][g] = *(const s16x8*)(Bg + (size_t)col*256 + kf*32 + l4*8);
    }
    int j = w*16 + l15;
    float rb = bih[j] + bhh[j];
    float zb = bih[128 + j] + bhh[128 + j];
    float ib = bih[256 + j];
    float hb = bhh[256 + j];

    for (int tile = blockIdx.x; tile < ntiles; tile += gridDim.x){
        if (t < 64) sst[t >> 1][t & 1] = 0.f;
        {
            int el = t >> 4, part = t & 15;
            const uint4* gsrc = (const uint4*)Ag + ((size_t)tile*32 + el)*32 + part*2;
            uint4 v0 = gsrc[0], v1 = gsrc[1];
            uint4* d = (uint4*)(sA + el*528 + part*32);
            d[0] = v0; d[1] = v1;
        }
        __syncthreads();

        f32x4 acc[2][4];
        #pragma unroll
        for (int rf = 0; rf < 2; ++rf)
            #pragma unroll
            for (int g = 0; g < 4; ++g) acc[rf][g] = (f32x4)0.f;
        #pragma unroll
        for (int kf = 0; kf < 8; ++kf){
            s16x8 a0 = *(const s16x8*)(sA + l15*528 + kf*64 + l4*16);
            s16x8 a1 = *(const s16x8*)(sA + (16 + l15)*528 + kf*64 + l4*16);
            #pragma unroll
            for (int g = 0; g < 4; ++g){
                acc[0][g] = MFMA16(a0, bfr[kf][g], acc[0][g]);
                acc[1][g] = MFMA16(a1, bfr[kf][g], acc[1][g]);
            }
        }
        #pragma unroll
        for (int rf = 0; rf < 2; ++rf)
            #pragma unroll
            for (int r = 0; r < 4; ++r){
                int rl = rf*16 + l4*4 + r;
                float rr = sigmoidf_(acc[rf][0][r] + rb);
                float zz = sigmoidf_(acc[rf][1][r] + zb);
                float iv = acc[rf][2][r] + ib;
                float hv = acc[rf][3][r] + hb;
                float nc = tanhf_(iv + rr*hv);
                float xej = bf16f(*(const u16*)(sA + rl*528 + 256 + 2*j));
                float v = (1.f - zz)*nc + zz*xej;
                v = fmaxf(v, 0.f);
                out[((size_t)tile*32 + rl)*128 + j] = v;
                float s1 = v, s2 = v*v;
                #pragma unroll
                for (int o = 1; o < 16; o <<= 1){ s1 += __shfl_xor(s1, o); s2 += __shfl_xor(s2, o); }
                if (l15 == 0){ atomicAdd(&sst[rl][0], s1); atomicAdd(&sst[rl][1], s2); }
            }
        __syncthreads();
        if (t < 32){
            size_t n = (size_t)tile*32 + t;
            stats[n] = sst[t][0];
            stats[N + n] = sst[t][1];
        }
        __syncthreads();
    }
}

// ---------------- K6: LayerNorm (no affine), in-place safe ----------------
__global__ void k_ln(const float* __restrict__ xnew, const float* __restrict__ stats,
                     float* __restrict__ out, int total, int N)
{
    int i4 = blockIdx.x*256 + threadIdx.x;
    if (i4*4 >= total) return;
    float4 v = ((const float4*)xnew)[i4];
    int n = (i4*4) >> 7;
    float mu  = stats[n] * (1.f/128.f);
    float var = stats[N + n] * (1.f/128.f) - mu*mu;
    var = fmaxf(var, 0.f);
    float rsd = rsqrtf(var + 1e-5f);
    float4 o;
    o.x = (v.x - mu)*rsd; o.y = (v.y - mu)*rsd;
    o.z = (v.z - mu)*rsd; o.w = (v.w - mu)*rsd;
    ((float4*)out)[i4] = o;
}

// ---------------- host ----------------
extern "C" void kernel_launch(void* const* d_in, const int* in_sizes, int n_in,
                              void* d_out, int out_size, void* d_ws, size_t ws_size,
                              hipStream_t stream)
{
    const float* x       = (const float*)d_in[0];
    const float* ea      = (const float*)d_in[1];
    const float* W_enter = (const float*)d_in[2];
    const float* b_enter = (const float*)d_in[3];
    const float* W1      = (const float*)d_in[4];
    const float* att_l   = (const float*)d_in[5];
    const float* att_r   = (const float*)d_in[6];
    const float* W2      = (const float*)d_in[7];
    const float* b_conv  = (const float*)d_in[8];
    const float* W_ih    = (const float*)d_in[9];
    const float* W_hh    = (const float*)d_in[10];
    const float* b_ih    = (const float*)d_in[11];
    const float* b_hh    = (const float*)d_in[12];
    const int*   eidx    = (const int*)d_in[13];

    int N = in_sizes[0] / DIN;
    int E = in_sizes[13] / 2;
    const int* src = eidx;
    const int* dst = eidx + E;
    float* out = (float*)d_out;

    size_t off = 0;
    char* base = (char*)d_ws;
    auto alloc = [&](size_t bytes) -> char* {
        char* p = base + off;
        off = (off + bytes + 255) & ~(size_t)255;
        return p;
    };
    u16*   Ag    = (u16*)  alloc((size_t)N*256*2);   // [h | xe] bf16
    float* r_dst = (float*)alloc((size_t)N*4);
    float* alpha = (float*)alloc((size_t)E*4);
    int*   deg   = (int*)  alloc((size_t)N*4);
    int*   rs    = (int*)  alloc((size_t)(N+1)*4);
    int*   cnt   = (int*)  alloc((size_t)N*4);
    int*   esort = (int*)  alloc((size_t)E*4);
    float* stats = (float*)alloc((size_t)N*2*4);
    int*   btot  = (int*)  alloc(1024);
    int*   bbase = (int*)  alloc(1024);
    u16*   W1b   = (u16*)  alloc(20480*2);
    u16*   W2b   = (u16*)  alloc(16384*2);
    u16*   Wentb = (u16*)  alloc(8192*2);
    u16*   Bg    = (u16*)  alloc(131072*2);

    size_t m_bf16_bytes = (size_t)E*HD*2;
    bool   big = (ws_size - off) >= m_bf16_bytes;
    void*  mbuf = (void*)(base + off);
    float* a_agg = out;   // d_out reused (dead before k_gru writes)
    float* xnew  = out;

    int ntiles_n64 = N/64, ntiles_e = (E + 63)/64, ntiles_g = N/32;

    k_prep   <<<(176128+255)/256, 256, 0, stream>>>(W1, W2, W_enter, W_ih, W_hh, W1b, W2b, Wentb, Bg);
    k_zero2  <<<(N+255)/256, 256, 0, stream>>>(deg, cnt, N);
    k_enter_mfma<<<ntiles_n64, 256, 0, stream>>>(x, Wentb, b_enter, att_r, Ag, r_dst, N);
    k_hist   <<<(E+255)/256, 256, 0, stream>>>(dst, deg, E);
    k_scan_a <<<N/1024, 256, 0, stream>>>(deg, rs, btot, N);
    k_scan_b <<<1, 256, 0, stream>>>(btot, bbase);
    k_scan_c <<<(N+255)/256, 256, 0, stream>>>(rs, bbase, N, E);
    if (big){
        k_edge_mfma<u16><<<4096, 256, 0, stream>>>(Ag, ea, W1b, att_l, r_dst, src, dst,
                                                   (u16*)mbuf, alpha, ntiles_e, E);
    } else {
        k_edge_mfma<u8> <<<4096, 256, 0, stream>>>(Ag, ea, W1b, att_l, r_dst, src, dst,
                                                   (u8*)mbuf, alpha, ntiles_e, E);
    }
    k_scatter<<<(E+255)/256, 256, 0, stream>>>(dst, rs, cnt, esort, E);
    if (big){
        k_agg<u16><<<(N+3)/4, 256, 0, stream>>>(rs, esort, alpha, (const u16*)mbuf, a_agg, N);
    } else {
        k_agg<u8> <<<(N+3)/4, 256, 0, stream>>>(rs, esort, alpha, (const u8*)mbuf, a_agg, N);
    }
    k_conv2_mfma<<<ntiles_n64, 256, 0, stream>>>(a_agg, W2b, b_conv, Ag, N);
    k_gru_mfma  <<<2048, 512, 0, stream>>>(Ag, Bg, b_ih, b_hh, xnew, stats, N, ntiles_g);
    k_ln     <<<((N*HD/4)+255)/256, 256, 0, stream>>>(xnew, stats, out, N*HD, N);
}

// Round 4
// 735.618 us; speedup vs baseline: 7.2304x; 1.2386x over previous
//
#include <hip/hip_runtime.h>
#include <stdint.h>

#define HD  128
#define DIN 64
#define DE  32

typedef unsigned int u32; typedef unsigned short u16; typedef unsigned char u8;
typedef short s16x8 __attribute__((ext_vector_type(8)));
typedef float f32x4 __attribute__((ext_vector_type(4)));

#define MFMA16(a,b,c) __builtin_amdgcn_mfma_f32_16x16x32_bf16((a),(b),(c),0,0,0)

__device__ __forceinline__ float lrelu(float x){ return x > 0.f ? x : 0.01f*x; }
__device__ __forceinline__ float sigmoidf_(float x){ return 1.f/(1.f + __expf(-x)); }
__device__ __forceinline__ float tanhf_(float x){
    float t = fminf(fmaxf(x, -15.f), 15.f);
    float e = __expf(2.f*t);
    return (e - 1.f)/(e + 1.f);
}
__device__ __forceinline__ float eluf_(float x){ return x > 0.f ? x : expm1f(x); }

__device__ __forceinline__ u16 f32_to_bf16(float x){
    u32 u = __float_as_uint(x);
    u += 0x7FFFu + ((u >> 16) & 1u);
    return (u16)(u >> 16);
}
__device__ __forceinline__ float bf16lo(u32 u){ return __uint_as_float((u & 0xFFFFu) << 16); }
__device__ __forceinline__ float bf16hi(u32 u){ return __uint_as_float(u & 0xFFFF0000u); }
__device__ __forceinline__ float bf16f(u16 h){ return __uint_as_float(((u32)h) << 16); }
__device__ __forceinline__ u32 pk2(float a, float b){
    return (u32)f32_to_bf16(a) | ((u32)f32_to_bf16(b) << 16);
}
// custom e4m3, exponent bias 13: normals in [2^-12, 7.5]
__device__ __forceinline__ u8 f32_to_f8(float x){
    u32 u = __float_as_uint(x);
    u32 s = (u >> 24) & 0x80u;
    u &= 0x7FFFFFFFu;
    u += 0x0007FFFFu + ((u >> 20) & 1u);
    int e = (int)(u >> 23) - 114;
    if (e <= 0)  return (u8)s;
    if (e > 15)  return (u8)(s | 0x7F);
    return (u8)(s | ((u32)e << 3) | ((u >> 20) & 7u));
}
__device__ __forceinline__ float f8_to_f32(u32 b){
    u32 e = (b >> 3) & 0xFu;
    u32 u = ((b & 0x80u) << 24) | ((e + 114u) << 23) | ((b & 7u) << 20);
    float f = __uint_as_float(u);
    return e ? f : 0.f;
}

template<typename MT> struct MC;
template<> struct MC<u16>{
    static __device__ __forceinline__ float2 load2(const u16* row, int lane){
        u32 u = *(const u32*)(row + 2*lane);
        float2 r; r.x = bf16lo(u); r.y = bf16hi(u);
        return r;
    }
};
template<> struct MC<u8>{
    static __device__ __forceinline__ float2 load2(const u8* row, int lane){
        u32 u = *(const u16*)(row + 2*lane);
        float2 r; r.x = f8_to_f32(u & 0xFFu); r.y = f8_to_f32((u >> 8) & 0xFFu);
        return r;
    }
};

__device__ __forceinline__ float wave_max(float v){
    #pragma unroll
    for (int o = 32; o > 0; o >>= 1) v = fmaxf(v, __shfl_xor(v, o, 64));
    return v;
}
__device__ __forceinline__ float wave_sum(float v){
    #pragma unroll
    for (int o = 32; o > 0; o >>= 1) v += __shfl_xor(v, o, 64);
    return v;
}
__device__ __forceinline__ float dot8_bf16(uint4 v, const float* __restrict__ al){
    float d = 0.f;
    d = fmaf(bf16lo(v.x), al[0], d); d = fmaf(bf16hi(v.x), al[1], d);
    d = fmaf(bf16lo(v.y), al[2], d); d = fmaf(bf16hi(v.y), al[3], d);
    d = fmaf(bf16lo(v.z), al[4], d); d = fmaf(bf16hi(v.z), al[5], d);
    d = fmaf(bf16lo(v.w), al[6], d); d = fmaf(bf16hi(v.w), al[7], d);
    return d;
}
__device__ __forceinline__ float dot16_f8(uint4 v, const float* __restrict__ al){
    float d = 0.f;
    u32 ws[4] = {v.x, v.y, v.z, v.w};
    #pragma unroll
    for (int i = 0; i < 4; ++i){
        #pragma unroll
        for (int b = 0; b < 4; ++b)
            d = fmaf(f8_to_f32((ws[i] >> (8*b)) & 0xFFu), al[4*i + b], d);
    }
    return d;
}

// ---------------- weight prep: fp32 -> bf16 (+ GRU B-pack) ----------------
__global__ void k_prep(const float* __restrict__ W1, const float* __restrict__ W2,
                       const float* __restrict__ Went,
                       const float* __restrict__ Wih, const float* __restrict__ Whh,
                       u16* __restrict__ W1b, u16* __restrict__ W2b,
                       u16* __restrict__ Wentb, u16* __restrict__ Bg)
{
    int i = blockIdx.x*256 + threadIdx.x;
    if (i < 20480){ W1b[i] = f32_to_bf16(W1[i]); return; }
    i -= 20480;
    if (i < 16384){ W2b[i] = f32_to_bf16(W2[i]); return; }
    i -= 16384;
    if (i < 8192){ Wentb[i] = f32_to_bf16(Went[i]); return; }
    i -= 8192;
    if (i < 131072){
        int col = i >> 8, k = i & 255;
        int g = col >> 7, j = col & 127;
        float v;
        if      (g == 0) v = (k < 128) ? Wih[j*128 + k]        : Whh[j*128 + k - 128];
        else if (g == 1) v = (k < 128) ? Wih[(128+j)*128 + k]  : Whh[(128+j)*128 + k - 128];
        else if (g == 2) v = (k < 128) ? Wih[(256+j)*128 + k]  : 0.f;
        else             v = (k < 128) ? 0.f                   : Whh[(256+j)*128 + k - 128];
        Bg[i] = f32_to_bf16(v);
    }
}

// ---------------- init ----------------
__global__ void k_zero2(int* __restrict__ a, int* __restrict__ b, int n){
    int i = blockIdx.x*256 + threadIdx.x;
    if (i < n){ a[i] = 0; b[i] = 0; }
}

// ---------------- K1 (MFMA): xe-half of Ag = bf16(lrelu(x@W^T+b)); r_dst = xe·att_r ----------------
__global__ __launch_bounds__(256, 2) void k_enter_mfma(
    const float* __restrict__ x, const u16* __restrict__ Wb, const float* __restrict__ be,
    const float* __restrict__ att_r, u16* __restrict__ Ag, float* __restrict__ r_out, int N)
{
    __shared__ __align__(16) u8 sA[64*144];
    __shared__ __align__(16) u8 sO[64*272];
    int t = threadIdx.x, w = t >> 6, lane = t & 63, l15 = lane & 15, l4 = lane >> 4;
    int tile = blockIdx.x;

    s16x8 bfr[2][2];
    #pragma unroll
    for (int kf = 0; kf < 2; ++kf)
        #pragma unroll
        for (int cf = 0; cf < 2; ++cf)
            bfr[kf][cf] = *(const s16x8*)(Wb + (size_t)(w*32 + cf*16 + l15)*64 + kf*32 + l4*8);

    int el = t >> 2, q = t & 3;
    size_t n = (size_t)tile*64 + el;
    {
        const float4* xs = (const float4*)(x + n*64 + q*16);
        float4 f0 = xs[0], f1 = xs[1], f2 = xs[2], f3 = xs[3];
        uint4 o0, o1;
        o0.x = pk2(f0.x,f0.y); o0.y = pk2(f0.z,f0.w); o0.z = pk2(f1.x,f1.y); o0.w = pk2(f1.z,f1.w);
        o1.x = pk2(f2.x,f2.y); o1.y = pk2(f2.z,f2.w); o1.z = pk2(f3.x,f3.y); o1.w = pk2(f3.z,f3.w);
        *(uint4*)(sA + el*144 + q*32)      = o0;
        *(uint4*)(sA + el*144 + q*32 + 16) = o1;
    }
    __syncthreads();

    f32x4 acc[4][2];
    #pragma unroll
    for (int rf = 0; rf < 4; ++rf){ acc[rf][0] = (f32x4)0.f; acc[rf][1] = (f32x4)0.f; }
    #pragma unroll
    for (int kf = 0; kf < 2; ++kf){
        s16x8 a[4];
        #pragma unroll
        for (int rf = 0; rf < 4; ++rf)
            a[rf] = *(const s16x8*)(sA + (rf*16 + l15)*144 + kf*64 + l4*16);
        #pragma unroll
        for (int rf = 0; rf < 4; ++rf){
            acc[rf][0] = MFMA16(a[rf], bfr[kf][0], acc[rf][0]);
            acc[rf][1] = MFMA16(a[rf], bfr[kf][1], acc[rf][1]);
        }
    }
    float b0 = be[w*32 + l15], b1 = be[w*32 + 16 + l15];
    #pragma unroll
    for (int rf = 0; rf < 4; ++rf)
        #pragma unroll
        for (int r = 0; r < 4; ++r){
            int row = rf*16 + l4*4 + r;
            *(u16*)(sO + row*272 + (w*32 + l15)*2)      = f32_to_bf16(lrelu(acc[rf][0][r] + b0));
            *(u16*)(sO + row*272 + (w*32 + 16 + l15)*2) = f32_to_bf16(lrelu(acc[rf][1][r] + b1));
        }
    __syncthreads();

    float dot = 0.f;
    #pragma unroll
    for (int i = 0; i < 4; ++i){
        uint4 v = *(const uint4*)(sO + el*272 + q*64 + 16*i);
        ((uint4*)Ag)[n*32 + 16 + q*4 + i] = v;         // xe half: byte n*512+256
        dot += dot8_bf16(v, att_r + q*32 + 8*i);
    }
    dot += __shfl_xor(dot, 1); dot += __shfl_xor(dot, 2);
    if (q == 0) r_out[n] = dot;
}

// ---------------- CSR build ----------------
__global__ void k_hist(const int* __restrict__ dst, int* __restrict__ deg, int E){
    int e = blockIdx.x*256 + threadIdx.x;
    if (e < E) atomicAdd(&deg[dst[e]], 1);
}
__global__ __launch_bounds__(256) void k_scan_a(
    const int* __restrict__ deg, int* __restrict__ rs, int* __restrict__ btot, int N)
{
    __shared__ int sd[256];
    int b = blockIdx.x, t = threadIdx.x;
    int base = b*1024 + t*4;
    int d0 = deg[base], d1 = deg[base+1], d2 = deg[base+2], d3 = deg[base+3];
    int s = d0 + d1 + d2 + d3;
    sd[t] = s; __syncthreads();
    for (int o = 1; o < 256; o <<= 1){
        int v = (t >= o) ? sd[t-o] : 0;
        __syncthreads();
        sd[t] += v;
        __syncthreads();
    }
    int ex = sd[t] - s;
    rs[base]   = ex;
    rs[base+1] = ex + d0;
    rs[base+2] = ex + d0 + d1;
    rs[base+3] = ex + d0 + d1 + d2;
    if (t == 0) btot[b] = sd[255];
}
__global__ __launch_bounds__(256) void k_scan_b(const int* __restrict__ btot, int* __restrict__ bbase){
    __shared__ int sd[256];
    int t = threadIdx.x;
    int s = btot[t];
    sd[t] = s; __syncthreads();
    for (int o = 1; o < 256; o <<= 1){
        int v = (t >= o) ? sd[t-o] : 0;
        __syncthreads();
        sd[t] += v;
        __syncthreads();
    }
    bbase[t] = sd[t] - s;
}
__global__ void k_scan_c(int* __restrict__ rs, const int* __restrict__ bbase, int N, int E){
    int i = blockIdx.x*256 + threadIdx.x;
    if (i < N) rs[i] += bbase[i >> 10];
    if (i == 0) rs[N] = E;
}
__global__ void k_scatter(const int* __restrict__ dst, const int* __restrict__ rs,
                          int* __restrict__ cnt, int* __restrict__ epos, int E){
    int e = blockIdx.x*256 + threadIdx.x;
    if (e >= E) return;
    int d = dst[e];
    int pos = rs[d] + atomicAdd(&cnt[d], 1);
    epos[e] = pos;
}

// ---------------- K2 (MFMA): m_s[epos[e]] = lrelu(W1@[xe[src],ea]); alpha_s[epos[e]] ----------------
template<typename MT>
__global__ __launch_bounds__(256, 2) void k_edge_mfma(
    const u16* __restrict__ Ag, const float* __restrict__ ea,
    const u16* __restrict__ W1b, const float* __restrict__ att_l,
    const float* __restrict__ r_dst, const int* __restrict__ src, const int* __restrict__ dst,
    const int* __restrict__ epos,
    MT* __restrict__ m, float* __restrict__ alpha, int ntiles, int E)
{
    __shared__ __align__(16) u8 sA[64*336];
    __shared__ __align__(16) u8 sM[64*272];
    int t = threadIdx.x, w = t >> 6, lane = t & 63, l15 = lane & 15, l4 = lane >> 4;
    constexpr int MS = (sizeof(MT) == 2) ? 272 : 144;

    s16x8 bfr[5][2];
    #pragma unroll
    for (int kf = 0; kf < 5; ++kf)
        #pragma unroll
        for (int cf = 0; cf < 2; ++cf)
            bfr[kf][cf] = *(const s16x8*)(W1b + (size_t)(w*32 + cf*16 + l15)*160 + kf*32 + l4*8);

    int el = t >> 2, q = t & 3;
    for (int tile = blockIdx.x; tile < ntiles; tile += gridDim.x){
        int e = tile*64 + el;
        if (e < E){
            int sn = src[e];
            const uint4* xs = (const uint4*)Ag + (size_t)sn*32 + 16 + q*4;
            uint4 v0 = xs[0], v1 = xs[1], v2 = xs[2], v3 = xs[3];
            uint4* d = (uint4*)(sA + el*336 + q*64);
            d[0] = v0; d[1] = v1; d[2] = v2; d[3] = v3;
            const float4* ef = (const float4*)(ea + (size_t)e*32 + q*8);
            float4 f0 = ef[0], f1 = ef[1];
            uint4 o;
            o.x = pk2(f0.x,f0.y); o.y = pk2(f0.z,f0.w); o.z = pk2(f1.x,f1.y); o.w = pk2(f1.z,f1.w);
            *(uint4*)(sA + el*336 + 256 + q*16) = o;
        }
        __syncthreads();

        f32x4 acc[4][2];
        #pragma unroll
        for (int rf = 0; rf < 4; ++rf){ acc[rf][0] = (f32x4)0.f; acc[rf][1] = (f32x4)0.f; }
        #pragma unroll
        for (int kf = 0; kf < 5; ++kf){
            s16x8 a[4];
            #pragma unroll
            for (int rf = 0; rf < 4; ++rf)
                a[rf] = *(const s16x8*)(sA + (rf*16 + l15)*336 + kf*64 + l4*16);
            #pragma unroll
            for (int rf = 0; rf < 4; ++rf){
                acc[rf][0] = MFMA16(a[rf], bfr[kf][0], acc[rf][0]);
                acc[rf][1] = MFMA16(a[rf], bfr[kf][1], acc[rf][1]);
            }
        }
        #pragma unroll
        for (int rf = 0; rf < 4; ++rf)
            #pragma unroll
            for (int cf = 0; cf < 2; ++cf)
                #pragma unroll
                for (int r = 0; r < 4; ++r){
                    int row = rf*16 + l4*4 + r;
                    int col = w*32 + cf*16 + l15;
                    float vv = lrelu(acc[rf][cf][r]);
                    if (sizeof(MT) == 2) *(u16*)(sM + row*MS + col*2) = f32_to_bf16(vv);
                    else                 sM[row*MS + col] = f32_to_f8(vv);
                }
        __syncthreads();

        if (e < E){
            int p = epos[e];
            float dot = 0.f;
            if (sizeof(MT) == 2){
                #pragma unroll
                for (int i = 0; i < 4; ++i){
                    uint4 v = *(const uint4*)(sM + el*272 + q*64 + 16*i);
                    dot += dot8_bf16(v, att_l + q*32 + 8*i);
                    ((uint4*)m)[(size_t)p*16 + q*4 + i] = v;
                }
            } else {
                #pragma unroll
                for (int i = 0; i < 2; ++i){
                    uint4 v = *(const uint4*)(sM + el*144 + q*32 + 16*i);
                    dot += dot16_f8(v, att_l + q*32 + 16*i);
                    ((uint4*)m)[(size_t)p*8 + q*2 + i] = v;
                }
            }
            dot += __shfl_xor(dot, 1); dot += __shfl_xor(dot, 2);
            if (q == 0) alpha[p] = lrelu(dot + r_dst[dst[e]]);
        }
        __syncthreads();
    }
}

// ---------------- K4: streaming segment softmax + weighted sum (CSR-sorted m) ----------------
template<typename MT>
__global__ __launch_bounds__(256) void k_agg(
    const int* __restrict__ rs,
    const float* __restrict__ alpha, const MT* __restrict__ m,
    float* __restrict__ a_out, int N)
{
    int wid  = (blockIdx.x*256 + threadIdx.x) >> 6;
    int lane = threadIdx.x & 63;
    if (wid >= N) return;
    int s = rs[wid], t = rs[wid+1];
    int deg = t - s;
    float ax = 0.f, ay = 0.f;
    if (deg > 0 && deg <= 64){
        float av = -1e38f;
        if (lane < deg) av = alpha[s + lane];
        float mx = wave_max(av);
        float ev = (lane < deg) ? __expf(av - mx) : 0.f;
        float ssum = wave_sum(ev);
        float wreg = ev / ssum;
        int k = 0;
        for (; k + 2 <= deg; k += 2){
            float w0 = __shfl(wreg, k);
            float w1 = __shfl(wreg, k + 1);
            float2 m0 = MC<MT>::load2(m + (size_t)(s + k)*HD, lane);
            float2 m1 = MC<MT>::load2(m + (size_t)(s + k + 1)*HD, lane);
            ax = fmaf(w0, m0.x, ax); ay = fmaf(w0, m0.y, ay);
            ax = fmaf(w1, m1.x, ax); ay = fmaf(w1, m1.y, ay);
        }
        if (k < deg){
            float w0 = __shfl(wreg, k);
            float2 m0 = MC<MT>::load2(m + (size_t)(s + k)*HD, lane);
            ax = fmaf(w0, m0.x, ax); ay = fmaf(w0, m0.y, ay);
        }
    } else if (deg > 64){
        float mx = -1e38f;
        for (int k = lane; k < deg; k += 64) mx = fmaxf(mx, alpha[s + k]);
        mx = wave_max(mx);
        float ssum = 0.f;
        for (int k = lane; k < deg; k += 64) ssum += __expf(alpha[s + k] - mx);
        ssum = wave_sum(ssum);
        float inv = 1.f / ssum;
        for (int k = 0; k < deg; ++k){
            float wgt = __expf(alpha[s + k] - mx) * inv;
            float2 mv = MC<MT>::load2(m + (size_t)(s + k)*HD, lane);
            ax = fmaf(wgt, mv.x, ax);
            ay = fmaf(wgt, mv.y, ay);
        }
    }
    float2 o; o.x = ax; o.y = ay;
    *(float2*)(a_out + (size_t)wid*HD + 2*lane) = o;
}

// ---------------- K5a (MFMA): h-half of Ag = bf16(elu(W2@a + bc)) ----------------
__global__ __launch_bounds__(256, 2) void k_conv2_mfma(
    const float* __restrict__ a, const u16* __restrict__ W2b, const float* __restrict__ bc,
    u16* __restrict__ Ag, int N)
{
    __shared__ __align__(16) u8 sA[64*272];
    __shared__ __align__(16) u8 sO[64*272];
    int t = threadIdx.x, w = t >> 6, lane = t & 63, l15 = lane & 15, l4 = lane >> 4;
    int tile = blockIdx.x;

    s16x8 bfr[4][2];
    #pragma unroll
    for (int kf = 0; kf < 4; ++kf)
        #pragma unroll
        for (int cf = 0; cf < 2; ++cf)
            bfr[kf][cf] = *(const s16x8*)(W2b + (size_t)(w*32 + cf*16 + l15)*128 + kf*32 + l4*8);

    int el = t >> 2, q = t & 3;
    size_t n = (size_t)tile*64 + el;
    {
        const float4* as = (const float4*)(a + n*128 + q*32);
        #pragma unroll
        for (int i = 0; i < 4; ++i){
            float4 f0 = as[2*i], f1 = as[2*i+1];
            uint4 o;
            o.x = pk2(f0.x,f0.y); o.y = pk2(f0.z,f0.w); o.z = pk2(f1.x,f1.y); o.w = pk2(f1.z,f1.w);
            *(uint4*)(sA + el*272 + q*64 + 16*i) = o;
        }
    }
    __syncthreads();

    f32x4 acc[4][2];
    #pragma unroll
    for (int rf = 0; rf < 4; ++rf){ acc[rf][0] = (f32x4)0.f; acc[rf][1] = (f32x4)0.f; }
    #pragma unroll
    for (int kf = 0; kf < 4; ++kf){
        s16x8 av[4];
        #pragma unroll
        for (int rf = 0; rf < 4; ++rf)
            av[rf] = *(const s16x8*)(sA + (rf*16 + l15)*272 + kf*64 + l4*16);
        #pragma unroll
        for (int rf = 0; rf < 4; ++rf){
            acc[rf][0] = MFMA16(av[rf], bfr[kf][0], acc[rf][0]);
            acc[rf][1] = MFMA16(av[rf], bfr[kf][1], acc[rf][1]);
        }
    }
    float b0 = bc[w*32 + l15], b1 = bc[w*32 + 16 + l15];
    #pragma unroll
    for (int rf = 0; rf < 4; ++rf)
        #pragma unroll
        for (int r = 0; r < 4; ++r){
            int row = rf*16 + l4*4 + r;
            *(u16*)(sO + row*272 + (w*32 + l15)*2)      = f32_to_bf16(eluf_(acc[rf][0][r] + b0));
            *(u16*)(sO + row*272 + (w*32 + 16 + l15)*2) = f32_to_bf16(eluf_(acc[rf][1][r] + b1));
        }
    __syncthreads();
    #pragma unroll
    for (int i = 0; i < 4; ++i){
        uint4 v = *(const uint4*)(sO + el*272 + q*64 + 16*i);
        ((uint4*)Ag)[n*32 + q*4 + i] = v;              // h half: byte n*512
    }
}

// ---------------- K5b (MFMA): GRU cell + fused LayerNorm -> out ----------------
__global__ __launch_bounds__(512, 2) void k_gru_mfma(
    const u16* __restrict__ Ag, const u16* __restrict__ Bg,
    const float* __restrict__ bih, const float* __restrict__ bhh,
    float* __restrict__ out, int N, int ntiles)
{
    __shared__ __align__(16) u8 sA[32*528];
    __shared__ __align__(16) float sOut[32*132];     // +4 pad breaks write conflicts
    int t = threadIdx.x, w = t >> 6, lane = t & 63, l15 = lane & 15, l4 = lane >> 4;

    s16x8 bfr[8][4];
    #pragma unroll
    for (int g = 0; g < 4; ++g){
        int col = g*128 + w*16 + l15;
        #pragma unroll
        for (int kf = 0; kf < 8; ++kf)
            bfr[kf][g] = *(const s16x8*)(Bg + (size_t)col*256 + kf*32 + l4*8);
    }
    int j = w*16 + l15;
    float rb = bih[j] + bhh[j];
    float zb = bih[128 + j] + bhh[128 + j];
    float ib = bih[256 + j];
    float hb = bhh[256 + j];

    for (int tile = blockIdx.x; tile < ntiles; tile += gridDim.x){
        {
            int el = t >> 4, part = t & 15;
            const uint4* gsrc = (const uint4*)Ag + ((size_t)tile*32 + el)*32 + part*2;
            uint4 v0 = gsrc[0], v1 = gsrc[1];
            uint4* d = (uint4*)(sA + el*528 + part*32);
            d[0] = v0; d[1] = v1;
        }
        __syncthreads();

        f32x4 acc[2][4];
        #pragma unroll
        for (int rf = 0; rf < 2; ++rf)
            #pragma unroll
            for (int g = 0; g < 4; ++g) acc[rf][g] = (f32x4)0.f;
        #pragma unroll
        for (int kf = 0; kf < 8; ++kf){
            s16x8 a0 = *(const s16x8*)(sA + l15*528 + kf*64 + l4*16);
            s16x8 a1 = *(const s16x8*)(sA + (16 + l15)*528 + kf*64 + l4*16);
            #pragma unroll
            for (int g = 0; g < 4; ++g){
                acc[0][g] = MFMA16(a0, bfr[kf][g], acc[0][g]);
                acc[1][g] = MFMA16(a1, bfr[kf][g], acc[1][g]);
            }
        }
        #pragma unroll
        for (int rf = 0; rf < 2; ++rf)
            #pragma unroll
            for (int r = 0; r < 4; ++r){
                int rl = rf*16 + l4*4 + r;
                float rr = sigmoidf_(acc[rf][0][r] + rb);
                float zz = sigmoidf_(acc[rf][1][r] + zb);
                float iv = acc[rf][2][r] + ib;
                float hv = acc[rf][3][r] + hb;
                float nc = tanhf_(iv + rr*hv);
                float xej = bf16f(*(const u16*)(sA + rl*528 + 256 + 2*j));
                float v = (1.f - zz)*nc + zz*xej;
                v = fmaxf(v, 0.f);
                sOut[rl*132 + j] = v;
            }
        __syncthreads();
        {
            int row = t >> 4, sub = t & 15;          // 16 threads/row, same wave
            const float* rp = sOut + row*132 + sub*8;
            float v0 = rp[0], v1 = rp[1], v2 = rp[2], v3 = rp[3];
            float v4 = rp[4], v5 = rp[5], v6 = rp[6], v7 = rp[7];
            float s1 = v0+v1+v2+v3+v4+v5+v6+v7;
            float s2 = v0*v0+v1*v1+v2*v2+v3*v3+v4*v4+v5*v5+v6*v6+v7*v7;
            #pragma unroll
            for (int o = 1; o < 16; o <<= 1){ s1 += __shfl_xor(s1, o); s2 += __shfl_xor(s2, o); }
            float mu  = s1 * (1.f/128.f);
            float var = s2 * (1.f/128.f) - mu*mu;
            var = fmaxf(var, 0.f);
            float rsd = rsqrtf(var + 1e-5f);
            float* op = out + ((size_t)tile*32 + row)*128 + sub*8;
            float4 o0, o1;
            o0.x = (v0-mu)*rsd; o0.y = (v1-mu)*rsd; o0.z = (v2-mu)*rsd; o0.w = (v3-mu)*rsd;
            o1.x = (v4-mu)*rsd; o1.y = (v5-mu)*rsd; o1.z = (v6-mu)*rsd; o1.w = (v7-mu)*rsd;
            ((float4*)op)[0] = o0; ((float4*)op)[1] = o1;
        }
        __syncthreads();
    }
}

// ---------------- host ----------------
extern "C" void kernel_launch(void* const* d_in, const int* in_sizes, int n_in,
                              void* d_out, int out_size, void* d_ws, size_t ws_size,
                              hipStream_t stream)
{
    const float* x       = (const float*)d_in[0];
    const float* ea      = (const float*)d_in[1];
    const float* W_enter = (const float*)d_in[2];
    const float* b_enter = (const float*)d_in[3];
    const float* W1      = (const float*)d_in[4];
    const float* att_l   = (const float*)d_in[5];
    const float* att_r   = (const float*)d_in[6];
    const float* W2      = (const float*)d_in[7];
    const float* b_conv  = (const float*)d_in[8];
    const float* W_ih    = (const float*)d_in[9];
    const float* W_hh    = (const float*)d_in[10];
    const float* b_ih    = (const float*)d_in[11];
    const float* b_hh    = (const float*)d_in[12];
    const int*   eidx    = (const int*)d_in[13];

    int N = in_sizes[0] / DIN;
    int E = in_sizes[13] / 2;
    const int* src = eidx;
    const int* dst = eidx + E;
    float* out = (float*)d_out;

    size_t off = 0;
    char* base = (char*)d_ws;
    auto alloc = [&](size_t bytes) -> char* {
        char* p = base + off;
        off = (off + bytes + 255) & ~(size_t)255;
        return p;
    };
    u16*   Ag    = (u16*)  alloc((size_t)N*256*2);   // [h | xe] bf16
    float* r_dst = (float*)alloc((size_t)N*4);
    float* alpha = (float*)alloc((size_t)E*4);
    int*   deg   = (int*)  alloc((size_t)N*4);
    int*   rs    = (int*)  alloc((size_t)(N+1)*4);
    int*   cnt   = (int*)  alloc((size_t)N*4);
    int*   epos  = (int*)  alloc((size_t)E*4);
    int*   btot  = (int*)  alloc(1024);
    int*   bbase = (int*)  alloc(1024);
    u16*   W1b   = (u16*)  alloc(20480*2);
    u16*   W2b   = (u16*)  alloc(16384*2);
    u16*   Wentb = (u16*)  alloc(8192*2);
    u16*   Bg    = (u16*)  alloc(131072*2);

    size_t m_bf16_bytes = (size_t)E*HD*2;
    bool   big = (ws_size - off) >= m_bf16_bytes;
    void*  mbuf = (void*)(base + off);
    float* a_agg = out;   // d_out reused (dead before k_gru writes)

    int ntiles_n64 = N/64, ntiles_e = (E + 63)/64, ntiles_g = N/32;

    k_prep   <<<(176128+255)/256, 256, 0, stream>>>(W1, W2, W_enter, W_ih, W_hh, W1b, W2b, Wentb, Bg);
    k_zero2  <<<(N+255)/256, 256, 0, stream>>>(deg, cnt, N);
    k_enter_mfma<<<ntiles_n64, 256, 0, stream>>>(x, Wentb, b_enter, att_r, Ag, r_dst, N);
    k_hist   <<<(E+255)/256, 256, 0, stream>>>(dst, deg, E);
    k_scan_a <<<N/1024, 256, 0, stream>>>(deg, rs, btot, N);
    k_scan_b <<<1, 256, 0, stream>>>(btot, bbase);
    k_scan_c <<<(N+255)/256, 256, 0, stream>>>(rs, bbase, N, E);
    k_scatter<<<(E+255)/256, 256, 0, stream>>>(dst, rs, cnt, epos, E);
    if (big){
        k_edge_mfma<u16><<<4096, 256, 0, stream>>>(Ag, ea, W1b, att_l, r_dst, src, dst, epos,
                                                   (u16*)mbuf, alpha, ntiles_e, E);
    } else {
        k_edge_mfma<u8> <<<4096, 256, 0, stream>>>(Ag, ea, W1b, att_l, r_dst, src, dst, epos,
                                                   (u8*)mbuf, alpha, ntiles_e, E);
    }
    if (big){
        k_agg<u16><<<(N+3)/4, 256, 0, stream>>>(rs, alpha, (const u16*)mbuf, a_agg, N);
    } else {
        k_agg<u8> <<<(N+3)/4, 256, 0, stream>>>(rs, alpha, (const u8*)mbuf, a_agg, N);
    }
    k_conv2_mfma<<<ntiles_n64, 256, 0, stream>>>(a_agg, W2b, b_conv, Ag, N);
    k_gru_mfma  <<<2048, 512, 0, stream>>>(Ag, Bg, b_ih, b_hh, out, N, ntiles_g);
}

// Round 5
// 729.813 us; speedup vs baseline: 7.2879x; 1.0080x over previous
//
#include <hip/hip_runtime.h>
#include <stdint.h>

#define HD  128
#define DIN 64
#define DE  32

typedef unsigned int u32; typedef unsigned short u16; typedef unsigned char u8;
typedef short s16x8 __attribute__((ext_vector_type(8)));
typedef float f32x4 __attribute__((ext_vector_type(4)));

#define MFMA16(a,b,c) __builtin_amdgcn_mfma_f32_16x16x32_bf16((a),(b),(c),0,0,0)

__device__ __forceinline__ float lrelu(float x){ return x > 0.f ? x : 0.01f*x; }
__device__ __forceinline__ float sigmoidf_(float x){ return 1.f/(1.f + __expf(-x)); }
__device__ __forceinline__ float tanhf_(float x){
    float t = fminf(fmaxf(x, -15.f), 15.f);
    float e = __expf(2.f*t);
    return (e - 1.f)/(e + 1.f);
}
__device__ __forceinline__ float eluf_(float x){ return x > 0.f ? x : expm1f(x); }

__device__ __forceinline__ u16 f32_to_bf16(float x){
    u32 u = __float_as_uint(x);
    u += 0x7FFFu + ((u >> 16) & 1u);
    return (u16)(u >> 16);
}
__device__ __forceinline__ float bf16lo(u32 u){ return __uint_as_float((u & 0xFFFFu) << 16); }
__device__ __forceinline__ float bf16hi(u32 u){ return __uint_as_float(u & 0xFFFF0000u); }
__device__ __forceinline__ float bf16f(u16 h){ return __uint_as_float(((u32)h) << 16); }
__device__ __forceinline__ u32 pk2(float a, float b){
    return (u32)f32_to_bf16(a) | ((u32)f32_to_bf16(b) << 16);
}
// custom e4m3, exponent bias 13: normals in [2^-12, 7.5]
__device__ __forceinline__ u8 f32_to_f8(float x){
    u32 u = __float_as_uint(x);
    u32 s = (u >> 24) & 0x80u;
    u &= 0x7FFFFFFFu;
    u += 0x0007FFFFu + ((u >> 20) & 1u);
    int e = (int)(u >> 23) - 114;
    if (e <= 0)  return (u8)s;
    if (e > 15)  return (u8)(s | 0x7F);
    return (u8)(s | ((u32)e << 3) | ((u >> 20) & 7u));
}
__device__ __forceinline__ float f8_to_f32(u32 b){
    u32 e = (b >> 3) & 0xFu;
    u32 u = ((b & 0x80u) << 24) | ((e + 114u) << 23) | ((b & 7u) << 20);
    float f = __uint_as_float(u);
    return e ? f : 0.f;
}

template<typename MT> struct MC;
template<> struct MC<u16>{
    static __device__ __forceinline__ float2 load2(const u16* row, int lane){
        u32 u = *(const u32*)(row + 2*lane);
        float2 r; r.x = bf16lo(u); r.y = bf16hi(u);
        return r;
    }
};
template<> struct MC<u8>{
    static __device__ __forceinline__ float2 load2(const u8* row, int lane){
        u32 u = *(const u16*)(row + 2*lane);
        float2 r; r.x = f8_to_f32(u & 0xFFu); r.y = f8_to_f32((u >> 8) & 0xFFu);
        return r;
    }
};

__device__ __forceinline__ float wave_max(float v){
    #pragma unroll
    for (int o = 32; o > 0; o >>= 1) v = fmaxf(v, __shfl_xor(v, o, 64));
    return v;
}
__device__ __forceinline__ float wave_sum(float v){
    #pragma unroll
    for (int o = 32; o > 0; o >>= 1) v += __shfl_xor(v, o, 64);
    return v;
}
__device__ __forceinline__ float dot8_bf16(uint4 v, const float* __restrict__ al){
    float d = 0.f;
    d = fmaf(bf16lo(v.x), al[0], d); d = fmaf(bf16hi(v.x), al[1], d);
    d = fmaf(bf16lo(v.y), al[2], d); d = fmaf(bf16hi(v.y), al[3], d);
    d = fmaf(bf16lo(v.z), al[4], d); d = fmaf(bf16hi(v.z), al[5], d);
    d = fmaf(bf16lo(v.w), al[6], d); d = fmaf(bf16hi(v.w), al[7], d);
    return d;
}
__device__ __forceinline__ float dot16_f8(uint4 v, const float* __restrict__ al){
    float d = 0.f;
    u32 ws[4] = {v.x, v.y, v.z, v.w};
    #pragma unroll
    for (int i = 0; i < 4; ++i){
        #pragma unroll
        for (int b = 0; b < 4; ++b)
            d = fmaf(f8_to_f32((ws[i] >> (8*b)) & 0xFFu), al[4*i + b], d);
    }
    return d;
}

// ---------------- weight prep: fp32 -> bf16 (+ GRU B-pack) ----------------
__global__ void k_prep(const float* __restrict__ W1, const float* __restrict__ W2,
                       const float* __restrict__ Went,
                       const float* __restrict__ Wih, const float* __restrict__ Whh,
                       u16* __restrict__ W1b, u16* __restrict__ W2b,
                       u16* __restrict__ Wentb, u16* __restrict__ Bg)
{
    int i = blockIdx.x*256 + threadIdx.x;
    if (i < 20480){ W1b[i] = f32_to_bf16(W1[i]); return; }
    i -= 20480;
    if (i < 16384){ W2b[i] = f32_to_bf16(W2[i]); return; }
    i -= 16384;
    if (i < 8192){ Wentb[i] = f32_to_bf16(Went[i]); return; }
    i -= 8192;
    if (i < 131072){
        int col = i >> 8, k = i & 255;
        int g = col >> 7, j = col & 127;
        float v;
        if      (g == 0) v = (k < 128) ? Wih[j*128 + k]        : Whh[j*128 + k - 128];
        else if (g == 1) v = (k < 128) ? Wih[(128+j)*128 + k]  : Whh[(128+j)*128 + k - 128];
        else if (g == 2) v = (k < 128) ? Wih[(256+j)*128 + k]  : 0.f;
        else             v = (k < 128) ? 0.f                   : Whh[(256+j)*128 + k - 128];
        Bg[i] = f32_to_bf16(v);
    }
}

// ---------------- init ----------------
__global__ void k_zero2(int* __restrict__ a, int* __restrict__ b, int n){
    int i = blockIdx.x*256 + threadIdx.x;
    if (i < n){ a[i] = 0; b[i] = 0; }
}

// ---------------- K1 (MFMA): xe-half of Ag = bf16(lrelu(x@W^T+b)); r_dst = xe·att_r ----------------
__global__ __launch_bounds__(256, 2) void k_enter_mfma(
    const float* __restrict__ x, const u16* __restrict__ Wb, const float* __restrict__ be,
    const float* __restrict__ att_r, u16* __restrict__ Ag, float* __restrict__ r_out, int N)
{
    __shared__ __align__(16) u8 sA[64*144];
    __shared__ __align__(16) u8 sO[64*272];
    int t = threadIdx.x, w = t >> 6, lane = t & 63, l15 = lane & 15, l4 = lane >> 4;
    int tile = blockIdx.x;

    s16x8 bfr[2][2];
    #pragma unroll
    for (int kf = 0; kf < 2; ++kf)
        #pragma unroll
        for (int cf = 0; cf < 2; ++cf)
            bfr[kf][cf] = *(const s16x8*)(Wb + (size_t)(w*32 + cf*16 + l15)*64 + kf*32 + l4*8);

    int el = t >> 2, q = t & 3;
    size_t n = (size_t)tile*64 + el;
    {
        const float4* xs = (const float4*)(x + n*64 + q*16);
        float4 f0 = xs[0], f1 = xs[1], f2 = xs[2], f3 = xs[3];
        uint4 o0, o1;
        o0.x = pk2(f0.x,f0.y); o0.y = pk2(f0.z,f0.w); o0.z = pk2(f1.x,f1.y); o0.w = pk2(f1.z,f1.w);
        o1.x = pk2(f2.x,f2.y); o1.y = pk2(f2.z,f2.w); o1.z = pk2(f3.x,f3.y); o1.w = pk2(f3.z,f3.w);
        *(uint4*)(sA + el*144 + q*32)      = o0;
        *(uint4*)(sA + el*144 + q*32 + 16) = o1;
    }
    __syncthreads();

    f32x4 acc[4][2];
    #pragma unroll
    for (int rf = 0; rf < 4; ++rf){ acc[rf][0] = (f32x4)0.f; acc[rf][1] = (f32x4)0.f; }
    #pragma unroll
    for (int kf = 0; kf < 2; ++kf){
        s16x8 a[4];
        #pragma unroll
        for (int rf = 0; rf < 4; ++rf)
            a[rf] = *(const s16x8*)(sA + (rf*16 + l15)*144 + kf*64 + l4*16);
        #pragma unroll
        for (int rf = 0; rf < 4; ++rf){
            acc[rf][0] = MFMA16(a[rf], bfr[kf][0], acc[rf][0]);
            acc[rf][1] = MFMA16(a[rf], bfr[kf][1], acc[rf][1]);
        }
    }
    float b0 = be[w*32 + l15], b1 = be[w*32 + 16 + l15];
    #pragma unroll
    for (int rf = 0; rf < 4; ++rf)
        #pragma unroll
        for (int r = 0; r < 4; ++r){
            int row = rf*16 + l4*4 + r;
            *(u16*)(sO + row*272 + (w*32 + l15)*2)      = f32_to_bf16(lrelu(acc[rf][0][r] + b0));
            *(u16*)(sO + row*272 + (w*32 + 16 + l15)*2) = f32_to_bf16(lrelu(acc[rf][1][r] + b1));
        }
    __syncthreads();

    float dot = 0.f;
    #pragma unroll
    for (int i = 0; i < 4; ++i){
        uint4 v = *(const uint4*)(sO + el*272 + q*64 + 16*i);
        ((uint4*)Ag)[n*32 + 16 + q*4 + i] = v;         // xe half: byte n*512+256
        dot += dot8_bf16(v, att_r + q*32 + 8*i);
    }
    dot += __shfl_xor(dot, 1); dot += __shfl_xor(dot, 2);
    if (q == 0) r_out[n] = dot;
}

// ---------------- CSR build ----------------
__global__ void k_hist(const int* __restrict__ dst, int* __restrict__ deg, int E){
    int e = blockIdx.x*256 + threadIdx.x;
    if (e < E) atomicAdd(&deg[dst[e]], 1);
}
__global__ __launch_bounds__(256) void k_scan_a(
    const int* __restrict__ deg, int* __restrict__ rs, int* __restrict__ btot, int N)
{
    __shared__ int sd[256];
    int b = blockIdx.x, t = threadIdx.x;
    int base = b*1024 + t*4;
    int d0 = deg[base], d1 = deg[base+1], d2 = deg[base+2], d3 = deg[base+3];
    int s = d0 + d1 + d2 + d3;
    sd[t] = s; __syncthreads();
    for (int o = 1; o < 256; o <<= 1){
        int v = (t >= o) ? sd[t-o] : 0;
        __syncthreads();
        sd[t] += v;
        __syncthreads();
    }
    int ex = sd[t] - s;
    rs[base]   = ex;
    rs[base+1] = ex + d0;
    rs[base+2] = ex + d0 + d1;
    rs[base+3] = ex + d0 + d1 + d2;
    if (t == 0) btot[b] = sd[255];
}
__global__ __launch_bounds__(256) void k_scan_b(const int* __restrict__ btot, int* __restrict__ bbase){
    __shared__ int sd[256];
    int t = threadIdx.x;
    int s = btot[t];
    sd[t] = s; __syncthreads();
    for (int o = 1; o < 256; o <<= 1){
        int v = (t >= o) ? sd[t-o] : 0;
        __syncthreads();
        sd[t] += v;
        __syncthreads();
    }
    bbase[t] = sd[t] - s;
}
__global__ void k_scan_c(int* __restrict__ rs, const int* __restrict__ bbase, int N, int E){
    int i = blockIdx.x*256 + threadIdx.x;
    if (i < N) rs[i] += bbase[i >> 10];
    if (i == 0) rs[N] = E;
}
__global__ void k_scatter(const int* __restrict__ dst, const int* __restrict__ rs,
                          int* __restrict__ cnt, int* __restrict__ epos, int E){
    int e = blockIdx.x*256 + threadIdx.x;
    if (e >= E) return;
    int d = dst[e];
    int pos = rs[d] + atomicAdd(&cnt[d], 1);
    epos[e] = pos;
}

// ---------------- K2 (MFMA, persistent + prefetch): m_s[epos[e]], alpha_s[epos[e]] ----------------
template<typename MT>
__global__ __launch_bounds__(256, 3) void k_edge_mfma(
    const u16* __restrict__ Ag, const float* __restrict__ ea,
    const u16* __restrict__ W1b, const float* __restrict__ att_l,
    const float* __restrict__ r_dst, const int* __restrict__ src, const int* __restrict__ dst,
    const int* __restrict__ epos,
    MT* __restrict__ m, float* __restrict__ alpha, int ntiles, int E)
{
    __shared__ __align__(16) u8 sA[64*336];      // sM aliases sA (sA dead after MFMA reads)
    u8* sM = sA;
    int t = threadIdx.x, w = t >> 6, lane = t & 63, l15 = lane & 15, l4 = lane >> 4;
    constexpr int MS = (sizeof(MT) == 2) ? 272 : 144;

    s16x8 bfr[5][2];
    #pragma unroll
    for (int kf = 0; kf < 5; ++kf)
        #pragma unroll
        for (int cf = 0; cf < 2; ++cf)
            bfr[kf][cf] = *(const s16x8*)(W1b + (size_t)(w*32 + cf*16 + l15)*160 + kf*32 + l4*8);

    int el = t >> 2, q = t & 3;
    int stride = gridDim.x;
    int tile = blockIdx.x;

    uint4 cx0, cx1, cx2, cx3;      // prefetched xe[src[e]] chunk (64B/thread)
    float4 ce0, ce1;               // prefetched edge_attr chunk
    {
        int e = tile*64 + el;
        if (tile < ntiles && e < E){
            int sn = src[e];
            const uint4* xs = (const uint4*)Ag + (size_t)sn*32 + 16 + q*4;
            cx0 = xs[0]; cx1 = xs[1]; cx2 = xs[2]; cx3 = xs[3];
            const float4* ef = (const float4*)(ea + (size_t)e*32 + q*8);
            ce0 = ef[0]; ce1 = ef[1];
        }
    }

    for (; tile < ntiles; tile += stride){
        int e = tile*64 + el;
        if (e < E){
            uint4* d = (uint4*)(sA + el*336 + q*64);
            d[0] = cx0; d[1] = cx1; d[2] = cx2; d[3] = cx3;
            uint4 o;
            o.x = pk2(ce0.x,ce0.y); o.y = pk2(ce0.z,ce0.w);
            o.z = pk2(ce1.x,ce1.y); o.w = pk2(ce1.z,ce1.w);
            *(uint4*)(sA + el*336 + 256 + q*16) = o;
        }
        __syncthreads();

        // issue next tile's gather; latency hides under MFMA + epilogue
        int nt = tile + stride;
        if (nt < ntiles){
            int e2 = nt*64 + el;
            if (e2 < E){
                int sn = src[e2];
                const uint4* xs = (const uint4*)Ag + (size_t)sn*32 + 16 + q*4;
                cx0 = xs[0]; cx1 = xs[1]; cx2 = xs[2]; cx3 = xs[3];
                const float4* ef = (const float4*)(ea + (size_t)e2*32 + q*8);
                ce0 = ef[0]; ce1 = ef[1];
            }
        }

        f32x4 acc[4][2];
        #pragma unroll
        for (int rf = 0; rf < 4; ++rf){ acc[rf][0] = (f32x4)0.f; acc[rf][1] = (f32x4)0.f; }
        #pragma unroll
        for (int kf = 0; kf < 5; ++kf){
            s16x8 a[4];
            #pragma unroll
            for (int rf = 0; rf < 4; ++rf)
                a[rf] = *(const s16x8*)(sA + (rf*16 + l15)*336 + kf*64 + l4*16);
            #pragma unroll
            for (int rf = 0; rf < 4; ++rf){
                acc[rf][0] = MFMA16(a[rf], bfr[kf][0], acc[rf][0]);
                acc[rf][1] = MFMA16(a[rf], bfr[kf][1], acc[rf][1]);
            }
        }
        __syncthreads();   // all sA reads done before overwriting as sM

        #pragma unroll
        for (int rf = 0; rf < 4; ++rf)
            #pragma unroll
            for (int cf = 0; cf < 2; ++cf)
                #pragma unroll
                for (int r = 0; r < 4; ++r){
                    int row = rf*16 + l4*4 + r;
                    int col = w*32 + cf*16 + l15;
                    float vv = lrelu(acc[rf][cf][r]);
                    if (sizeof(MT) == 2) *(u16*)(sM + row*MS + col*2) = f32_to_bf16(vv);
                    else                 sM[row*MS + col] = f32_to_f8(vv);
                }
        __syncthreads();

        if (e < E){
            int p = epos[e];
            float dot = 0.f;
            if (sizeof(MT) == 2){
                #pragma unroll
                for (int i = 0; i < 4; ++i){
                    uint4 v = *(const uint4*)(sM + el*272 + q*64 + 16*i);
                    dot += dot8_bf16(v, att_l + q*32 + 8*i);
                    ((uint4*)m)[(size_t)p*16 + q*4 + i] = v;
                }
            } else {
                #pragma unroll
                for (int i = 0; i < 2; ++i){
                    uint4 v = *(const uint4*)(sM + el*144 + q*32 + 16*i);
                    dot += dot16_f8(v, att_l + q*32 + 16*i);
                    ((uint4*)m)[(size_t)p*8 + q*2 + i] = v;
                }
            }
            dot += __shfl_xor(dot, 1); dot += __shfl_xor(dot, 2);
            if (q == 0) alpha[p] = lrelu(dot + r_dst[dst[e]]);
        }
        __syncthreads();   // sM reads done before next iteration's sA write
    }
}

// ---------------- K4: streaming segment softmax + weighted sum (CSR-sorted m) ----------------
template<typename MT>
__global__ __launch_bounds__(256) void k_agg(
    const int* __restrict__ rs,
    const float* __restrict__ alpha, const MT* __restrict__ m,
    float* __restrict__ a_out, int N)
{
    int wid  = (blockIdx.x*256 + threadIdx.x) >> 6;
    int lane = threadIdx.x & 63;
    if (wid >= N) return;
    int s = rs[wid], t = rs[wid+1];
    int deg = t - s;
    float ax = 0.f, ay = 0.f;
    if (deg > 0 && deg <= 64){
        float av = -1e38f;
        if (lane < deg) av = alpha[s + lane];
        float mx = wave_max(av);
        float ev = (lane < deg) ? __expf(av - mx) : 0.f;
        float ssum = wave_sum(ev);
        float wreg = ev / ssum;
        int k = 0;
        for (; k + 2 <= deg; k += 2){
            float w0 = __shfl(wreg, k);
            float w1 = __shfl(wreg, k + 1);
            float2 m0 = MC<MT>::load2(m + (size_t)(s + k)*HD, lane);
            float2 m1 = MC<MT>::load2(m + (size_t)(s + k + 1)*HD, lane);
            ax = fmaf(w0, m0.x, ax); ay = fmaf(w0, m0.y, ay);
            ax = fmaf(w1, m1.x, ax); ay = fmaf(w1, m1.y, ay);
        }
        if (k < deg){
            float w0 = __shfl(wreg, k);
            float2 m0 = MC<MT>::load2(m + (size_t)(s + k)*HD, lane);
            ax = fmaf(w0, m0.x, ax); ay = fmaf(w0, m0.y, ay);
        }
    } else if (deg > 64){
        float mx = -1e38f;
        for (int k = lane; k < deg; k += 64) mx = fmaxf(mx, alpha[s + k]);
        mx = wave_max(mx);
        float ssum = 0.f;
        for (int k = lane; k < deg; k += 64) ssum += __expf(alpha[s + k] - mx);
        ssum = wave_sum(ssum);
        float inv = 1.f / ssum;
        for (int k = 0; k < deg; ++k){
            float wgt = __expf(alpha[s + k] - mx) * inv;
            float2 mv = MC<MT>::load2(m + (size_t)(s + k)*HD, lane);
            ax = fmaf(wgt, mv.x, ax);
            ay = fmaf(wgt, mv.y, ay);
        }
    }
    float2 o; o.x = ax; o.y = ay;
    *(float2*)(a_out + (size_t)wid*HD + 2*lane) = o;
}

// ---------------- K5a (MFMA): h-half of Ag = bf16(elu(W2@a + bc)) ----------------
__global__ __launch_bounds__(256, 2) void k_conv2_mfma(
    const float* __restrict__ a, const u16* __restrict__ W2b, const float* __restrict__ bc,
    u16* __restrict__ Ag, int N)
{
    __shared__ __align__(16) u8 sA[64*272];
    __shared__ __align__(16) u8 sO[64*272];
    int t = threadIdx.x, w = t >> 6, lane = t & 63, l15 = lane & 15, l4 = lane >> 4;
    int tile = blockIdx.x;

    s16x8 bfr[4][2];
    #pragma unroll
    for (int kf = 0; kf < 4; ++kf)
        #pragma unroll
        for (int cf = 0; cf < 2; ++cf)
            bfr[kf][cf] = *(const s16x8*)(W2b + (size_t)(w*32 + cf*16 + l15)*128 + kf*32 + l4*8);

    int el = t >> 2, q = t & 3;
    size_t n = (size_t)tile*64 + el;
    {
        const float4* as = (const float4*)(a + n*128 + q*32);
        #pragma unroll
        for (int i = 0; i < 4; ++i){
            float4 f0 = as[2*i], f1 = as[2*i+1];
            uint4 o;
            o.x = pk2(f0.x,f0.y); o.y = pk2(f0.z,f0.w); o.z = pk2(f1.x,f1.y); o.w = pk2(f1.z,f1.w);
            *(uint4*)(sA + el*272 + q*64 + 16*i) = o;
        }
    }
    __syncthreads();

    f32x4 acc[4][2];
    #pragma unroll
    for (int rf = 0; rf < 4; ++rf){ acc[rf][0] = (f32x4)0.f; acc[rf][1] = (f32x4)0.f; }
    #pragma unroll
    for (int kf = 0; kf < 4; ++kf){
        s16x8 av[4];
        #pragma unroll
        for (int rf = 0; rf < 4; ++rf)
            av[rf] = *(const s16x8*)(sA + (rf*16 + l15)*272 + kf*64 + l4*16);
        #pragma unroll
        for (int rf = 0; rf < 4; ++rf){
            acc[rf][0] = MFMA16(av[rf], bfr[kf][0], acc[rf][0]);
            acc[rf][1] = MFMA16(av[rf], bfr[kf][1], acc[rf][1]);
        }
    }
    float b0 = bc[w*32 + l15], b1 = bc[w*32 + 16 + l15];
    #pragma unroll
    for (int rf = 0; rf < 4; ++rf)
        #pragma unroll
        for (int r = 0; r < 4; ++r){
            int row = rf*16 + l4*4 + r;
            *(u16*)(sO + row*272 + (w*32 + l15)*2)      = f32_to_bf16(eluf_(acc[rf][0][r] + b0));
            *(u16*)(sO + row*272 + (w*32 + 16 + l15)*2) = f32_to_bf16(eluf_(acc[rf][1][r] + b1));
        }
    __syncthreads();
    #pragma unroll
    for (int i = 0; i < 4; ++i){
        uint4 v = *(const uint4*)(sO + el*272 + q*64 + 16*i);
        ((uint4*)Ag)[n*32 + q*4 + i] = v;              // h half: byte n*512
    }
}

// ---------------- K5b (MFMA): GRU cell + fused LayerNorm -> out ----------------
__global__ __launch_bounds__(512, 2) void k_gru_mfma(
    const u16* __restrict__ Ag, const u16* __restrict__ Bg,
    const float* __restrict__ bih, const float* __restrict__ bhh,
    float* __restrict__ out, int N, int ntiles)
{
    __shared__ __align__(16) u8 sA[32*528];
    __shared__ __align__(16) float sOut[32*132];     // +4 pad breaks write conflicts
    int t = threadIdx.x, w = t >> 6, lane = t & 63, l15 = lane & 15, l4 = lane >> 4;

    s16x8 bfr[8][4];
    #pragma unroll
    for (int g = 0; g < 4; ++g){
        int col = g*128 + w*16 + l15;
        #pragma unroll
        for (int kf = 0; kf < 8; ++kf)
            bfr[kf][g] = *(const s16x8*)(Bg + (size_t)col*256 + kf*32 + l4*8);
    }
    int j = w*16 + l15;
    float rb = bih[j] + bhh[j];
    float zb = bih[128 + j] + bhh[128 + j];
    float ib = bih[256 + j];
    float hb = bhh[256 + j];

    for (int tile = blockIdx.x; tile < ntiles; tile += gridDim.x){
        {
            int el = t >> 4, part = t & 15;
            const uint4* gsrc = (const uint4*)Ag + ((size_t)tile*32 + el)*32 + part*2;
            uint4 v0 = gsrc[0], v1 = gsrc[1];
            uint4* d = (uint4*)(sA + el*528 + part*32);
            d[0] = v0; d[1] = v1;
        }
        __syncthreads();

        f32x4 acc[2][4];
        #pragma unroll
        for (int rf = 0; rf < 2; ++rf)
            #pragma unroll
            for (int g = 0; g < 4; ++g) acc[rf][g] = (f32x4)0.f;
        #pragma unroll
        for (int kf = 0; kf < 8; ++kf){
            s16x8 a0 = *(const s16x8*)(sA + l15*528 + kf*64 + l4*16);
            s16x8 a1 = *(const s16x8*)(sA + (16 + l15)*528 + kf*64 + l4*16);
            #pragma unroll
            for (int g = 0; g < 4; ++g){
                acc[0][g] = MFMA16(a0, bfr[kf][g], acc[0][g]);
                acc[1][g] = MFMA16(a1, bfr[kf][g], acc[1][g]);
            }
        }
        #pragma unroll
        for (int rf = 0; rf < 2; ++rf)
            #pragma unroll
            for (int r = 0; r < 4; ++r){
                int rl = rf*16 + l4*4 + r;
                float rr = sigmoidf_(acc[rf][0][r] + rb);
                float zz = sigmoidf_(acc[rf][1][r] + zb);
                float iv = acc[rf][2][r] + ib;
                float hv = acc[rf][3][r] + hb;
                float nc = tanhf_(iv + rr*hv);
                float xej = bf16f(*(const u16*)(sA + rl*528 + 256 + 2*j));
                float v = (1.f - zz)*nc + zz*xej;
                v = fmaxf(v, 0.f);
                sOut[rl*132 + j] = v;
            }
        __syncthreads();
        {
            int row = t >> 4, sub = t & 15;          // 16 threads/row, same wave
            const float* rp = sOut + row*132 + sub*8;
            float v0 = rp[0], v1 = rp[1], v2 = rp[2], v3 = rp[3];
            float v4 = rp[4], v5 = rp[5], v6 = rp[6], v7 = rp[7];
            float s1 = v0+v1+v2+v3+v4+v5+v6+v7;
            float s2 = v0*v0+v1*v1+v2*v2+v3*v3+v4*v4+v5*v5+v6*v6+v7*v7;
            #pragma unroll
            for (int o = 1; o < 16; o <<= 1){ s1 += __shfl_xor(s1, o); s2 += __shfl_xor(s2, o); }
            float mu  = s1 * (1.f/128.f);
            float var = s2 * (1.f/128.f) - mu*mu;
            var = fmaxf(var, 0.f);
            float rsd = rsqrtf(var + 1e-5f);
            float* op = out + ((size_t)tile*32 + row)*128 + sub*8;
            float4 o0, o1;
            o0.x = (v0-mu)*rsd; o0.y = (v1-mu)*rsd; o0.z = (v2-mu)*rsd; o0.w = (v3-mu)*rsd;
            o1.x = (v4-mu)*rsd; o1.y = (v5-mu)*rsd; o1.z = (v6-mu)*rsd; o1.w = (v7-mu)*rsd;
            ((float4*)op)[0] = o0; ((float4*)op)[1] = o1;
        }
        __syncthreads();
    }
}

// ---------------- host ----------------
extern "C" void kernel_launch(void* const* d_in, const int* in_sizes, int n_in,
                              void* d_out, int out_size, void* d_ws, size_t ws_size,
                              hipStream_t stream)
{
    const float* x       = (const float*)d_in[0];
    const float* ea      = (const float*)d_in[1];
    const float* W_enter = (const float*)d_in[2];
    const float* b_enter = (const float*)d_in[3];
    const float* W1      = (const float*)d_in[4];
    const float* att_l   = (const float*)d_in[5];
    const float* att_r   = (const float*)d_in[6];
    const float* W2      = (const float*)d_in[7];
    const float* b_conv  = (const float*)d_in[8];
    const float* W_ih    = (const float*)d_in[9];
    const float* W_hh    = (const float*)d_in[10];
    const float* b_ih    = (const float*)d_in[11];
    const float* b_hh    = (const float*)d_in[12];
    const int*   eidx    = (const int*)d_in[13];

    int N = in_sizes[0] / DIN;
    int E = in_sizes[13] / 2;
    const int* src = eidx;
    const int* dst = eidx + E;
    float* out = (float*)d_out;

    size_t off = 0;
    char* base = (char*)d_ws;
    auto alloc = [&](size_t bytes) -> char* {
        char* p = base + off;
        off = (off + bytes + 255) & ~(size_t)255;
        return p;
    };
    u16*   Ag    = (u16*)  alloc((size_t)N*256*2);   // [h | xe] bf16
    float* r_dst = (float*)alloc((size_t)N*4);
    float* alpha = (float*)alloc((size_t)E*4);
    int*   deg   = (int*)  alloc((size_t)N*4);
    int*   rs    = (int*)  alloc((size_t)(N+1)*4);
    int*   cnt   = (int*)  alloc((size_t)N*4);
    int*   epos  = (int*)  alloc((size_t)E*4);
    int*   btot  = (int*)  alloc(1024);
    int*   bbase = (int*)  alloc(1024);
    u16*   W1b   = (u16*)  alloc(20480*2);
    u16*   W2b   = (u16*)  alloc(16384*2);
    u16*   Wentb = (u16*)  alloc(8192*2);
    u16*   Bg    = (u16*)  alloc(131072*2);

    size_t m_bf16_bytes = (size_t)E*HD*2;
    bool   big = (ws_size - off) >= m_bf16_bytes;
    void*  mbuf = (void*)(base + off);
    float* a_agg = out;   // d_out reused (dead before k_gru writes)

    int ntiles_n64 = N/64, ntiles_e = (E + 63)/64, ntiles_g = N/32;

    k_prep   <<<(176128+255)/256, 256, 0, stream>>>(W1, W2, W_enter, W_ih, W_hh, W1b, W2b, Wentb, Bg);
    k_zero2  <<<(N+255)/256, 256, 0, stream>>>(deg, cnt, N);
    k_enter_mfma<<<ntiles_n64, 256, 0, stream>>>(x, Wentb, b_enter, att_r, Ag, r_dst, N);
    k_hist   <<<(E+255)/256, 256, 0, stream>>>(dst, deg, E);
    k_scan_a <<<N/1024, 256, 0, stream>>>(deg, rs, btot, N);
    k_scan_b <<<1, 256, 0, stream>>>(btot, bbase);
    k_scan_c <<<(N+255)/256, 256, 0, stream>>>(rs, bbase, N, E);
    k_scatter<<<(E+255)/256, 256, 0, stream>>>(dst, rs, cnt, epos, E);
    if (big){
        k_edge_mfma<u16><<<768, 256, 0, stream>>>(Ag, ea, W1b, att_l, r_dst, src, dst, epos,
                                                  (u16*)mbuf, alpha, ntiles_e, E);
    } else {
        k_edge_mfma<u8> <<<768, 256, 0, stream>>>(Ag, ea, W1b, att_l, r_dst, src, dst, epos,
                                                  (u8*)mbuf, alpha, ntiles_e, E);
    }
    if (big){
        k_agg<u16><<<(N+3)/4, 256, 0, stream>>>(rs, alpha, (const u16*)mbuf, a_agg, N);
    } else {
        k_agg<u8> <<<(N+3)/4, 256, 0, stream>>>(rs, alpha, (const u8*)mbuf, a_agg, N);
    }
    k_conv2_mfma<<<ntiles_n64, 256, 0, stream>>>(a_agg, W2b, b_conv, Ag, N);
    k_gru_mfma  <<<2048, 512, 0, stream>>>(Ag, Bg, b_ih, b_hh, out, N, ntiles_g);
}

// Round 6
// 691.296 us; speedup vs baseline: 7.6940x; 1.0557x over previous
//
#include <hip/hip_runtime.h>
#include <stdint.h>

#define HD  128
#define DIN 64
#define DE  32

typedef unsigned int u32; typedef unsigned short u16; typedef unsigned char u8;
typedef short s16x8 __attribute__((ext_vector_type(8)));
typedef float f32x4 __attribute__((ext_vector_type(4)));

#define MFMA16(a,b,c) __builtin_amdgcn_mfma_f32_16x16x32_bf16((a),(b),(c),0,0,0)

__device__ __forceinline__ float lrelu(float x){ return x > 0.f ? x : 0.01f*x; }
__device__ __forceinline__ float sigmoidf_(float x){ return 1.f/(1.f + __expf(-x)); }
__device__ __forceinline__ float tanhf_(float x){
    float t = fminf(fmaxf(x, -15.f), 15.f);
    float e = __expf(2.f*t);
    return (e - 1.f)/(e + 1.f);
}
__device__ __forceinline__ float eluf_(float x){ return x > 0.f ? x : expm1f(x); }

__device__ __forceinline__ u16 f32_to_bf16(float x){
    u32 u = __float_as_uint(x);
    u += 0x7FFFu + ((u >> 16) & 1u);
    return (u16)(u >> 16);
}
__device__ __forceinline__ float bf16lo(u32 u){ return __uint_as_float((u & 0xFFFFu) << 16); }
__device__ __forceinline__ float bf16hi(u32 u){ return __uint_as_float(u & 0xFFFF0000u); }
__device__ __forceinline__ float bf16f(u16 h){ return __uint_as_float(((u32)h) << 16); }
__device__ __forceinline__ u32 pk2(float a, float b){
    return (u32)f32_to_bf16(a) | ((u32)f32_to_bf16(b) << 16);
}
// custom e4m3, exponent bias 13: normals in [2^-12, 7.5]
__device__ __forceinline__ u8 f32_to_f8(float x){
    u32 u = __float_as_uint(x);
    u32 s = (u >> 24) & 0x80u;
    u &= 0x7FFFFFFFu;
    u += 0x0007FFFFu + ((u >> 20) & 1u);
    int e = (int)(u >> 23) - 114;
    if (e <= 0)  return (u8)s;
    if (e > 15)  return (u8)(s | 0x7F);
    return (u8)(s | ((u32)e << 3) | ((u >> 20) & 7u));
}
__device__ __forceinline__ float f8_to_f32(u32 b){
    u32 e = (b >> 3) & 0xFu;
    u32 u = ((b & 0x80u) << 24) | ((e + 114u) << 23) | ((b & 7u) << 20);
    float f = __uint_as_float(u);
    return e ? f : 0.f;
}

__device__ __forceinline__ float wave_max(float v){
    #pragma unroll
    for (int o = 32; o > 0; o >>= 1) v = fmaxf(v, __shfl_xor(v, o, 64));
    return v;
}
__device__ __forceinline__ float wave_sum(float v){
    #pragma unroll
    for (int o = 32; o > 0; o >>= 1) v += __shfl_xor(v, o, 64);
    return v;
}
__device__ __forceinline__ float dot8_bf16(uint4 v, const float* __restrict__ al){
    float d = 0.f;
    d = fmaf(bf16lo(v.x), al[0], d); d = fmaf(bf16hi(v.x), al[1], d);
    d = fmaf(bf16lo(v.y), al[2], d); d = fmaf(bf16hi(v.y), al[3], d);
    d = fmaf(bf16lo(v.z), al[4], d); d = fmaf(bf16hi(v.z), al[5], d);
    d = fmaf(bf16lo(v.w), al[6], d); d = fmaf(bf16hi(v.w), al[7], d);
    return d;
}
__device__ __forceinline__ float dot16_f8(uint4 v, const float* __restrict__ al){
    float d = 0.f;
    u32 ws[4] = {v.x, v.y, v.z, v.w};
    #pragma unroll
    for (int i = 0; i < 4; ++i){
        #pragma unroll
        for (int b = 0; b < 4; ++b)
            d = fmaf(f8_to_f32((ws[i] >> (8*b)) & 0xFFu), al[4*i + b], d);
    }
    return d;
}

// ---------------- weight prep: fp32 -> bf16 (+ GRU B-pack) ----------------
__global__ void k_prep(const float* __restrict__ W1, const float* __restrict__ W2,
                       const float* __restrict__ Went,
                       const float* __restrict__ Wih, const float* __restrict__ Whh,
                       u16* __restrict__ W1b, u16* __restrict__ W2b,
                       u16* __restrict__ Wentb, u16* __restrict__ Bg)
{
    int i = blockIdx.x*256 + threadIdx.x;
    if (i < 20480){ W1b[i] = f32_to_bf16(W1[i]); return; }
    i -= 20480;
    if (i < 16384){ W2b[i] = f32_to_bf16(W2[i]); return; }
    i -= 16384;
    if (i < 8192){ Wentb[i] = f32_to_bf16(Went[i]); return; }
    i -= 8192;
    if (i < 131072){
        int col = i >> 8, k = i & 255;
        int g = col >> 7, j = col & 127;
        float v;
        if      (g == 0) v = (k < 128) ? Wih[j*128 + k]        : Whh[j*128 + k - 128];
        else if (g == 1) v = (k < 128) ? Wih[(128+j)*128 + k]  : Whh[(128+j)*128 + k - 128];
        else if (g == 2) v = (k < 128) ? Wih[(256+j)*128 + k]  : 0.f;
        else             v = (k < 128) ? 0.f                   : Whh[(256+j)*128 + k - 128];
        Bg[i] = f32_to_bf16(v);
    }
}

// ---------------- init ----------------
__global__ void k_zero2(int* __restrict__ a, int* __restrict__ b, int n){
    int i = blockIdx.x*256 + threadIdx.x;
    if (i < n){ a[i] = 0; b[i] = 0; }
}

// ---------------- K1 (MFMA): xe-half of Ag = bf16(lrelu(x@W^T+b)); r_dst = xe·att_r ----------------
__global__ __launch_bounds__(256, 2) void k_enter_mfma(
    const float* __restrict__ x, const u16* __restrict__ Wb, const float* __restrict__ be,
    const float* __restrict__ att_r, u16* __restrict__ Ag, float* __restrict__ r_out, int N)
{
    __shared__ __align__(16) u8 sA[64*144];
    __shared__ __align__(16) u8 sO[64*272];
    int t = threadIdx.x, w = t >> 6, lane = t & 63, l15 = lane & 15, l4 = lane >> 4;
    int tile = blockIdx.x;

    s16x8 bfr[2][2];
    #pragma unroll
    for (int kf = 0; kf < 2; ++kf)
        #pragma unroll
        for (int cf = 0; cf < 2; ++cf)
            bfr[kf][cf] = *(const s16x8*)(Wb + (size_t)(w*32 + cf*16 + l15)*64 + kf*32 + l4*8);

    int el = t >> 2, q = t & 3;
    size_t n = (size_t)tile*64 + el;
    {
        const float4* xs = (const float4*)(x + n*64 + q*16);
        float4 f0 = xs[0], f1 = xs[1], f2 = xs[2], f3 = xs[3];
        uint4 o0, o1;
        o0.x = pk2(f0.x,f0.y); o0.y = pk2(f0.z,f0.w); o0.z = pk2(f1.x,f1.y); o0.w = pk2(f1.z,f1.w);
        o1.x = pk2(f2.x,f2.y); o1.y = pk2(f2.z,f2.w); o1.z = pk2(f3.x,f3.y); o1.w = pk2(f3.z,f3.w);
        *(uint4*)(sA + el*144 + q*32)      = o0;
        *(uint4*)(sA + el*144 + q*32 + 16) = o1;
    }
    __syncthreads();

    f32x4 acc[4][2];
    #pragma unroll
    for (int rf = 0; rf < 4; ++rf){ acc[rf][0] = (f32x4)0.f; acc[rf][1] = (f32x4)0.f; }
    #pragma unroll
    for (int kf = 0; kf < 2; ++kf){
        s16x8 a[4];
        #pragma unroll
        for (int rf = 0; rf < 4; ++rf)
            a[rf] = *(const s16x8*)(sA + (rf*16 + l15)*144 + kf*64 + l4*16);
        #pragma unroll
        for (int rf = 0; rf < 4; ++rf){
            acc[rf][0] = MFMA16(a[rf], bfr[kf][0], acc[rf][0]);
            acc[rf][1] = MFMA16(a[rf], bfr[kf][1], acc[rf][1]);
        }
    }
    float b0 = be[w*32 + l15], b1 = be[w*32 + 16 + l15];
    #pragma unroll
    for (int rf = 0; rf < 4; ++rf)
        #pragma unroll
        for (int r = 0; r < 4; ++r){
            int row = rf*16 + l4*4 + r;
            *(u16*)(sO + row*272 + (w*32 + l15)*2)      = f32_to_bf16(lrelu(acc[rf][0][r] + b0));
            *(u16*)(sO + row*272 + (w*32 + 16 + l15)*2) = f32_to_bf16(lrelu(acc[rf][1][r] + b1));
        }
    __syncthreads();

    float dot = 0.f;
    #pragma unroll
    for (int i = 0; i < 4; ++i){
        uint4 v = *(const uint4*)(sO + el*272 + q*64 + 16*i);
        ((uint4*)Ag)[n*32 + 16 + q*4 + i] = v;         // xe half: byte n*512+256
        dot += dot8_bf16(v, att_r + q*32 + 8*i);
    }
    dot += __shfl_xor(dot, 1); dot += __shfl_xor(dot, 2);
    if (q == 0) r_out[n] = dot;
}

// ---------------- CSR build ----------------
__global__ void k_hist(const int* __restrict__ dst, int* __restrict__ deg, int E){
    int e = blockIdx.x*256 + threadIdx.x;
    if (e < E) atomicAdd(&deg[dst[e]], 1);
}
__global__ __launch_bounds__(256) void k_scan_a(
    const int* __restrict__ deg, int* __restrict__ rs, int* __restrict__ btot, int N)
{
    __shared__ int sd[256];
    int b = blockIdx.x, t = threadIdx.x;
    int base = b*1024 + t*4;
    int d0 = deg[base], d1 = deg[base+1], d2 = deg[base+2], d3 = deg[base+3];
    int s = d0 + d1 + d2 + d3;
    sd[t] = s; __syncthreads();
    for (int o = 1; o < 256; o <<= 1){
        int v = (t >= o) ? sd[t-o] : 0;
        __syncthreads();
        sd[t] += v;
        __syncthreads();
    }
    int ex = sd[t] - s;
    rs[base]   = ex;
    rs[base+1] = ex + d0;
    rs[base+2] = ex + d0 + d1;
    rs[base+3] = ex + d0 + d1 + d2;
    if (t == 0) btot[b] = sd[255];
}
__global__ __launch_bounds__(256) void k_scan_b(const int* __restrict__ btot, int* __restrict__ bbase){
    __shared__ int sd[256];
    int t = threadIdx.x;
    int s = btot[t];
    sd[t] = s; __syncthreads();
    for (int o = 1; o < 256; o <<= 1){
        int v = (t >= o) ? sd[t-o] : 0;
        __syncthreads();
        sd[t] += v;
        __syncthreads();
    }
    bbase[t] = sd[t] - s;
}
__global__ void k_scan_c(int* __restrict__ rs, const int* __restrict__ bbase, int N, int E){
    int i = blockIdx.x*256 + threadIdx.x;
    if (i < N) rs[i] += bbase[i >> 10];
    if (i == 0) rs[N] = E;
}
__global__ void k_scatter(const int* __restrict__ dst, const int* __restrict__ rs,
                          int* __restrict__ cnt, int* __restrict__ epos, int E){
    int e = blockIdx.x*256 + threadIdx.x;
    if (e >= E) return;
    int d = dst[e];
    int pos = rs[d] + atomicAdd(&cnt[d], 1);
    epos[e] = pos;
}

// ---------------- K2 (MFMA, persistent + prefetch): m_s[epos[e]] (fp8), alpha_s[epos[e]] ----------------
__global__ __launch_bounds__(256, 3) void k_edge_mfma(
    const u16* __restrict__ Ag, const float* __restrict__ ea,
    const u16* __restrict__ W1b, const float* __restrict__ att_l,
    const float* __restrict__ r_dst, const int* __restrict__ src, const int* __restrict__ dst,
    const int* __restrict__ epos,
    u8* __restrict__ m, float* __restrict__ alpha, int ntiles, int E)
{
    __shared__ __align__(16) u8 sA[64*336];      // sM aliases sA (sA dead after MFMA reads)
    u8* sM = sA;
    int t = threadIdx.x, w = t >> 6, lane = t & 63, l15 = lane & 15, l4 = lane >> 4;
    constexpr int MS = 144;

    s16x8 bfr[5][2];
    #pragma unroll
    for (int kf = 0; kf < 5; ++kf)
        #pragma unroll
        for (int cf = 0; cf < 2; ++cf)
            bfr[kf][cf] = *(const s16x8*)(W1b + (size_t)(w*32 + cf*16 + l15)*160 + kf*32 + l4*8);

    int el = t >> 2, q = t & 3;
    int stride = gridDim.x;
    int tile = blockIdx.x;

    uint4 cx0, cx1, cx2, cx3;      // prefetched xe[src[e]] chunk (64B/thread)
    float4 ce0, ce1;               // prefetched edge_attr chunk
    {
        int e = tile*64 + el;
        if (tile < ntiles && e < E){
            int sn = src[e];
            const uint4* xs = (const uint4*)Ag + (size_t)sn*32 + 16 + q*4;
            cx0 = xs[0]; cx1 = xs[1]; cx2 = xs[2]; cx3 = xs[3];
            const float4* ef = (const float4*)(ea + (size_t)e*32 + q*8);
            ce0 = ef[0]; ce1 = ef[1];
        }
    }

    for (; tile < ntiles; tile += stride){
        int e = tile*64 + el;
        if (e < E){
            uint4* d = (uint4*)(sA + el*336 + q*64);
            d[0] = cx0; d[1] = cx1; d[2] = cx2; d[3] = cx3;
            uint4 o;
            o.x = pk2(ce0.x,ce0.y); o.y = pk2(ce0.z,ce0.w);
            o.z = pk2(ce1.x,ce1.y); o.w = pk2(ce1.z,ce1.w);
            *(uint4*)(sA + el*336 + 256 + q*16) = o;
        }
        __syncthreads();

        // issue next tile's gather; latency hides under MFMA + epilogue
        int nt = tile + stride;
        if (nt < ntiles){
            int e2 = nt*64 + el;
            if (e2 < E){
                int sn = src[e2];
                const uint4* xs = (const uint4*)Ag + (size_t)sn*32 + 16 + q*4;
                cx0 = xs[0]; cx1 = xs[1]; cx2 = xs[2]; cx3 = xs[3];
                const float4* ef = (const float4*)(ea + (size_t)e2*32 + q*8);
                ce0 = ef[0]; ce1 = ef[1];
            }
        }

        f32x4 acc[4][2];
        #pragma unroll
        for (int rf = 0; rf < 4; ++rf){ acc[rf][0] = (f32x4)0.f; acc[rf][1] = (f32x4)0.f; }
        #pragma unroll
        for (int kf = 0; kf < 5; ++kf){
            s16x8 a[4];
            #pragma unroll
            for (int rf = 0; rf < 4; ++rf)
                a[rf] = *(const s16x8*)(sA + (rf*16 + l15)*336 + kf*64 + l4*16);
            #pragma unroll
            for (int rf = 0; rf < 4; ++rf){
                acc[rf][0] = MFMA16(a[rf], bfr[kf][0], acc[rf][0]);
                acc[rf][1] = MFMA16(a[rf], bfr[kf][1], acc[rf][1]);
            }
        }
        __syncthreads();   // all sA reads done before overwriting as sM

        #pragma unroll
        for (int rf = 0; rf < 4; ++rf)
            #pragma unroll
            for (int cf = 0; cf < 2; ++cf)
                #pragma unroll
                for (int r = 0; r < 4; ++r){
                    int row = rf*16 + l4*4 + r;
                    int col = w*32 + cf*16 + l15;
                    sM[row*MS + col] = f32_to_f8(lrelu(acc[rf][cf][r]));
                }
        __syncthreads();

        if (e < E){
            int p = epos[e];
            float dot = 0.f;
            #pragma unroll
            for (int i = 0; i < 2; ++i){
                uint4 v = *(const uint4*)(sM + el*144 + q*32 + 16*i);
                dot += dot16_f8(v, att_l + q*32 + 16*i);
                ((uint4*)m)[(size_t)p*8 + q*2 + i] = v;
            }
            dot += __shfl_xor(dot, 1); dot += __shfl_xor(dot, 2);
            if (q == 0) alpha[p] = lrelu(dot + r_dst[dst[e]]);
        }
        __syncthreads();   // sM reads done before next iteration's sA write
    }
}

// ---------------- K4: streaming segment softmax + weighted sum (fp8 m) -> bf16 a_agg ----------------
__global__ __launch_bounds__(256) void k_agg(
    const int* __restrict__ rs,
    const float* __restrict__ alpha, const u8* __restrict__ m,
    u16* __restrict__ a_out, int N)
{
    int wid  = (blockIdx.x*256 + threadIdx.x) >> 6;
    int lane = threadIdx.x & 63;
    if (wid >= N) return;
    int s = rs[wid], t = rs[wid+1];
    int deg = t - s;
    float ax = 0.f, ay = 0.f;
    if (deg > 0 && deg <= 64){
        float av = -1e38f;
        if (lane < deg) av = alpha[s + lane];
        float mx = wave_max(av);
        float ev = (lane < deg) ? __expf(av - mx) : 0.f;
        float ssum = wave_sum(ev);
        float wreg = ev / ssum;
        int k = 0;
        for (; k + 2 <= deg; k += 2){
            float w0 = __shfl(wreg, k);
            float w1 = __shfl(wreg, k + 1);
            u32 u0 = *(const u16*)(m + (size_t)(s + k)*HD + 2*lane);
            u32 u1 = *(const u16*)(m + (size_t)(s + k + 1)*HD + 2*lane);
            ax = fmaf(w0, f8_to_f32(u0 & 0xFFu), ax); ay = fmaf(w0, f8_to_f32((u0 >> 8) & 0xFFu), ay);
            ax = fmaf(w1, f8_to_f32(u1 & 0xFFu), ax); ay = fmaf(w1, f8_to_f32((u1 >> 8) & 0xFFu), ay);
        }
        if (k < deg){
            float w0 = __shfl(wreg, k);
            u32 u0 = *(const u16*)(m + (size_t)(s + k)*HD + 2*lane);
            ax = fmaf(w0, f8_to_f32(u0 & 0xFFu), ax); ay = fmaf(w0, f8_to_f32((u0 >> 8) & 0xFFu), ay);
        }
    } else if (deg > 64){
        float mx = -1e38f;
        for (int k = lane; k < deg; k += 64) mx = fmaxf(mx, alpha[s + k]);
        mx = wave_max(mx);
        float ssum = 0.f;
        for (int k = lane; k < deg; k += 64) ssum += __expf(alpha[s + k] - mx);
        ssum = wave_sum(ssum);
        float inv = 1.f / ssum;
        for (int k = 0; k < deg; ++k){
            float wgt = __expf(alpha[s + k] - mx) * inv;
            u32 u0 = *(const u16*)(m + (size_t)(s + k)*HD + 2*lane);
            ax = fmaf(wgt, f8_to_f32(u0 & 0xFFu), ax);
            ay = fmaf(wgt, f8_to_f32((u0 >> 8) & 0xFFu), ay);
        }
    }
    *(u32*)(a_out + (size_t)wid*HD + 2*lane) = pk2(ax, ay);
}

// ---------------- K5a (MFMA): h-half of Ag = bf16(elu(W2@a + bc)), a in bf16 ----------------
__global__ __launch_bounds__(256, 2) void k_conv2_mfma(
    const u16* __restrict__ a, const u16* __restrict__ W2b, const float* __restrict__ bc,
    u16* __restrict__ Ag, int N)
{
    __shared__ __align__(16) u8 sA[64*272];
    __shared__ __align__(16) u8 sO[64*272];
    int t = threadIdx.x, w = t >> 6, lane = t & 63, l15 = lane & 15, l4 = lane >> 4;
    int tile = blockIdx.x;

    s16x8 bfr[4][2];
    #pragma unroll
    for (int kf = 0; kf < 4; ++kf)
        #pragma unroll
        for (int cf = 0; cf < 2; ++cf)
            bfr[kf][cf] = *(const s16x8*)(W2b + (size_t)(w*32 + cf*16 + l15)*128 + kf*32 + l4*8);

    int el = t >> 2, q = t & 3;
    size_t n = (size_t)tile*64 + el;
    {
        const uint4* as = (const uint4*)(a + n*HD) + q*4;
        uint4 v0 = as[0], v1 = as[1], v2 = as[2], v3 = as[3];
        uint4* d = (uint4*)(sA + el*272 + q*64);
        d[0] = v0; d[1] = v1; d[2] = v2; d[3] = v3;
    }
    __syncthreads();

    f32x4 acc[4][2];
    #pragma unroll
    for (int rf = 0; rf < 4; ++rf){ acc[rf][0] = (f32x4)0.f; acc[rf][1] = (f32x4)0.f; }
    #pragma unroll
    for (int kf = 0; kf < 4; ++kf){
        s16x8 av[4];
        #pragma unroll
        for (int rf = 0; rf < 4; ++rf)
            av[rf] = *(const s16x8*)(sA + (rf*16 + l15)*272 + kf*64 + l4*16);
        #pragma unroll
        for (int rf = 0; rf < 4; ++rf){
            acc[rf][0] = MFMA16(av[rf], bfr[kf][0], acc[rf][0]);
            acc[rf][1] = MFMA16(av[rf], bfr[kf][1], acc[rf][1]);
        }
    }
    float b0 = bc[w*32 + l15], b1 = bc[w*32 + 16 + l15];
    #pragma unroll
    for (int rf = 0; rf < 4; ++rf)
        #pragma unroll
        for (int r = 0; r < 4; ++r){
            int row = rf*16 + l4*4 + r;
            *(u16*)(sO + row*272 + (w*32 + l15)*2)      = f32_to_bf16(eluf_(acc[rf][0][r] + b0));
            *(u16*)(sO + row*272 + (w*32 + 16 + l15)*2) = f32_to_bf16(eluf_(acc[rf][1][r] + b1));
        }
    __syncthreads();
    #pragma unroll
    for (int i = 0; i < 4; ++i){
        uint4 v = *(const uint4*)(sO + el*272 + q*64 + 16*i);
        ((uint4*)Ag)[n*32 + q*4 + i] = v;              // h half: byte n*512
    }
}

// ---------------- K5b (MFMA): GRU cell + fused LayerNorm -> out ----------------
__global__ __launch_bounds__(512, 2) void k_gru_mfma(
    const u16* __restrict__ Ag, const u16* __restrict__ Bg,
    const float* __restrict__ bih, const float* __restrict__ bhh,
    float* __restrict__ out, int N, int ntiles)
{
    __shared__ __align__(16) u8 sA[32*528];
    __shared__ __align__(16) float sOut[32*132];     // +4 pad breaks write conflicts
    int t = threadIdx.x, w = t >> 6, lane = t & 63, l15 = lane & 15, l4 = lane >> 4;

    s16x8 bfr[8][4];
    #pragma unroll
    for (int g = 0; g < 4; ++g){
        int col = g*128 + w*16 + l15;
        #pragma unroll
        for (int kf = 0; kf < 8; ++kf)
            bfr[kf][g] = *(const s16x8*)(Bg + (size_t)col*256 + kf*32 + l4*8);
    }
    int j = w*16 + l15;
    float rb = bih[j] + bhh[j];
    float zb = bih[128 + j] + bhh[128 + j];
    float ib = bih[256 + j];
    float hb = bhh[256 + j];

    for (int tile = blockIdx.x; tile < ntiles; tile += gridDim.x){
        {
            int el = t >> 4, part = t & 15;
            const uint4* gsrc = (const uint4*)Ag + ((size_t)tile*32 + el)*32 + part*2;
            uint4 v0 = gsrc[0], v1 = gsrc[1];
            uint4* d = (uint4*)(sA + el*528 + part*32);
            d[0] = v0; d[1] = v1;
        }
        __syncthreads();

        f32x4 acc[2][4];
        #pragma unroll
        for (int rf = 0; rf < 2; ++rf)
            #pragma unroll
            for (int g = 0; g < 4; ++g) acc[rf][g] = (f32x4)0.f;
        #pragma unroll
        for (int kf = 0; kf < 8; ++kf){
            s16x8 a0 = *(const s16x8*)(sA + l15*528 + kf*64 + l4*16);
            s16x8 a1 = *(const s16x8*)(sA + (16 + l15)*528 + kf*64 + l4*16);
            #pragma unroll
            for (int g = 0; g < 4; ++g){
                acc[0][g] = MFMA16(a0, bfr[kf][g], acc[0][g]);
                acc[1][g] = MFMA16(a1, bfr[kf][g], acc[1][g]);
            }
        }
        #pragma unroll
        for (int rf = 0; rf < 2; ++rf)
            #pragma unroll
            for (int r = 0; r < 4; ++r){
                int rl = rf*16 + l4*4 + r;
                float rr = sigmoidf_(acc[rf][0][r] + rb);
                float zz = sigmoidf_(acc[rf][1][r] + zb);
                float iv = acc[rf][2][r] + ib;
                float hv = acc[rf][3][r] + hb;
                float nc = tanhf_(iv + rr*hv);
                float xej = bf16f(*(const u16*)(sA + rl*528 + 256 + 2*j));
                float v = (1.f - zz)*nc + zz*xej;
                v = fmaxf(v, 0.f);
                sOut[rl*132 + j] = v;
            }
        __syncthreads();
        {
            int row = t >> 4, sub = t & 15;          // 16 threads/row, same wave
            const float* rp = sOut + row*132 + sub*8;
            float v0 = rp[0], v1 = rp[1], v2 = rp[2], v3 = rp[3];
            float v4 = rp[4], v5 = rp[5], v6 = rp[6], v7 = rp[7];
            float s1 = v0+v1+v2+v3+v4+v5+v6+v7;
            float s2 = v0*v0+v1*v1+v2*v2+v3*v3+v4*v4+v5*v5+v6*v6+v7*v7;
            #pragma unroll
            for (int o = 1; o < 16; o <<= 1){ s1 += __shfl_xor(s1, o); s2 += __shfl_xor(s2, o); }
            float mu  = s1 * (1.f/128.f);
            float var = s2 * (1.f/128.f) - mu*mu;
            var = fmaxf(var, 0.f);
            float rsd = rsqrtf(var + 1e-5f);
            float* op = out + ((size_t)tile*32 + row)*128 + sub*8;
            float4 o0, o1;
            o0.x = (v0-mu)*rsd; o0.y = (v1-mu)*rsd; o0.z = (v2-mu)*rsd; o0.w = (v3-mu)*rsd;
            o1.x = (v4-mu)*rsd; o1.y = (v5-mu)*rsd; o1.z = (v6-mu)*rsd; o1.w = (v7-mu)*rsd;
            ((float4*)op)[0] = o0; ((float4*)op)[1] = o1;
        }
        __syncthreads();
    }
}

// ---------------- host ----------------
extern "C" void kernel_launch(void* const* d_in, const int* in_sizes, int n_in,
                              void* d_out, int out_size, void* d_ws, size_t ws_size,
                              hipStream_t stream)
{
    const float* x       = (const float*)d_in[0];
    const float* ea      = (const float*)d_in[1];
    const float* W_enter = (const float*)d_in[2];
    const float* b_enter = (const float*)d_in[3];
    const float* W1      = (const float*)d_in[4];
    const float* att_l   = (const float*)d_in[5];
    const float* att_r   = (const float*)d_in[6];
    const float* W2      = (const float*)d_in[7];
    const float* b_conv  = (const float*)d_in[8];
    const float* W_ih    = (const float*)d_in[9];
    const float* W_hh    = (const float*)d_in[10];
    const float* b_ih    = (const float*)d_in[11];
    const float* b_hh    = (const float*)d_in[12];
    const int*   eidx    = (const int*)d_in[13];

    int N = in_sizes[0] / DIN;
    int E = in_sizes[13] / 2;
    const int* src = eidx;
    const int* dst = eidx + E;
    float* out = (float*)d_out;

    size_t off = 0;
    char* base = (char*)d_ws;
    auto alloc = [&](size_t bytes) -> char* {
        char* p = base + off;
        off = (off + bytes + 255) & ~(size_t)255;
        return p;
    };
    u16*   Ag    = (u16*)  alloc((size_t)N*256*2);   // [h | xe] bf16
    float* r_dst = (float*)alloc((size_t)N*4);
    float* alpha = (float*)alloc((size_t)E*4);
    int*   deg   = (int*)  alloc((size_t)N*4);
    int*   rs    = (int*)  alloc((size_t)(N+1)*4);
    int*   cnt   = (int*)  alloc((size_t)N*4);
    int*   epos  = (int*)  alloc((size_t)E*4);
    int*   btot  = (int*)  alloc(1024);
    int*   bbase = (int*)  alloc(1024);
    u16*   W1b   = (u16*)  alloc(20480*2);
    u16*   W2b   = (u16*)  alloc(16384*2);
    u16*   Wentb = (u16*)  alloc(8192*2);
    u16*   Bg    = (u16*)  alloc(131072*2);
    u8*    mbuf  = (u8*)   alloc((size_t)E*HD);      // fp8 m, CSR-sorted

    u16* a_agg = (u16*)out;   // d_out reused as bf16 a_agg (dead before k_gru writes)

    int ntiles_n64 = N/64, ntiles_e = (E + 63)/64, ntiles_g = N/32;

    k_prep   <<<(176128+255)/256, 256, 0, stream>>>(W1, W2, W_enter, W_ih, W_hh, W1b, W2b, Wentb, Bg);
    k_zero2  <<<(N+255)/256, 256, 0, stream>>>(deg, cnt, N);
    k_enter_mfma<<<ntiles_n64, 256, 0, stream>>>(x, Wentb, b_enter, att_r, Ag, r_dst, N);
    k_hist   <<<(E+255)/256, 256, 0, stream>>>(dst, deg, E);
    k_scan_a <<<N/1024, 256, 0, stream>>>(deg, rs, btot, N);
    k_scan_b <<<1, 256, 0, stream>>>(btot, bbase);
    k_scan_c <<<(N+255)/256, 256, 0, stream>>>(rs, bbase, N, E);
    k_scatter<<<(E+255)/256, 256, 0, stream>>>(dst, rs, cnt, epos, E);
    k_edge_mfma<<<1536, 256, 0, stream>>>(Ag, ea, W1b, att_l, r_dst, src, dst, epos,
                                          mbuf, alpha, ntiles_e, E);
    k_agg    <<<(N+3)/4, 256, 0, stream>>>(rs, alpha, mbuf, a_agg, N);
    k_conv2_mfma<<<ntiles_n64, 256, 0, stream>>>(a_agg, W2b, b_conv, Ag, N);
    k_gru_mfma  <<<2048, 512, 0, stream>>>(Ag, Bg, b_ih, b_hh, out, N, ntiles_g);
}

// Round 7
// 660.394 us; speedup vs baseline: 8.0540x; 1.0468x over previous
//
#include <hip/hip_runtime.h>
#include <stdint.h>

#define HD  128
#define DIN 64
#define DE  32

typedef unsigned int u32; typedef unsigned short u16; typedef unsigned char u8;
typedef short s16x8 __attribute__((ext_vector_type(8)));
typedef float f32x4 __attribute__((ext_vector_type(4)));
typedef float f32x2 __attribute__((ext_vector_type(2)));

#define MFMA16(a,b,c) __builtin_amdgcn_mfma_f32_16x16x32_bf16((a),(b),(c),0,0,0)

__device__ __forceinline__ float lrelu(float x){ return x > 0.f ? x : 0.01f*x; }
__device__ __forceinline__ float sigmoidf_(float x){ return 1.f/(1.f + __expf(-x)); }
__device__ __forceinline__ float tanhf_(float x){
    float t = fminf(fmaxf(x, -15.f), 15.f);
    float e = __expf(2.f*t);
    return (e - 1.f)/(e + 1.f);
}
__device__ __forceinline__ float eluf_(float x){ return x > 0.f ? x : expm1f(x); }

__device__ __forceinline__ u16 f32_to_bf16(float x){
    u32 u = __float_as_uint(x);
    u += 0x7FFFu + ((u >> 16) & 1u);
    return (u16)(u >> 16);
}
__device__ __forceinline__ float bf16lo(u32 u){ return __uint_as_float((u & 0xFFFFu) << 16); }
__device__ __forceinline__ float bf16hi(u32 u){ return __uint_as_float(u & 0xFFFF0000u); }
__device__ __forceinline__ float bf16f(u16 h){ return __uint_as_float(((u32)h) << 16); }
__device__ __forceinline__ u32 pk2(float a, float b){
    return (u32)f32_to_bf16(a) | ((u32)f32_to_bf16(b) << 16);
}
// HW OCP e4m3fn converters (gfx950)
__device__ __forceinline__ u8 hw_f8(float v){
    return (u8)__builtin_amdgcn_cvt_pk_fp8_f32(v, v, 0, false);
}
__device__ __forceinline__ f32x2 hw_f8_dec2(u32 u){   // decodes bytes [0:1]
    return __builtin_amdgcn_cvt_pk_f32_fp8((int)u, false);
}
__device__ __forceinline__ f32x2 hw_f8_dec2_hi(u32 u){ // decodes bytes [2:3]
    return __builtin_amdgcn_cvt_pk_f32_fp8((int)u, true);
}

__device__ __forceinline__ float wave_max(float v){
    #pragma unroll
    for (int o = 32; o > 0; o >>= 1) v = fmaxf(v, __shfl_xor(v, o, 64));
    return v;
}
__device__ __forceinline__ float wave_sum(float v){
    #pragma unroll
    for (int o = 32; o > 0; o >>= 1) v += __shfl_xor(v, o, 64);
    return v;
}
__device__ __forceinline__ float dot8_bf16(uint4 v, const float* __restrict__ al){
    float d = 0.f;
    d = fmaf(bf16lo(v.x), al[0], d); d = fmaf(bf16hi(v.x), al[1], d);
    d = fmaf(bf16lo(v.y), al[2], d); d = fmaf(bf16hi(v.y), al[3], d);
    d = fmaf(bf16lo(v.z), al[4], d); d = fmaf(bf16hi(v.z), al[5], d);
    d = fmaf(bf16lo(v.w), al[6], d); d = fmaf(bf16hi(v.w), al[7], d);
    return d;
}

// ---------------- weight prep: fp32 -> bf16 (+ GRU B-pack) ----------------
__global__ void k_prep(const float* __restrict__ W1, const float* __restrict__ W2,
                       const float* __restrict__ Went,
                       const float* __restrict__ Wih, const float* __restrict__ Whh,
                       u16* __restrict__ W1b, u16* __restrict__ W2b,
                       u16* __restrict__ Wentb, u16* __restrict__ Bg)
{
    int i = blockIdx.x*256 + threadIdx.x;
    if (i < 20480){ W1b[i] = f32_to_bf16(W1[i]); return; }
    i -= 20480;
    if (i < 16384){ W2b[i] = f32_to_bf16(W2[i]); return; }
    i -= 16384;
    if (i < 8192){ Wentb[i] = f32_to_bf16(Went[i]); return; }
    i -= 8192;
    if (i < 131072){
        int col = i >> 8, k = i & 255;
        int g = col >> 7, j = col & 127;
        float v;
        if      (g == 0) v = (k < 128) ? Wih[j*128 + k]        : Whh[j*128 + k - 128];
        else if (g == 1) v = (k < 128) ? Wih[(128+j)*128 + k]  : Whh[(128+j)*128 + k - 128];
        else if (g == 2) v = (k < 128) ? Wih[(256+j)*128 + k]  : 0.f;
        else             v = (k < 128) ? 0.f                   : Whh[(256+j)*128 + k - 128];
        Bg[i] = f32_to_bf16(v);
    }
}

// ---------------- init ----------------
__global__ void k_zero2(int* __restrict__ a, int* __restrict__ b, int n){
    int i = blockIdx.x*256 + threadIdx.x;
    if (i < n){ a[i] = 0; b[i] = 0; }
}

// ---------------- K1 (MFMA): xe-half of Ag = bf16(lrelu(x@W^T+b)); r_dst = xe·att_r ----------------
__global__ __launch_bounds__(256, 2) void k_enter_mfma(
    const float* __restrict__ x, const u16* __restrict__ Wb, const float* __restrict__ be,
    const float* __restrict__ att_r, u16* __restrict__ Ag, float* __restrict__ r_out, int N)
{
    __shared__ __align__(16) u8 sA[64*144];
    __shared__ __align__(16) u8 sO[64*272];
    int t = threadIdx.x, w = t >> 6, lane = t & 63, l15 = lane & 15, l4 = lane >> 4;
    int tile = blockIdx.x;

    s16x8 bfr[2][2];
    #pragma unroll
    for (int kf = 0; kf < 2; ++kf)
        #pragma unroll
        for (int cf = 0; cf < 2; ++cf)
            bfr[kf][cf] = *(const s16x8*)(Wb + (size_t)(w*32 + cf*16 + l15)*64 + kf*32 + l4*8);

    int el = t >> 2, q = t & 3;
    size_t n = (size_t)tile*64 + el;
    {
        const float4* xs = (const float4*)(x + n*64 + q*16);
        float4 f0 = xs[0], f1 = xs[1], f2 = xs[2], f3 = xs[3];
        uint4 o0, o1;
        o0.x = pk2(f0.x,f0.y); o0.y = pk2(f0.z,f0.w); o0.z = pk2(f1.x,f1.y); o0.w = pk2(f1.z,f1.w);
        o1.x = pk2(f2.x,f2.y); o1.y = pk2(f2.z,f2.w); o1.z = pk2(f3.x,f3.y); o1.w = pk2(f3.z,f3.w);
        *(uint4*)(sA + el*144 + q*32)      = o0;
        *(uint4*)(sA + el*144 + q*32 + 16) = o1;
    }
    __syncthreads();

    f32x4 acc[4][2];
    #pragma unroll
    for (int rf = 0; rf < 4; ++rf){ acc[rf][0] = (f32x4)0.f; acc[rf][1] = (f32x4)0.f; }
    #pragma unroll
    for (int kf = 0; kf < 2; ++kf){
        s16x8 a[4];
        #pragma unroll
        for (int rf = 0; rf < 4; ++rf)
            a[rf] = *(const s16x8*)(sA + (rf*16 + l15)*144 + kf*64 + l4*16);
        #pragma unroll
        for (int rf = 0; rf < 4; ++rf){
            acc[rf][0] = MFMA16(a[rf], bfr[kf][0], acc[rf][0]);
            acc[rf][1] = MFMA16(a[rf], bfr[kf][1], acc[rf][1]);
        }
    }
    float b0 = be[w*32 + l15], b1 = be[w*32 + 16 + l15];
    #pragma unroll
    for (int rf = 0; rf < 4; ++rf)
        #pragma unroll
        for (int r = 0; r < 4; ++r){
            int row = rf*16 + l4*4 + r;
            *(u16*)(sO + row*272 + (w*32 + l15)*2)      = f32_to_bf16(lrelu(acc[rf][0][r] + b0));
            *(u16*)(sO + row*272 + (w*32 + 16 + l15)*2) = f32_to_bf16(lrelu(acc[rf][1][r] + b1));
        }
    __syncthreads();

    float dot = 0.f;
    #pragma unroll
    for (int i = 0; i < 4; ++i){
        uint4 v = *(const uint4*)(sO + el*272 + q*64 + 16*i);
        ((uint4*)Ag)[n*32 + 16 + q*4 + i] = v;         // xe half: byte n*512+256
        dot += dot8_bf16(v, att_r + q*32 + 8*i);
    }
    dot += __shfl_xor(dot, 1); dot += __shfl_xor(dot, 2);
    if (q == 0) r_out[n] = dot;
}

// ---------------- CSR build ----------------
__global__ void k_hist(const int* __restrict__ dst, int* __restrict__ deg, int E){
    int e = blockIdx.x*256 + threadIdx.x;
    if (e < E) atomicAdd(&deg[dst[e]], 1);
}
__global__ __launch_bounds__(256) void k_scan_a(
    const int* __restrict__ deg, int* __restrict__ rs, int* __restrict__ btot, int N)
{
    __shared__ int sd[256];
    int b = blockIdx.x, t = threadIdx.x;
    int base = b*1024 + t*4;
    int d0 = deg[base], d1 = deg[base+1], d2 = deg[base+2], d3 = deg[base+3];
    int s = d0 + d1 + d2 + d3;
    sd[t] = s; __syncthreads();
    for (int o = 1; o < 256; o <<= 1){
        int v = (t >= o) ? sd[t-o] : 0;
        __syncthreads();
        sd[t] += v;
        __syncthreads();
    }
    int ex = sd[t] - s;
    rs[base]   = ex;
    rs[base+1] = ex + d0;
    rs[base+2] = ex + d0 + d1;
    rs[base+3] = ex + d0 + d1 + d2;
    if (t == 0) btot[b] = sd[255];
}
__global__ __launch_bounds__(256) void k_scan_b(const int* __restrict__ btot, int* __restrict__ bbase){
    __shared__ int sd[256];
    int t = threadIdx.x;
    int s = btot[t];
    sd[t] = s; __syncthreads();
    for (int o = 1; o < 256; o <<= 1){
        int v = (t >= o) ? sd[t-o] : 0;
        __syncthreads();
        sd[t] += v;
        __syncthreads();
    }
    bbase[t] = sd[t] - s;
}
__global__ void k_scan_c(int* __restrict__ rs, const int* __restrict__ bbase, int N, int E){
    int i = blockIdx.x*256 + threadIdx.x;
    if (i < N) rs[i] += bbase[i >> 10];
    if (i == 0) rs[N] = E;
}
__global__ void k_scatter(const int* __restrict__ dst, const int* __restrict__ rs,
                          int* __restrict__ cnt, int* __restrict__ epos, int E){
    int e = blockIdx.x*256 + threadIdx.x;
    if (e >= E) return;
    int d = dst[e];
    int pos = rs[d] + atomicAdd(&cnt[d], 1);
    epos[e] = pos;
}

// ---------------- K2 (MFMA, 8-wave, persistent + prefetch, HW fp8) ----------------
__global__ __launch_bounds__(512, 6) void k_edge_mfma(
    const u16* __restrict__ Ag, const float* __restrict__ ea,
    const u16* __restrict__ W1b, const float* __restrict__ att_l,
    const float* __restrict__ r_dst, const int* __restrict__ src, const int* __restrict__ dst,
    const int* __restrict__ epos,
    u8* __restrict__ m, float* __restrict__ alpha, int ntiles, int E)
{
    __shared__ __align__(16) u8 sA[64*336];      // sM aliases sA (sA dead after MFMA reads)
    u8* sM = sA;
    int t = threadIdx.x, w = t >> 6, lane = t & 63, l15 = lane & 15, l4 = lane >> 4;

    s16x8 bfr[5];                 // wave w owns cols [w*16, w*16+16)
    #pragma unroll
    for (int kf = 0; kf < 5; ++kf)
        bfr[kf] = *(const s16x8*)(W1b + (size_t)(w*16 + l15)*160 + kf*32 + l4*8);

    int el = t >> 3, q = t & 7;   // 64 edges/tile, 8 threads/edge
    int stride = gridDim.x;
    int tile = blockIdx.x;

    uint4 cx0, cx1;               // prefetched 32B of xe[src[e]]
    u32 ce0, ce1;                 // prefetched 8B packed edge_attr
    {
        int e = tile*64 + el;
        if (tile < ntiles && e < E){
            int sn = src[e];
            const uint4* xs = (const uint4*)Ag + (size_t)sn*32 + 16 + q*2;
            cx0 = xs[0]; cx1 = xs[1];
            float4 f = *(const float4*)(ea + (size_t)e*32 + q*4);
            ce0 = pk2(f.x, f.y); ce1 = pk2(f.z, f.w);
        }
    }

    for (; tile < ntiles; tile += stride){
        int e = tile*64 + el;
        if (e < E){
            uint4* d = (uint4*)(sA + el*336 + q*32);
            d[0] = cx0; d[1] = cx1;
            *(u32*)(sA + el*336 + 256 + q*8)     = ce0;
            *(u32*)(sA + el*336 + 256 + q*8 + 4) = ce1;
        }
        __syncthreads();

        // issue next tile's gather; latency hides under MFMA + epilogue
        int nt = tile + stride;
        if (nt < ntiles){
            int e2 = nt*64 + el;
            if (e2 < E){
                int sn = src[e2];
                const uint4* xs = (const uint4*)Ag + (size_t)sn*32 + 16 + q*2;
                cx0 = xs[0]; cx1 = xs[1];
                float4 f = *(const float4*)(ea + (size_t)e2*32 + q*4);
                ce0 = pk2(f.x, f.y); ce1 = pk2(f.z, f.w);
            }
        }

        f32x4 acc[4];
        #pragma unroll
        for (int rf = 0; rf < 4; ++rf) acc[rf] = (f32x4)0.f;
        #pragma unroll
        for (int kf = 0; kf < 5; ++kf){
            s16x8 a[4];
            #pragma unroll
            for (int rf = 0; rf < 4; ++rf)
                a[rf] = *(const s16x8*)(sA + (rf*16 + l15)*336 + kf*64 + l4*16);
            #pragma unroll
            for (int rf = 0; rf < 4; ++rf)
                acc[rf] = MFMA16(a[rf], bfr[kf], acc[rf]);
        }
        __syncthreads();   // all sA reads done before overwriting as sM

        int col = w*16 + l15;
        #pragma unroll
        for (int rf = 0; rf < 4; ++rf)
            #pragma unroll
            for (int r = 0; r < 4; ++r){
                int row = rf*16 + l4*4 + r;
                sM[row*144 + col] = hw_f8(lrelu(acc[rf][r]));
            }
        __syncthreads();

        if (e < E){
            int p = epos[e];
            uint4 v = *(const uint4*)(sM + el*144 + q*16);
            ((uint4*)m)[(size_t)p*8 + q] = v;
            u32 ws[4] = {v.x, v.y, v.z, v.w};
            float dotv = 0.f;
            #pragma unroll
            for (int i = 0; i < 4; ++i){
                f32x2 fa = hw_f8_dec2(ws[i]);
                f32x2 fb = hw_f8_dec2_hi(ws[i]);
                const float* al = att_l + q*16 + i*4;
                dotv = fmaf(fa.x, al[0], dotv); dotv = fmaf(fa.y, al[1], dotv);
                dotv = fmaf(fb.x, al[2], dotv); dotv = fmaf(fb.y, al[3], dotv);
            }
            dotv += __shfl_xor(dotv, 1); dotv += __shfl_xor(dotv, 2); dotv += __shfl_xor(dotv, 4);
            if (q == 0) alpha[p] = lrelu(dotv + r_dst[dst[e]]);
        }
        __syncthreads();   // sM reads done before next iteration's sA write
    }
}

// ---------------- K4: streaming segment softmax + weighted sum (fp8 m, HW dec) -> bf16 a_agg ----------------
__global__ __launch_bounds__(256) void k_agg(
    const int* __restrict__ rs,
    const float* __restrict__ alpha, const u8* __restrict__ m,
    u16* __restrict__ a_out, int N)
{
    int wid  = (blockIdx.x*256 + threadIdx.x) >> 6;
    int lane = threadIdx.x & 63;
    if (wid >= N) return;
    int s = rs[wid], t = rs[wid+1];
    int deg = t - s;
    float ax = 0.f, ay = 0.f;
    if (deg > 0 && deg <= 64){
        float av = -1e38f;
        if (lane < deg) av = alpha[s + lane];
        float mx = wave_max(av);
        float ev = (lane < deg) ? __expf(av - mx) : 0.f;
        float ssum = wave_sum(ev);
        float wreg = ev / ssum;
        int k = 0;
        for (; k + 2 <= deg; k += 2){
            float w0 = __shfl(wreg, k);
            float w1 = __shfl(wreg, k + 1);
            u32 u0 = *(const u16*)(m + (size_t)(s + k)*HD + 2*lane);
            u32 u1 = *(const u16*)(m + (size_t)(s + k + 1)*HD + 2*lane);
            f32x2 f0 = hw_f8_dec2(u0);
            f32x2 f1 = hw_f8_dec2(u1);
            ax = fmaf(w0, f0.x, ax); ay = fmaf(w0, f0.y, ay);
            ax = fmaf(w1, f1.x, ax); ay = fmaf(w1, f1.y, ay);
        }
        if (k < deg){
            float w0 = __shfl(wreg, k);
            u32 u0 = *(const u16*)(m + (size_t)(s + k)*HD + 2*lane);
            f32x2 f0 = hw_f8_dec2(u0);
            ax = fmaf(w0, f0.x, ax); ay = fmaf(w0, f0.y, ay);
        }
    } else if (deg > 64){
        float mx = -1e38f;
        for (int k = lane; k < deg; k += 64) mx = fmaxf(mx, alpha[s + k]);
        mx = wave_max(mx);
        float ssum = 0.f;
        for (int k = lane; k < deg; k += 64) ssum += __expf(alpha[s + k] - mx);
        ssum = wave_sum(ssum);
        float inv = 1.f / ssum;
        for (int k = 0; k < deg; ++k){
            float wgt = __expf(alpha[s + k] - mx) * inv;
            u32 u0 = *(const u16*)(m + (size_t)(s + k)*HD + 2*lane);
            f32x2 f0 = hw_f8_dec2(u0);
            ax = fmaf(wgt, f0.x, ax);
            ay = fmaf(wgt, f0.y, ay);
        }
    }
    *(u32*)(a_out + (size_t)wid*HD + 2*lane) = pk2(ax, ay);
}

// ---------------- K5a (MFMA): h-half of Ag = bf16(elu(W2@a + bc)), a in bf16 ----------------
__global__ __launch_bounds__(256, 2) void k_conv2_mfma(
    const u16* __restrict__ a, const u16* __restrict__ W2b, const float* __restrict__ bc,
    u16* __restrict__ Ag, int N)
{
    __shared__ __align__(16) u8 sA[64*272];
    __shared__ __align__(16) u8 sO[64*272];
    int t = threadIdx.x, w = t >> 6, lane = t & 63, l15 = lane & 15, l4 = lane >> 4;
    int tile = blockIdx.x;

    s16x8 bfr[4][2];
    #pragma unroll
    for (int kf = 0; kf < 4; ++kf)
        #pragma unroll
        for (int cf = 0; cf < 2; ++cf)
            bfr[kf][cf] = *(const s16x8*)(W2b + (size_t)(w*32 + cf*16 + l15)*128 + kf*32 + l4*8);

    int el = t >> 2, q = t & 3;
    size_t n = (size_t)tile*64 + el;
    {
        const uint4* as = (const uint4*)(a + n*HD) + q*4;
        uint4 v0 = as[0], v1 = as[1], v2 = as[2], v3 = as[3];
        uint4* d = (uint4*)(sA + el*272 + q*64);
        d[0] = v0; d[1] = v1; d[2] = v2; d[3] = v3;
    }
    __syncthreads();

    f32x4 acc[4][2];
    #pragma unroll
    for (int rf = 0; rf < 4; ++rf){ acc[rf][0] = (f32x4)0.f; acc[rf][1] = (f32x4)0.f; }
    #pragma unroll
    for (int kf = 0; kf < 4; ++kf){
        s16x8 av[4];
        #pragma unroll
        for (int rf = 0; rf < 4; ++rf)
            av[rf] = *(const s16x8*)(sA + (rf*16 + l15)*272 + kf*64 + l4*16);
        #pragma unroll
        for (int rf = 0; rf < 4; ++rf){
            acc[rf][0] = MFMA16(av[rf], bfr[kf][0], acc[rf][0]);
            acc[rf][1] = MFMA16(av[rf], bfr[kf][1], acc[rf][1]);
        }
    }
    float b0 = bc[w*32 + l15], b1 = bc[w*32 + 16 + l15];
    #pragma unroll
    for (int rf = 0; rf < 4; ++rf)
        #pragma unroll
        for (int r = 0; r < 4; ++r){
            int row = rf*16 + l4*4 + r;
            *(u16*)(sO + row*272 + (w*32 + l15)*2)      = f32_to_bf16(eluf_(acc[rf][0][r] + b0));
            *(u16*)(sO + row*272 + (w*32 + 16 + l15)*2) = f32_to_bf16(eluf_(acc[rf][1][r] + b1));
        }
    __syncthreads();
    #pragma unroll
    for (int i = 0; i < 4; ++i){
        uint4 v = *(const uint4*)(sO + el*272 + q*64 + 16*i);
        ((uint4*)Ag)[n*32 + q*4 + i] = v;              // h half: byte n*512
    }
}

// ---------------- K5b (MFMA): GRU cell + fused LayerNorm -> out ----------------
__global__ __launch_bounds__(512, 2) void k_gru_mfma(
    const u16* __restrict__ Ag, const u16* __restrict__ Bg,
    const float* __restrict__ bih, const float* __restrict__ bhh,
    float* __restrict__ out, int N, int ntiles)
{
    __shared__ __align__(16) u8 sA[32*528];
    __shared__ __align__(16) float sOut[32*132];     // +4 pad breaks write conflicts
    int t = threadIdx.x, w = t >> 6, lane = t & 63, l15 = lane & 15, l4 = lane >> 4;

    s16x8 bfr[8][4];
    #pragma unroll
    for (int g = 0; g < 4; ++g){
        int col = g*128 + w*16 + l15;
        #pragma unroll
        for (int kf = 0; kf < 8; ++kf)
            bfr[kf][g] = *(const s16x8*)(Bg + (size_t)col*256 + kf*32 + l4*8);
    }
    int j = w*16 + l15;
    float rb = bih[j] + bhh[j];
    float zb = bih[128 + j] + bhh[128 + j];
    float ib = bih[256 + j];
    float hb = bhh[256 + j];

    for (int tile = blockIdx.x; tile < ntiles; tile += gridDim.x){
        {
            int el = t >> 4, part = t & 15;
            const uint4* gsrc = (const uint4*)Ag + ((size_t)tile*32 + el)*32 + part*2;
            uint4 v0 = gsrc[0], v1 = gsrc[1];
            uint4* d = (uint4*)(sA + el*528 + part*32);
            d[0] = v0; d[1] = v1;
        }
        __syncthreads();

        f32x4 acc[2][4];
        #pragma unroll
        for (int rf = 0; rf < 2; ++rf)
            #pragma unroll
            for (int g = 0; g < 4; ++g) acc[rf][g] = (f32x4)0.f;
        #pragma unroll
        for (int kf = 0; kf < 8; ++kf){
            s16x8 a0 = *(const s16x8*)(sA + l15*528 + kf*64 + l4*16);
            s16x8 a1 = *(const s16x8*)(sA + (16 + l15)*528 + kf*64 + l4*16);
            #pragma unroll
            for (int g = 0; g < 4; ++g){
                acc[0][g] = MFMA16(a0, bfr[kf][g], acc[0][g]);
                acc[1][g] = MFMA16(a1, bfr[kf][g], acc[1][g]);
            }
        }
        #pragma unroll
        for (int rf = 0; rf < 2; ++rf)
            #pragma unroll
            for (int r = 0; r < 4; ++r){
                int rl = rf*16 + l4*4 + r;
                float rr = sigmoidf_(acc[rf][0][r] + rb);
                float zz = sigmoidf_(acc[rf][1][r] + zb);
                float iv = acc[rf][2][r] + ib;
                float hv = acc[rf][3][r] + hb;
                float nc = tanhf_(iv + rr*hv);
                float xej = bf16f(*(const u16*)(sA + rl*528 + 256 + 2*j));
                float v = (1.f - zz)*nc + zz*xej;
                v = fmaxf(v, 0.f);
                sOut[rl*132 + j] = v;
            }
        __syncthreads();
        {
            int row = t >> 4, sub = t & 15;          // 16 threads/row, same wave
            const float* rp = sOut + row*132 + sub*8;
            float v0 = rp[0], v1 = rp[1], v2 = rp[2], v3 = rp[3];
            float v4 = rp[4], v5 = rp[5], v6 = rp[6], v7 = rp[7];
            float s1 = v0+v1+v2+v3+v4+v5+v6+v7;
            float s2 = v0*v0+v1*v1+v2*v2+v3*v3+v4*v4+v5*v5+v6*v6+v7*v7;
            #pragma unroll
            for (int o = 1; o < 16; o <<= 1){ s1 += __shfl_xor(s1, o); s2 += __shfl_xor(s2, o); }
            float mu  = s1 * (1.f/128.f);
            float var = s2 * (1.f/128.f) - mu*mu;
            var = fmaxf(var, 0.f);
            float rsd = rsqrtf(var + 1e-5f);
            float* op = out + ((size_t)tile*32 + row)*128 + sub*8;
            float4 o0, o1;
            o0.x = (v0-mu)*rsd; o0.y = (v1-mu)*rsd; o0.z = (v2-mu)*rsd; o0.w = (v3-mu)*rsd;
            o1.x = (v4-mu)*rsd; o1.y = (v5-mu)*rsd; o1.z = (v6-mu)*rsd; o1.w = (v7-mu)*rsd;
            ((float4*)op)[0] = o0; ((float4*)op)[1] = o1;
        }
        __syncthreads();
    }
}

// ---------------- host ----------------
extern "C" void kernel_launch(void* const* d_in, const int* in_sizes, int n_in,
                              void* d_out, int out_size, void* d_ws, size_t ws_size,
                              hipStream_t stream)
{
    const float* x       = (const float*)d_in[0];
    const float* ea      = (const float*)d_in[1];
    const float* W_enter = (const float*)d_in[2];
    const float* b_enter = (const float*)d_in[3];
    const float* W1      = (const float*)d_in[4];
    const float* att_l   = (const float*)d_in[5];
    const float* att_r   = (const float*)d_in[6];
    const float* W2      = (const float*)d_in[7];
    const float* b_conv  = (const float*)d_in[8];
    const float* W_ih    = (const float*)d_in[9];
    const float* W_hh    = (const float*)d_in[10];
    const float* b_ih    = (const float*)d_in[11];
    const float* b_hh    = (const float*)d_in[12];
    const int*   eidx    = (const int*)d_in[13];

    int N = in_sizes[0] / DIN;
    int E = in_sizes[13] / 2;
    const int* src = eidx;
    const int* dst = eidx + E;
    float* out = (float*)d_out;

    size_t off = 0;
    char* base = (char*)d_ws;
    auto alloc = [&](size_t bytes) -> char* {
        char* p = base + off;
        off = (off + bytes + 255) & ~(size_t)255;
        return p;
    };
    u16*   Ag    = (u16*)  alloc((size_t)N*256*2);   // [h | xe] bf16
    float* r_dst = (float*)alloc((size_t)N*4);
    float* alpha = (float*)alloc((size_t)E*4);
    int*   deg   = (int*)  alloc((size_t)N*4);
    int*   rs    = (int*)  alloc((size_t)(N+1)*4);
    int*   cnt   = (int*)  alloc((size_t)N*4);
    int*   epos  = (int*)  alloc((size_t)E*4);
    int*   btot  = (int*)  alloc(1024);
    int*   bbase = (int*)  alloc(1024);
    u16*   W1b   = (u16*)  alloc(20480*2);
    u16*   W2b   = (u16*)  alloc(16384*2);
    u16*   Wentb = (u16*)  alloc(8192*2);
    u16*   Bg    = (u16*)  alloc(131072*2);
    u8*    mbuf  = (u8*)   alloc((size_t)E*HD);      // fp8 m, CSR-sorted

    u16* a_agg = (u16*)out;   // d_out reused as bf16 a_agg (dead before k_gru writes)

    int ntiles_n64 = N/64, ntiles_e = (E + 63)/64, ntiles_g = N/32;

    k_prep   <<<(176128+255)/256, 256, 0, stream>>>(W1, W2, W_enter, W_ih, W_hh, W1b, W2b, Wentb, Bg);
    k_zero2  <<<(N+255)/256, 256, 0, stream>>>(deg, cnt, N);
    k_enter_mfma<<<ntiles_n64, 256, 0, stream>>>(x, Wentb, b_enter, att_r, Ag, r_dst, N);
    k_hist   <<<(E+255)/256, 256, 0, stream>>>(dst, deg, E);
    k_scan_a <<<N/1024, 256, 0, stream>>>(deg, rs, btot, N);
    k_scan_b <<<1, 256, 0, stream>>>(btot, bbase);
    k_scan_c <<<(N+255)/256, 256, 0, stream>>>(rs, bbase, N, E);
    k_scatter<<<(E+255)/256, 256, 0, stream>>>(dst, rs, cnt, epos, E);
    k_edge_mfma<<<768, 512, 0, stream>>>(Ag, ea, W1b, att_l, r_dst, src, dst, epos,
                                         mbuf, alpha, ntiles_e, E);
    k_agg    <<<(N+3)/4, 256, 0, stream>>>(rs, alpha, mbuf, a_agg, N);
    k_conv2_mfma<<<ntiles_n64, 256, 0, stream>>>(a_agg, W2b, b_conv, Ag, N);
    k_gru_mfma  <<<2048, 512, 0, stream>>>(Ag, Bg, b_ih, b_hh, out, N, ntiles_g);
}

// Round 8
// 635.576 us; speedup vs baseline: 8.3685x; 1.0390x over previous
//
#include <hip/hip_runtime.h>
#include <stdint.h>

#define HD  128
#define DIN 64
#define DE  32

typedef unsigned int u32; typedef unsigned short u16; typedef unsigned char u8;
typedef short s16x8 __attribute__((ext_vector_type(8)));
typedef float f32x4 __attribute__((ext_vector_type(4)));
typedef float f32x2 __attribute__((ext_vector_type(2)));

#define MFMA16(a,b,c) __builtin_amdgcn_mfma_f32_16x16x32_bf16((a),(b),(c),0,0,0)

__device__ __forceinline__ float lrelu(float x){ return x > 0.f ? x : 0.01f*x; }
__device__ __forceinline__ float sigmoidf_(float x){ return 1.f/(1.f + __expf(-x)); }
__device__ __forceinline__ float tanhf_(float x){
    float t = fminf(fmaxf(x, -15.f), 15.f);
    float e = __expf(2.f*t);
    return (e - 1.f)/(e + 1.f);
}
__device__ __forceinline__ float eluf_(float x){ return x > 0.f ? x : expm1f(x); }

__device__ __forceinline__ u16 f32_to_bf16(float x){
    u32 u = __float_as_uint(x);
    u += 0x7FFFu + ((u >> 16) & 1u);
    return (u16)(u >> 16);
}
__device__ __forceinline__ float bf16lo(u32 u){ return __uint_as_float((u & 0xFFFFu) << 16); }
__device__ __forceinline__ float bf16hi(u32 u){ return __uint_as_float(u & 0xFFFF0000u); }
__device__ __forceinline__ float bf16f(u16 h){ return __uint_as_float(((u32)h) << 16); }
__device__ __forceinline__ u32 pk2(float a, float b){
    return (u32)f32_to_bf16(a) | ((u32)f32_to_bf16(b) << 16);
}
// HW OCP e4m3fn converters (gfx950)
__device__ __forceinline__ u8 hw_f8(float v){
    return (u8)__builtin_amdgcn_cvt_pk_fp8_f32(v, v, 0, false);
}
__device__ __forceinline__ f32x2 hw_f8_dec2(u32 u){   // decodes bytes [0:1]
    return __builtin_amdgcn_cvt_pk_f32_fp8((int)u, false);
}
__device__ __forceinline__ f32x2 hw_f8_dec2_hi(u32 u){ // decodes bytes [2:3]
    return __builtin_amdgcn_cvt_pk_f32_fp8((int)u, true);
}

__device__ __forceinline__ float wave_max(float v){
    #pragma unroll
    for (int o = 32; o > 0; o >>= 1) v = fmaxf(v, __shfl_xor(v, o, 64));
    return v;
}
__device__ __forceinline__ float wave_sum(float v){
    #pragma unroll
    for (int o = 32; o > 0; o >>= 1) v += __shfl_xor(v, o, 64);
    return v;
}
__device__ __forceinline__ float dot8_bf16(uint4 v, const float* __restrict__ al){
    float d = 0.f;
    d = fmaf(bf16lo(v.x), al[0], d); d = fmaf(bf16hi(v.x), al[1], d);
    d = fmaf(bf16lo(v.y), al[2], d); d = fmaf(bf16hi(v.y), al[3], d);
    d = fmaf(bf16lo(v.z), al[4], d); d = fmaf(bf16hi(v.z), al[5], d);
    d = fmaf(bf16lo(v.w), al[6], d); d = fmaf(bf16hi(v.w), al[7], d);
    return d;
}

// ---------------- weight prep: fp32 -> bf16 (+ GRU B-pack) ----------------
__global__ void k_prep(const float* __restrict__ W1, const float* __restrict__ W2,
                       const float* __restrict__ Went,
                       const float* __restrict__ Wih, const float* __restrict__ Whh,
                       u16* __restrict__ W1b, u16* __restrict__ W2b,
                       u16* __restrict__ Wentb, u16* __restrict__ Bg)
{
    int i = blockIdx.x*256 + threadIdx.x;
    if (i < 20480){ W1b[i] = f32_to_bf16(W1[i]); return; }
    i -= 20480;
    if (i < 16384){ W2b[i] = f32_to_bf16(W2[i]); return; }
    i -= 16384;
    if (i < 8192){ Wentb[i] = f32_to_bf16(Went[i]); return; }
    i -= 8192;
    if (i < 131072){
        int col = i >> 8, k = i & 255;
        int g = col >> 7, j = col & 127;
        float v;
        if      (g == 0) v = (k < 128) ? Wih[j*128 + k]        : Whh[j*128 + k - 128];
        else if (g == 1) v = (k < 128) ? Wih[(128+j)*128 + k]  : Whh[(128+j)*128 + k - 128];
        else if (g == 2) v = (k < 128) ? Wih[(256+j)*128 + k]  : 0.f;
        else             v = (k < 128) ? 0.f                   : Whh[(256+j)*128 + k - 128];
        Bg[i] = f32_to_bf16(v);
    }
}

// ---------------- init ----------------
__global__ void k_zero2(int* __restrict__ a, int* __restrict__ b, int n){
    int i = blockIdx.x*256 + threadIdx.x;
    if (i < n){ a[i] = 0; b[i] = 0; }
}

// ---------------- K1 (MFMA): xe-half of Ag = bf16(lrelu(x@W^T+b)); r_dst = xe·att_r ----------------
__global__ __launch_bounds__(256, 2) void k_enter_mfma(
    const float* __restrict__ x, const u16* __restrict__ Wb, const float* __restrict__ be,
    const float* __restrict__ att_r, u16* __restrict__ Ag, float* __restrict__ r_out, int N)
{
    __shared__ __align__(16) u8 sA[64*144];
    __shared__ __align__(16) u8 sO[64*272];
    int t = threadIdx.x, w = t >> 6, lane = t & 63, l15 = lane & 15, l4 = lane >> 4;
    int tile = blockIdx.x;

    s16x8 bfr[2][2];
    #pragma unroll
    for (int kf = 0; kf < 2; ++kf)
        #pragma unroll
        for (int cf = 0; cf < 2; ++cf)
            bfr[kf][cf] = *(const s16x8*)(Wb + (size_t)(w*32 + cf*16 + l15)*64 + kf*32 + l4*8);

    int el = t >> 2, q = t & 3;
    size_t n = (size_t)tile*64 + el;
    {
        const float4* xs = (const float4*)(x + n*64 + q*16);
        float4 f0 = xs[0], f1 = xs[1], f2 = xs[2], f3 = xs[3];
        uint4 o0, o1;
        o0.x = pk2(f0.x,f0.y); o0.y = pk2(f0.z,f0.w); o0.z = pk2(f1.x,f1.y); o0.w = pk2(f1.z,f1.w);
        o1.x = pk2(f2.x,f2.y); o1.y = pk2(f2.z,f2.w); o1.z = pk2(f3.x,f3.y); o1.w = pk2(f3.z,f3.w);
        *(uint4*)(sA + el*144 + q*32)      = o0;
        *(uint4*)(sA + el*144 + q*32 + 16) = o1;
    }
    __syncthreads();

    f32x4 acc[4][2];
    #pragma unroll
    for (int rf = 0; rf < 4; ++rf){ acc[rf][0] = (f32x4)0.f; acc[rf][1] = (f32x4)0.f; }
    #pragma unroll
    for (int kf = 0; kf < 2; ++kf){
        s16x8 a[4];
        #pragma unroll
        for (int rf = 0; rf < 4; ++rf)
            a[rf] = *(const s16x8*)(sA + (rf*16 + l15)*144 + kf*64 + l4*16);
        #pragma unroll
        for (int rf = 0; rf < 4; ++rf){
            acc[rf][0] = MFMA16(a[rf], bfr[kf][0], acc[rf][0]);
            acc[rf][1] = MFMA16(a[rf], bfr[kf][1], acc[rf][1]);
        }
    }
    float b0 = be[w*32 + l15], b1 = be[w*32 + 16 + l15];
    #pragma unroll
    for (int rf = 0; rf < 4; ++rf)
        #pragma unroll
        for (int r = 0; r < 4; ++r){
            int row = rf*16 + l4*4 + r;
            *(u16*)(sO + row*272 + (w*32 + l15)*2)      = f32_to_bf16(lrelu(acc[rf][0][r] + b0));
            *(u16*)(sO + row*272 + (w*32 + 16 + l15)*2) = f32_to_bf16(lrelu(acc[rf][1][r] + b1));
        }
    __syncthreads();

    float dot = 0.f;
    #pragma unroll
    for (int i = 0; i < 4; ++i){
        uint4 v = *(const uint4*)(sO + el*272 + q*64 + 16*i);
        ((uint4*)Ag)[n*32 + 16 + q*4 + i] = v;         // xe half: byte n*512+256
        dot += dot8_bf16(v, att_r + q*32 + 8*i);
    }
    dot += __shfl_xor(dot, 1); dot += __shfl_xor(dot, 2);
    if (q == 0) r_out[n] = dot;
}

// ---------------- CSR build ----------------
__global__ void k_hist(const int* __restrict__ dst, int* __restrict__ deg, int E){
    int e = blockIdx.x*256 + threadIdx.x;
    if (e < E) atomicAdd(&deg[dst[e]], 1);
}
__global__ __launch_bounds__(256) void k_scan_a(
    const int* __restrict__ deg, int* __restrict__ rs, int* __restrict__ btot, int N)
{
    __shared__ int sd[256];
    int b = blockIdx.x, t = threadIdx.x;
    int base = b*1024 + t*4;
    int d0 = deg[base], d1 = deg[base+1], d2 = deg[base+2], d3 = deg[base+3];
    int s = d0 + d1 + d2 + d3;
    sd[t] = s; __syncthreads();
    for (int o = 1; o < 256; o <<= 1){
        int v = (t >= o) ? sd[t-o] : 0;
        __syncthreads();
        sd[t] += v;
        __syncthreads();
    }
    int ex = sd[t] - s;
    rs[base]   = ex;
    rs[base+1] = ex + d0;
    rs[base+2] = ex + d0 + d1;
    rs[base+3] = ex + d0 + d1 + d2;
    if (t == 0) btot[b] = sd[255];
}
__global__ __launch_bounds__(256) void k_scan_b(const int* __restrict__ btot, int* __restrict__ bbase){
    __shared__ int sd[256];
    int t = threadIdx.x;
    int s = btot[t];
    sd[t] = s; __syncthreads();
    for (int o = 1; o < 256; o <<= 1){
        int v = (t >= o) ? sd[t-o] : 0;
        __syncthreads();
        sd[t] += v;
        __syncthreads();
    }
    bbase[t] = sd[t] - s;
}
__global__ void k_scan_c(int* __restrict__ rs, const int* __restrict__ bbase, int N, int E){
    int i = blockIdx.x*256 + threadIdx.x;
    if (i < N) rs[i] += bbase[i >> 10];
    if (i == 0) rs[N] = E;
}
__global__ void k_scatter(const int* __restrict__ dst, const int* __restrict__ rs,
                          int* __restrict__ cnt, int* __restrict__ epos, int E){
    int e = blockIdx.x*256 + threadIdx.x;
    if (e >= E) return;
    int d = dst[e];
    int pos = rs[d] + atomicAdd(&cnt[d], 1);
    epos[e] = pos;
}

// ---------------- K2 (MFMA, 8-wave, persistent + prefetch, HW fp8) ----------------
__global__ __launch_bounds__(512, 6) void k_edge_mfma(
    const u16* __restrict__ Ag, const float* __restrict__ ea,
    const u16* __restrict__ W1b, const float* __restrict__ att_l,
    const float* __restrict__ r_dst, const int* __restrict__ src, const int* __restrict__ dst,
    const int* __restrict__ epos,
    u8* __restrict__ m, float* __restrict__ alpha, int ntiles, int E)
{
    __shared__ __align__(16) u8 sA[64*336];      // sM aliases sA (sA dead after MFMA reads)
    u8* sM = sA;
    int t = threadIdx.x, w = t >> 6, lane = t & 63, l15 = lane & 15, l4 = lane >> 4;

    s16x8 bfr[5];                 // wave w owns cols [w*16, w*16+16)
    #pragma unroll
    for (int kf = 0; kf < 5; ++kf)
        bfr[kf] = *(const s16x8*)(W1b + (size_t)(w*16 + l15)*160 + kf*32 + l4*8);

    int el = t >> 3, q = t & 7;   // 64 edges/tile, 8 threads/edge
    int stride = gridDim.x;
    int tile = blockIdx.x;

    uint4 cx0, cx1;               // prefetched 32B of xe[src[e]]
    u32 ce0, ce1;                 // prefetched 8B packed edge_attr
    {
        int e = tile*64 + el;
        if (tile < ntiles && e < E){
            int sn = src[e];
            const uint4* xs = (const uint4*)Ag + (size_t)sn*32 + 16 + q*2;
            cx0 = xs[0]; cx1 = xs[1];
            float4 f = *(const float4*)(ea + (size_t)e*32 + q*4);
            ce0 = pk2(f.x, f.y); ce1 = pk2(f.z, f.w);
        }
    }

    for (; tile < ntiles; tile += stride){
        int e = tile*64 + el;
        if (e < E){
            uint4* d = (uint4*)(sA + el*336 + q*32);
            d[0] = cx0; d[1] = cx1;
            *(u32*)(sA + el*336 + 256 + q*8)     = ce0;
            *(u32*)(sA + el*336 + 256 + q*8 + 4) = ce1;
        }
        __syncthreads();

        // issue next tile's gather; latency hides under MFMA + epilogue
        int nt = tile + stride;
        if (nt < ntiles){
            int e2 = nt*64 + el;
            if (e2 < E){
                int sn = src[e2];
                const uint4* xs = (const uint4*)Ag + (size_t)sn*32 + 16 + q*2;
                cx0 = xs[0]; cx1 = xs[1];
                float4 f = *(const float4*)(ea + (size_t)e2*32 + q*4);
                ce0 = pk2(f.x, f.y); ce1 = pk2(f.z, f.w);
            }
        }

        f32x4 acc[4];
        #pragma unroll
        for (int rf = 0; rf < 4; ++rf) acc[rf] = (f32x4)0.f;
        #pragma unroll
        for (int kf = 0; kf < 5; ++kf){
            s16x8 a[4];
            #pragma unroll
            for (int rf = 0; rf < 4; ++rf)
                a[rf] = *(const s16x8*)(sA + (rf*16 + l15)*336 + kf*64 + l4*16);
            #pragma unroll
            for (int rf = 0; rf < 4; ++rf)
                acc[rf] = MFMA16(a[rf], bfr[kf], acc[rf]);
        }
        __syncthreads();   // all sA reads done before overwriting as sM

        int col = w*16 + l15;
        #pragma unroll
        for (int rf = 0; rf < 4; ++rf)
            #pragma unroll
            for (int r = 0; r < 4; ++r){
                int row = rf*16 + l4*4 + r;
                sM[row*144 + col] = hw_f8(lrelu(acc[rf][r]));
            }
        __syncthreads();

        if (e < E){
            int p = epos[e];
            uint4 v = *(const uint4*)(sM + el*144 + q*16);
            ((uint4*)m)[(size_t)p*8 + q] = v;
            u32 ws[4] = {v.x, v.y, v.z, v.w};
            float dotv = 0.f;
            #pragma unroll
            for (int i = 0; i < 4; ++i){
                f32x2 fa = hw_f8_dec2(ws[i]);
                f32x2 fb = hw_f8_dec2_hi(ws[i]);
                const float* al = att_l + q*16 + i*4;
                dotv = fmaf(fa.x, al[0], dotv); dotv = fmaf(fa.y, al[1], dotv);
                dotv = fmaf(fb.x, al[2], dotv); dotv = fmaf(fb.y, al[3], dotv);
            }
            dotv += __shfl_xor(dotv, 1); dotv += __shfl_xor(dotv, 2); dotv += __shfl_xor(dotv, 4);
            if (q == 0) alpha[p] = lrelu(dotv + r_dst[dst[e]]);
        }
        __syncthreads();   // sM reads done before next iteration's sA write
    }
}

// ---------------- K4: streaming segment softmax + weighted sum (fp8 m, HW dec) -> bf16 a_agg ----------------
__global__ __launch_bounds__(256) void k_agg(
    const int* __restrict__ rs,
    const float* __restrict__ alpha, const u8* __restrict__ m,
    u16* __restrict__ a_out, int N)
{
    int wid  = (blockIdx.x*256 + threadIdx.x) >> 6;
    int lane = threadIdx.x & 63;
    if (wid >= N) return;
    int s = rs[wid], t = rs[wid+1];
    int deg = t - s;
    float ax = 0.f, ay = 0.f;
    if (deg > 0 && deg <= 64){
        float av = -1e38f;
        if (lane < deg) av = alpha[s + lane];
        float mx = wave_max(av);
        float ev = (lane < deg) ? __expf(av - mx) : 0.f;
        float ssum = wave_sum(ev);
        float wreg = ev / ssum;
        int k = 0;
        for (; k + 2 <= deg; k += 2){
            float w0 = __shfl(wreg, k);
            float w1 = __shfl(wreg, k + 1);
            u32 u0 = *(const u16*)(m + (size_t)(s + k)*HD + 2*lane);
            u32 u1 = *(const u16*)(m + (size_t)(s + k + 1)*HD + 2*lane);
            f32x2 f0 = hw_f8_dec2(u0);
            f32x2 f1 = hw_f8_dec2(u1);
            ax = fmaf(w0, f0.x, ax); ay = fmaf(w0, f0.y, ay);
            ax = fmaf(w1, f1.x, ax); ay = fmaf(w1, f1.y, ay);
        }
        if (k < deg){
            float w0 = __shfl(wreg, k);
            u32 u0 = *(const u16*)(m + (size_t)(s + k)*HD + 2*lane);
            f32x2 f0 = hw_f8_dec2(u0);
            ax = fmaf(w0, f0.x, ax); ay = fmaf(w0, f0.y, ay);
        }
    } else if (deg > 64){
        float mx = -1e38f;
        for (int k = lane; k < deg; k += 64) mx = fmaxf(mx, alpha[s + k]);
        mx = wave_max(mx);
        float ssum = 0.f;
        for (int k = lane; k < deg; k += 64) ssum += __expf(alpha[s + k] - mx);
        ssum = wave_sum(ssum);
        float inv = 1.f / ssum;
        for (int k = 0; k < deg; ++k){
            float wgt = __expf(alpha[s + k] - mx) * inv;
            u32 u0 = *(const u16*)(m + (size_t)(s + k)*HD + 2*lane);
            f32x2 f0 = hw_f8_dec2(u0);
            ax = fmaf(wgt, f0.x, ax);
            ay = fmaf(wgt, f0.y, ay);
        }
    }
    *(u32*)(a_out + (size_t)wid*HD + 2*lane) = pk2(ax, ay);
}

// ---------------- K5a (MFMA): h-half of Ag = bf16(elu(W2@a + bc)), a in bf16 ----------------
__global__ __launch_bounds__(256, 2) void k_conv2_mfma(
    const u16* __restrict__ a, const u16* __restrict__ W2b, const float* __restrict__ bc,
    u16* __restrict__ Ag, int N)
{
    __shared__ __align__(16) u8 sA[64*272];
    __shared__ __align__(16) u8 sO[64*272];
    int t = threadIdx.x, w = t >> 6, lane = t & 63, l15 = lane & 15, l4 = lane >> 4;
    int tile = blockIdx.x;

    s16x8 bfr[4][2];
    #pragma unroll
    for (int kf = 0; kf < 4; ++kf)
        #pragma unroll
        for (int cf = 0; cf < 2; ++cf)
            bfr[kf][cf] = *(const s16x8*)(W2b + (size_t)(w*32 + cf*16 + l15)*128 + kf*32 + l4*8);

    int el = t >> 2, q = t & 3;
    size_t n = (size_t)tile*64 + el;
    {
        const uint4* as = (const uint4*)(a + n*HD) + q*4;
        uint4 v0 = as[0], v1 = as[1], v2 = as[2], v3 = as[3];
        uint4* d = (uint4*)(sA + el*272 + q*64);
        d[0] = v0; d[1] = v1; d[2] = v2; d[3] = v3;
    }
    __syncthreads();

    f32x4 acc[4][2];
    #pragma unroll
    for (int rf = 0; rf < 4; ++rf){ acc[rf][0] = (f32x4)0.f; acc[rf][1] = (f32x4)0.f; }
    #pragma unroll
    for (int kf = 0; kf < 4; ++kf){
        s16x8 av[4];
        #pragma unroll
        for (int rf = 0; rf < 4; ++rf)
            av[rf] = *(const s16x8*)(sA + (rf*16 + l15)*272 + kf*64 + l4*16);
        #pragma unroll
        for (int rf = 0; rf < 4; ++rf){
            acc[rf][0] = MFMA16(av[rf], bfr[kf][0], acc[rf][0]);
            acc[rf][1] = MFMA16(av[rf], bfr[kf][1], acc[rf][1]);
        }
    }
    float b0 = bc[w*32 + l15], b1 = bc[w*32 + 16 + l15];
    #pragma unroll
    for (int rf = 0; rf < 4; ++rf)
        #pragma unroll
        for (int r = 0; r < 4; ++r){
            int row = rf*16 + l4*4 + r;
            *(u16*)(sO + row*272 + (w*32 + l15)*2)      = f32_to_bf16(eluf_(acc[rf][0][r] + b0));
            *(u16*)(sO + row*272 + (w*32 + 16 + l15)*2) = f32_to_bf16(eluf_(acc[rf][1][r] + b1));
        }
    __syncthreads();
    #pragma unroll
    for (int i = 0; i < 4; ++i){
        uint4 v = *(const uint4*)(sO + el*272 + q*64 + 16*i);
        ((uint4*)Ag)[n*32 + q*4 + i] = v;              // h half: byte n*512
    }
}

// ---------------- K5b (MFMA): GRU cell + fused LayerNorm -> out ----------------
// Zero-skip B-pack: gate2 (in) only K<128, gate3 (hn) only K>=128.
__global__ __launch_bounds__(512, 3) void k_gru_mfma(
    const u16* __restrict__ Ag, const u16* __restrict__ Bg,
    const float* __restrict__ bih, const float* __restrict__ bhh,
    float* __restrict__ out, int N, int ntiles)
{
    __shared__ __align__(16) u8 sA[32*528];
    __shared__ __align__(16) float sOut[32*132];     // +4 pad breaks write conflicts
    int t = threadIdx.x, w = t >> 6, lane = t & 63, l15 = lane & 15, l4 = lane >> 4;

    s16x8 bfr0[8], bfr1[8], bfr2[4], bfr3[4];        // 24 frags = 96 VGPR (was 32/128)
    {
        int jc = w*16 + l15;
        #pragma unroll
        for (int kf = 0; kf < 8; ++kf){
            bfr0[kf] = *(const s16x8*)(Bg + (size_t)(jc)*256       + kf*32 + l4*8);
            bfr1[kf] = *(const s16x8*)(Bg + (size_t)(128 + jc)*256 + kf*32 + l4*8);
        }
        #pragma unroll
        for (int kf = 0; kf < 4; ++kf){
            bfr2[kf] = *(const s16x8*)(Bg + (size_t)(256 + jc)*256 + kf*32 + l4*8);
            bfr3[kf] = *(const s16x8*)(Bg + (size_t)(384 + jc)*256 + (kf+4)*32 + l4*8);
        }
    }
    int j = w*16 + l15;
    float rb = bih[j] + bhh[j];
    float zb = bih[128 + j] + bhh[128 + j];
    float ib = bih[256 + j];
    float hb = bhh[256 + j];

    int el = t >> 4, part = t & 15;
    int stride = gridDim.x;
    int tile = blockIdx.x;
    uint4 pv0, pv1;               // prefetched A chunk
    if (tile < ntiles){
        const uint4* gsrc = (const uint4*)Ag + ((size_t)tile*32 + el)*32 + part*2;
        pv0 = gsrc[0]; pv1 = gsrc[1];
    }

    for (; tile < ntiles; tile += stride){
        {
            uint4* d = (uint4*)(sA + el*528 + part*32);
            d[0] = pv0; d[1] = pv1;
        }
        __syncthreads();

        int nt = tile + stride;
        if (nt < ntiles){
            const uint4* gsrc = (const uint4*)Ag + ((size_t)nt*32 + el)*32 + part*2;
            pv0 = gsrc[0]; pv1 = gsrc[1];
        }

        f32x4 acc[2][4];
        #pragma unroll
        for (int rf = 0; rf < 2; ++rf)
            #pragma unroll
            for (int g = 0; g < 4; ++g) acc[rf][g] = (f32x4)0.f;
        #pragma unroll
        for (int kf = 0; kf < 8; ++kf){
            s16x8 a0 = *(const s16x8*)(sA + l15*528 + kf*64 + l4*16);
            s16x8 a1 = *(const s16x8*)(sA + (16 + l15)*528 + kf*64 + l4*16);
            acc[0][0] = MFMA16(a0, bfr0[kf], acc[0][0]);
            acc[1][0] = MFMA16(a1, bfr0[kf], acc[1][0]);
            acc[0][1] = MFMA16(a0, bfr1[kf], acc[0][1]);
            acc[1][1] = MFMA16(a1, bfr1[kf], acc[1][1]);
            if (kf < 4){
                acc[0][2] = MFMA16(a0, bfr2[kf], acc[0][2]);
                acc[1][2] = MFMA16(a1, bfr2[kf], acc[1][2]);
            } else {
                acc[0][3] = MFMA16(a0, bfr3[kf-4], acc[0][3]);
                acc[1][3] = MFMA16(a1, bfr3[kf-4], acc[1][3]);
            }
        }
        #pragma unroll
        for (int rf = 0; rf < 2; ++rf)
            #pragma unroll
            for (int r = 0; r < 4; ++r){
                int rl = rf*16 + l4*4 + r;
                float rr = sigmoidf_(acc[rf][0][r] + rb);
                float zz = sigmoidf_(acc[rf][1][r] + zb);
                float iv = acc[rf][2][r] + ib;
                float hv = acc[rf][3][r] + hb;
                float nc = tanhf_(iv + rr*hv);
                float xej = bf16f(*(const u16*)(sA + rl*528 + 256 + 2*j));
                float v = (1.f - zz)*nc + zz*xej;
                v = fmaxf(v, 0.f);
                sOut[rl*132 + j] = v;
            }
        __syncthreads();
        {
            int row = t >> 4, sub = t & 15;          // 16 threads/row, same wave
            const float* rp = sOut + row*132 + sub*8;
            float v0 = rp[0], v1 = rp[1], v2 = rp[2], v3 = rp[3];
            float v4 = rp[4], v5 = rp[5], v6 = rp[6], v7 = rp[7];
            float s1 = v0+v1+v2+v3+v4+v5+v6+v7;
            float s2 = v0*v0+v1*v1+v2*v2+v3*v3+v4*v4+v5*v5+v6*v6+v7*v7;
            #pragma unroll
            for (int o = 1; o < 16; o <<= 1){ s1 += __shfl_xor(s1, o); s2 += __shfl_xor(s2, o); }
            float mu  = s1 * (1.f/128.f);
            float var = s2 * (1.f/128.f) - mu*mu;
            var = fmaxf(var, 0.f);
            float rsd = rsqrtf(var + 1e-5f);
            float* op = out + ((size_t)tile*32 + row)*128 + sub*8;
            float4 o0, o1;
            o0.x = (v0-mu)*rsd; o0.y = (v1-mu)*rsd; o0.z = (v2-mu)*rsd; o0.w = (v3-mu)*rsd;
            o1.x = (v4-mu)*rsd; o1.y = (v5-mu)*rsd; o1.z = (v6-mu)*rsd; o1.w = (v7-mu)*rsd;
            ((float4*)op)[0] = o0; ((float4*)op)[1] = o1;
        }
        __syncthreads();
    }
}

// ---------------- host ----------------
extern "C" void kernel_launch(void* const* d_in, const int* in_sizes, int n_in,
                              void* d_out, int out_size, void* d_ws, size_t ws_size,
                              hipStream_t stream)
{
    const float* x       = (const float*)d_in[0];
    const float* ea      = (const float*)d_in[1];
    const float* W_enter = (const float*)d_in[2];
    const float* b_enter = (const float*)d_in[3];
    const float* W1      = (const float*)d_in[4];
    const float* att_l   = (const float*)d_in[5];
    const float* att_r   = (const float*)d_in[6];
    const float* W2      = (const float*)d_in[7];
    const float* b_conv  = (const float*)d_in[8];
    const float* W_ih    = (const float*)d_in[9];
    const float* W_hh    = (const float*)d_in[10];
    const float* b_ih    = (const float*)d_in[11];
    const float* b_hh    = (const float*)d_in[12];
    const int*   eidx    = (const int*)d_in[13];

    int N = in_sizes[0] / DIN;
    int E = in_sizes[13] / 2;
    const int* src = eidx;
    const int* dst = eidx + E;
    float* out = (float*)d_out;

    size_t off = 0;
    char* base = (char*)d_ws;
    auto alloc = [&](size_t bytes) -> char* {
        char* p = base + off;
        off = (off + bytes + 255) & ~(size_t)255;
        return p;
    };
    u16*   Ag    = (u16*)  alloc((size_t)N*256*2);   // [h | xe] bf16
    float* r_dst = (float*)alloc((size_t)N*4);
    float* alpha = (float*)alloc((size_t)E*4);
    int*   deg   = (int*)  alloc((size_t)N*4);
    int*   rs    = (int*)  alloc((size_t)(N+1)*4);
    int*   cnt   = (int*)  alloc((size_t)N*4);
    int*   epos  = (int*)  alloc((size_t)E*4);
    int*   btot  = (int*)  alloc(1024);
    int*   bbase = (int*)  alloc(1024);
    u16*   W1b   = (u16*)  alloc(20480*2);
    u16*   W2b   = (u16*)  alloc(16384*2);
    u16*   Wentb = (u16*)  alloc(8192*2);
    u16*   Bg    = (u16*)  alloc(131072*2);
    u8*    mbuf  = (u8*)   alloc((size_t)E*HD);      // fp8 m, CSR-sorted

    u16* a_agg = (u16*)out;   // d_out reused as bf16 a_agg (dead before k_gru writes)

    int ntiles_n64 = N/64, ntiles_e = (E + 63)/64, ntiles_g = N/32;

    k_prep   <<<(176128+255)/256, 256, 0, stream>>>(W1, W2, W_enter, W_ih, W_hh, W1b, W2b, Wentb, Bg);
    k_zero2  <<<(N+255)/256, 256, 0, stream>>>(deg, cnt, N);
    k_enter_mfma<<<ntiles_n64, 256, 0, stream>>>(x, Wentb, b_enter, att_r, Ag, r_dst, N);
    k_hist   <<<(E+255)/256, 256, 0, stream>>>(dst, deg, E);
    k_scan_a <<<N/1024, 256, 0, stream>>>(deg, rs, btot, N);
    k_scan_b <<<1, 256, 0, stream>>>(btot, bbase);
    k_scan_c <<<(N+255)/256, 256, 0, stream>>>(rs, bbase, N, E);
    k_scatter<<<(E+255)/256, 256, 0, stream>>>(dst, rs, cnt, epos, E);
    k_edge_mfma<<<768, 512, 0, stream>>>(Ag, ea, W1b, att_l, r_dst, src, dst, epos,
                                         mbuf, alpha, ntiles_e, E);
    k_agg    <<<(N+3)/4, 256, 0, stream>>>(rs, alpha, mbuf, a_agg, N);
    k_conv2_mfma<<<ntiles_n64, 256, 0, stream>>>(a_agg, W2b, b_conv, Ag, N);
    k_gru_mfma  <<<2048, 512, 0, stream>>>(Ag, Bg, b_ih, b_hh, out, N, ntiles_g);
}

// Round 9
// 597.223 us; speedup vs baseline: 8.9059x; 1.0642x over previous
//
#include <hip/hip_runtime.h>
#include <stdint.h>

#define HD  128
#define DIN 64
#define DE  32

typedef unsigned int u32; typedef unsigned short u16; typedef unsigned char u8;
typedef short s16x8 __attribute__((ext_vector_type(8)));
typedef float f32x4 __attribute__((ext_vector_type(4)));
typedef float f32x2 __attribute__((ext_vector_type(2)));

#define MFMA16(a,b,c) __builtin_amdgcn_mfma_f32_16x16x32_bf16((a),(b),(c),0,0,0)

__device__ __forceinline__ float lrelu(float x){ return x > 0.f ? x : 0.01f*x; }
__device__ __forceinline__ float sigmoidf_(float x){ return 1.f/(1.f + __expf(-x)); }
__device__ __forceinline__ float tanhf_(float x){
    float t = fminf(fmaxf(x, -15.f), 15.f);
    float e = __expf(2.f*t);
    return (e - 1.f)/(e + 1.f);
}
__device__ __forceinline__ float eluf_(float x){ return x > 0.f ? x : expm1f(x); }

__device__ __forceinline__ u16 f32_to_bf16(float x){
    u32 u = __float_as_uint(x);
    u += 0x7FFFu + ((u >> 16) & 1u);
    return (u16)(u >> 16);
}
__device__ __forceinline__ float bf16lo(u32 u){ return __uint_as_float((u & 0xFFFFu) << 16); }
__device__ __forceinline__ float bf16hi(u32 u){ return __uint_as_float(u & 0xFFFF0000u); }
__device__ __forceinline__ float bf16f(u16 h){ return __uint_as_float(((u32)h) << 16); }
__device__ __forceinline__ u32 pk2(float a, float b){
    return (u32)f32_to_bf16(a) | ((u32)f32_to_bf16(b) << 16);
}
// HW OCP e4m3fn converters (gfx950)
__device__ __forceinline__ u8 hw_f8(float v){
    return (u8)__builtin_amdgcn_cvt_pk_fp8_f32(v, v, 0, false);
}
__device__ __forceinline__ f32x2 hw_f8_dec2(u32 u){   // decodes bytes [0:1]
    return __builtin_amdgcn_cvt_pk_f32_fp8((int)u, false);
}
__device__ __forceinline__ f32x2 hw_f8_dec2_hi(u32 u){ // decodes bytes [2:3]
    return __builtin_amdgcn_cvt_pk_f32_fp8((int)u, true);
}

__device__ __forceinline__ float wave_max(float v){
    #pragma unroll
    for (int o = 32; o > 0; o >>= 1) v = fmaxf(v, __shfl_xor(v, o, 64));
    return v;
}
__device__ __forceinline__ float wave_sum(float v){
    #pragma unroll
    for (int o = 32; o > 0; o >>= 1) v += __shfl_xor(v, o, 64);
    return v;
}
__device__ __forceinline__ float dot8_bf16(uint4 v, const float* __restrict__ al){
    float d = 0.f;
    d = fmaf(bf16lo(v.x), al[0], d); d = fmaf(bf16hi(v.x), al[1], d);
    d = fmaf(bf16lo(v.y), al[2], d); d = fmaf(bf16hi(v.y), al[3], d);
    d = fmaf(bf16lo(v.z), al[4], d); d = fmaf(bf16hi(v.z), al[5], d);
    d = fmaf(bf16lo(v.w), al[6], d); d = fmaf(bf16hi(v.w), al[7], d);
    return d;
}

// ---------------- weight prep: fp32 -> bf16 (+ GRU B-pack) ----------------
__global__ void k_prep(const float* __restrict__ W1, const float* __restrict__ W2,
                       const float* __restrict__ Went,
                       const float* __restrict__ Wih, const float* __restrict__ Whh,
                       u16* __restrict__ W1b, u16* __restrict__ W2b,
                       u16* __restrict__ Wentb, u16* __restrict__ Bg)
{
    int i = blockIdx.x*256 + threadIdx.x;
    if (i < 20480){ W1b[i] = f32_to_bf16(W1[i]); return; }
    i -= 20480;
    if (i < 16384){ W2b[i] = f32_to_bf16(W2[i]); return; }
    i -= 16384;
    if (i < 8192){ Wentb[i] = f32_to_bf16(Went[i]); return; }
    i -= 8192;
    if (i < 131072){
        int col = i >> 8, k = i & 255;
        int g = col >> 7, j = col & 127;
        float v;
        if      (g == 0) v = (k < 128) ? Wih[j*128 + k]        : Whh[j*128 + k - 128];
        else if (g == 1) v = (k < 128) ? Wih[(128+j)*128 + k]  : Whh[(128+j)*128 + k - 128];
        else if (g == 2) v = (k < 128) ? Wih[(256+j)*128 + k]  : 0.f;
        else             v = (k < 128) ? 0.f                   : Whh[(256+j)*128 + k - 128];
        Bg[i] = f32_to_bf16(v);
    }
}

// ---------------- init ----------------
__global__ void k_zero2(int* __restrict__ a, int* __restrict__ b, int n){
    int i = blockIdx.x*256 + threadIdx.x;
    if (i < n){ a[i] = 0; b[i] = 0; }
}

// ---------------- K1 (MFMA): xe-half of Ag = bf16(lrelu(x@W^T+b)); r_dst = xe·att_r ----------------
__global__ __launch_bounds__(256, 2) void k_enter_mfma(
    const float* __restrict__ x, const u16* __restrict__ Wb, const float* __restrict__ be,
    const float* __restrict__ att_r, u16* __restrict__ Ag, float* __restrict__ r_out, int N)
{
    __shared__ __align__(16) u8 sA[64*144];
    __shared__ __align__(16) u8 sO[64*272];
    int t = threadIdx.x, w = t >> 6, lane = t & 63, l15 = lane & 15, l4 = lane >> 4;
    int tile = blockIdx.x;

    s16x8 bfr[2][2];
    #pragma unroll
    for (int kf = 0; kf < 2; ++kf)
        #pragma unroll
        for (int cf = 0; cf < 2; ++cf)
            bfr[kf][cf] = *(const s16x8*)(Wb + (size_t)(w*32 + cf*16 + l15)*64 + kf*32 + l4*8);

    int el = t >> 2, q = t & 3;
    size_t n = (size_t)tile*64 + el;
    {
        const float4* xs = (const float4*)(x + n*64 + q*16);
        float4 f0 = xs[0], f1 = xs[1], f2 = xs[2], f3 = xs[3];
        uint4 o0, o1;
        o0.x = pk2(f0.x,f0.y); o0.y = pk2(f0.z,f0.w); o0.z = pk2(f1.x,f1.y); o0.w = pk2(f1.z,f1.w);
        o1.x = pk2(f2.x,f2.y); o1.y = pk2(f2.z,f2.w); o1.z = pk2(f3.x,f3.y); o1.w = pk2(f3.z,f3.w);
        *(uint4*)(sA + el*144 + q*32)      = o0;
        *(uint4*)(sA + el*144 + q*32 + 16) = o1;
    }
    __syncthreads();

    f32x4 acc[4][2];
    #pragma unroll
    for (int rf = 0; rf < 4; ++rf){ acc[rf][0] = (f32x4)0.f; acc[rf][1] = (f32x4)0.f; }
    #pragma unroll
    for (int kf = 0; kf < 2; ++kf){
        s16x8 a[4];
        #pragma unroll
        for (int rf = 0; rf < 4; ++rf)
            a[rf] = *(const s16x8*)(sA + (rf*16 + l15)*144 + kf*64 + l4*16);
        #pragma unroll
        for (int rf = 0; rf < 4; ++rf){
            acc[rf][0] = MFMA16(a[rf], bfr[kf][0], acc[rf][0]);
            acc[rf][1] = MFMA16(a[rf], bfr[kf][1], acc[rf][1]);
        }
    }
    float b0 = be[w*32 + l15], b1 = be[w*32 + 16 + l15];
    #pragma unroll
    for (int rf = 0; rf < 4; ++rf)
        #pragma unroll
        for (int r = 0; r < 4; ++r){
            int row = rf*16 + l4*4 + r;
            *(u16*)(sO + row*272 + (w*32 + l15)*2)      = f32_to_bf16(lrelu(acc[rf][0][r] + b0));
            *(u16*)(sO + row*272 + (w*32 + 16 + l15)*2) = f32_to_bf16(lrelu(acc[rf][1][r] + b1));
        }
    __syncthreads();

    float dot = 0.f;
    #pragma unroll
    for (int i = 0; i < 4; ++i){
        uint4 v = *(const uint4*)(sO + el*272 + q*64 + 16*i);
        ((uint4*)Ag)[n*32 + 16 + q*4 + i] = v;         // xe half: byte n*512+256
        dot += dot8_bf16(v, att_r + q*32 + 8*i);
    }
    dot += __shfl_xor(dot, 1); dot += __shfl_xor(dot, 2);
    if (q == 0) r_out[n] = dot;
}

// ---------------- CSR build ----------------
__global__ void k_hist(const int* __restrict__ dst, int* __restrict__ deg, int E){
    int e = blockIdx.x*256 + threadIdx.x;
    if (e < E) atomicAdd(&deg[dst[e]], 1);
}
__global__ __launch_bounds__(256) void k_scan_a(
    const int* __restrict__ deg, int* __restrict__ rs, int* __restrict__ btot, int N)
{
    __shared__ int sd[256];
    int b = blockIdx.x, t = threadIdx.x;
    int base = b*1024 + t*4;
    int d0 = deg[base], d1 = deg[base+1], d2 = deg[base+2], d3 = deg[base+3];
    int s = d0 + d1 + d2 + d3;
    sd[t] = s; __syncthreads();
    for (int o = 1; o < 256; o <<= 1){
        int v = (t >= o) ? sd[t-o] : 0;
        __syncthreads();
        sd[t] += v;
        __syncthreads();
    }
    int ex = sd[t] - s;
    rs[base]   = ex;
    rs[base+1] = ex + d0;
    rs[base+2] = ex + d0 + d1;
    rs[base+3] = ex + d0 + d1 + d2;
    if (t == 0) btot[b] = sd[255];
}
__global__ __launch_bounds__(256) void k_scan_b(const int* __restrict__ btot, int* __restrict__ bbase){
    __shared__ int sd[256];
    int t = threadIdx.x;
    int s = btot[t];
    sd[t] = s; __syncthreads();
    for (int o = 1; o < 256; o <<= 1){
        int v = (t >= o) ? sd[t-o] : 0;
        __syncthreads();
        sd[t] += v;
        __syncthreads();
    }
    bbase[t] = sd[t] - s;
}
__global__ void k_scan_c(int* __restrict__ rs, const int* __restrict__ bbase, int N, int E){
    int i = blockIdx.x*256 + threadIdx.x;
    if (i < N) rs[i] += bbase[i >> 10];
    if (i == 0) rs[N] = E;
}
__global__ void k_scatter(const int* __restrict__ dst, const int* __restrict__ rs,
                          int* __restrict__ cnt, int* __restrict__ epos, int E){
    int e = blockIdx.x*256 + threadIdx.x;
    if (e >= E) return;
    int d = dst[e];
    int pos = rs[d] + atomicAdd(&cnt[d], 1);
    epos[e] = pos;
}

// ---------------- K2 (MFMA, 8-wave, 2-barrier pipeline, HW fp8) ----------------
__global__ __launch_bounds__(512, 4) void k_edge_mfma(
    const u16* __restrict__ Ag, const float* __restrict__ ea,
    const u16* __restrict__ W1b, const float* __restrict__ att_l,
    const float* __restrict__ r_dst, const int* __restrict__ src, const int* __restrict__ dst,
    const int* __restrict__ epos,
    u8* __restrict__ m, float* __restrict__ alpha, int ntiles, int E)
{
    __shared__ __align__(16) u8 sA[64*336];
    __shared__ __align__(16) u8 sM[64*144];
    int t = threadIdx.x, w = t >> 6, lane = t & 63, l15 = lane & 15, l4 = lane >> 4;

    s16x8 bfr[5];                 // wave w owns cols [w*16, w*16+16)
    #pragma unroll
    for (int kf = 0; kf < 5; ++kf)
        bfr[kf] = *(const s16x8*)(W1b + (size_t)(w*16 + l15)*160 + kf*32 + l4*8);

    int el = t >> 3, q = t & 7;   // 64 edges/tile, 8 threads/edge
    int stride = gridDim.x;
    int tile = blockIdx.x;

    uint4 cx0, cx1;               // prefetched 32B of xe[src[e]]
    u32 ce0, ce1;                 // prefetched 8B packed edge_attr
    int   pe = 0;                 // prefetched epos[e]
    float rdv = 0.f;              // prefetched r_dst[dst[e]]
    {
        int e = tile*64 + el;
        if (tile < ntiles && e < E){
            int sn = src[e];
            const uint4* xs = (const uint4*)Ag + (size_t)sn*32 + 16 + q*2;
            cx0 = xs[0]; cx1 = xs[1];
            float4 f = *(const float4*)(ea + (size_t)e*32 + q*4);
            ce0 = pk2(f.x, f.y); ce1 = pk2(f.z, f.w);
            pe  = epos[e];
            rdv = r_dst[dst[e]];
        }
    }

    int   ptile = -1;             // previous tile awaiting epilogue
    int   pe_prev = 0;
    float rdv_prev = 0.f;

    for (; tile < ntiles; tile += stride){
        int e = tile*64 + el;
        if (e < E){
            uint4* d = (uint4*)(sA + el*336 + q*32);
            d[0] = cx0; d[1] = cx1;
            *(u32*)(sA + el*336 + 256 + q*8)     = ce0;
            *(u32*)(sA + el*336 + 256 + q*8 + 4) = ce1;
        }
        int pe_cur = pe; float rdv_cur = rdv;

        // issue next tile's gather; latency hides under epilogue + MFMA
        int nt = tile + stride;
        if (nt < ntiles){
            int e2 = nt*64 + el;
            if (e2 < E){
                int sn = src[e2];
                const uint4* xs = (const uint4*)Ag + (size_t)sn*32 + 16 + q*2;
                cx0 = xs[0]; cx1 = xs[1];
                float4 f = *(const float4*)(ea + (size_t)e2*32 + q*4);
                ce0 = pk2(f.x, f.y); ce1 = pk2(f.z, f.w);
                pe  = epos[e2];
                rdv = r_dst[dst[e2]];
            }
        }

        // epilogue for previous tile (reads sM written last iteration)
        if (ptile >= 0){
            int ep = ptile*64 + el;
            if (ep < E){
                uint4 v = *(const uint4*)(sM + el*144 + q*16);
                ((uint4*)m)[(size_t)pe_prev*8 + q] = v;
                u32 ws[4] = {v.x, v.y, v.z, v.w};
                float dotv = 0.f;
                #pragma unroll
                for (int i = 0; i < 4; ++i){
                    f32x2 fa = hw_f8_dec2(ws[i]);
                    f32x2 fb = hw_f8_dec2_hi(ws[i]);
                    const float* al = att_l + q*16 + i*4;
                    dotv = fmaf(fa.x, al[0], dotv); dotv = fmaf(fa.y, al[1], dotv);
                    dotv = fmaf(fb.x, al[2], dotv); dotv = fmaf(fb.y, al[3], dotv);
                }
                dotv += __shfl_xor(dotv, 1); dotv += __shfl_xor(dotv, 2); dotv += __shfl_xor(dotv, 4);
                if (q == 0) alpha[pe_prev] = lrelu(dotv + rdv_prev);
            }
        }
        __syncthreads();    // sA staged + sM fully consumed

        f32x4 acc[4];
        #pragma unroll
        for (int rf = 0; rf < 4; ++rf) acc[rf] = (f32x4)0.f;
        #pragma unroll
        for (int kf = 0; kf < 5; ++kf){
            s16x8 a[4];
            #pragma unroll
            for (int rf = 0; rf < 4; ++rf)
                a[rf] = *(const s16x8*)(sA + (rf*16 + l15)*336 + kf*64 + l4*16);
            #pragma unroll
            for (int rf = 0; rf < 4; ++rf)
                acc[rf] = MFMA16(a[rf], bfr[kf], acc[rf]);
        }

        int col = w*16 + l15;
        #pragma unroll
        for (int rf = 0; rf < 4; ++rf)
            #pragma unroll
            for (int r = 0; r < 4; ++r){
                int row = rf*16 + l4*4 + r;
                sM[row*144 + col] = hw_f8(lrelu(acc[rf][r]));
            }
        __syncthreads();    // sM ready; sA free for next stage

        ptile = tile; pe_prev = pe_cur; rdv_prev = rdv_cur;
    }

    // drain: epilogue for the last tile
    if (ptile >= 0){
        int ep = ptile*64 + el;
        if (ep < E){
            uint4 v = *(const uint4*)(sM + el*144 + q*16);
            ((uint4*)m)[(size_t)pe_prev*8 + q] = v;
            u32 ws[4] = {v.x, v.y, v.z, v.w};
            float dotv = 0.f;
            #pragma unroll
            for (int i = 0; i < 4; ++i){
                f32x2 fa = hw_f8_dec2(ws[i]);
                f32x2 fb = hw_f8_dec2_hi(ws[i]);
                const float* al = att_l + q*16 + i*4;
                dotv = fmaf(fa.x, al[0], dotv); dotv = fmaf(fa.y, al[1], dotv);
                dotv = fmaf(fb.x, al[2], dotv); dotv = fmaf(fb.y, al[3], dotv);
            }
            dotv += __shfl_xor(dotv, 1); dotv += __shfl_xor(dotv, 2); dotv += __shfl_xor(dotv, 4);
            if (q == 0) alpha[pe_prev] = lrelu(dotv + rdv_prev);
        }
    }
}

// ---------------- K4: streaming segment softmax + weighted sum (fp8 m, HW dec) -> bf16 a_agg ----------------
__global__ __launch_bounds__(256) void k_agg(
    const int* __restrict__ rs,
    const float* __restrict__ alpha, const u8* __restrict__ m,
    u16* __restrict__ a_out, int N)
{
    int wid  = (blockIdx.x*256 + threadIdx.x) >> 6;
    int lane = threadIdx.x & 63;
    if (wid >= N) return;
    int s = rs[wid], t = rs[wid+1];
    int deg = t - s;
    float ax = 0.f, ay = 0.f;
    if (deg > 0 && deg <= 64){
        float av = -1e38f;
        if (lane < deg) av = alpha[s + lane];
        float mx = wave_max(av);
        float ev = (lane < deg) ? __expf(av - mx) : 0.f;
        float ssum = wave_sum(ev);
        float wreg = ev / ssum;
        int k = 0;
        for (; k + 2 <= deg; k += 2){
            float w0 = __shfl(wreg, k);
            float w1 = __shfl(wreg, k + 1);
            u32 u0 = *(const u16*)(m + (size_t)(s + k)*HD + 2*lane);
            u32 u1 = *(const u16*)(m + (size_t)(s + k + 1)*HD + 2*lane);
            f32x2 f0 = hw_f8_dec2(u0);
            f32x2 f1 = hw_f8_dec2(u1);
            ax = fmaf(w0, f0.x, ax); ay = fmaf(w0, f0.y, ay);
            ax = fmaf(w1, f1.x, ax); ay = fmaf(w1, f1.y, ay);
        }
        if (k < deg){
            float w0 = __shfl(wreg, k);
            u32 u0 = *(const u16*)(m + (size_t)(s + k)*HD + 2*lane);
            f32x2 f0 = hw_f8_dec2(u0);
            ax = fmaf(w0, f0.x, ax); ay = fmaf(w0, f0.y, ay);
        }
    } else if (deg > 64){
        float mx = -1e38f;
        for (int k = lane; k < deg; k += 64) mx = fmaxf(mx, alpha[s + k]);
        mx = wave_max(mx);
        float ssum = 0.f;
        for (int k = lane; k < deg; k += 64) ssum += __expf(alpha[s + k] - mx);
        ssum = wave_sum(ssum);
        float inv = 1.f / ssum;
        for (int k = 0; k < deg; ++k){
            float wgt = __expf(alpha[s + k] - mx) * inv;
            u32 u0 = *(const u16*)(m + (size_t)(s + k)*HD + 2*lane);
            f32x2 f0 = hw_f8_dec2(u0);
            ax = fmaf(wgt, f0.x, ax);
            ay = fmaf(wgt, f0.y, ay);
        }
    }
    *(u32*)(a_out + (size_t)wid*HD + 2*lane) = pk2(ax, ay);
}

// ---------------- K5a (MFMA): h-half of Ag = bf16(elu(W2@a + bc)), a in bf16 ----------------
__global__ __launch_bounds__(256, 2) void k_conv2_mfma(
    const u16* __restrict__ a, const u16* __restrict__ W2b, const float* __restrict__ bc,
    u16* __restrict__ Ag, int N)
{
    __shared__ __align__(16) u8 sA[64*272];
    __shared__ __align__(16) u8 sO[64*272];
    int t = threadIdx.x, w = t >> 6, lane = t & 63, l15 = lane & 15, l4 = lane >> 4;
    int tile = blockIdx.x;

    s16x8 bfr[4][2];
    #pragma unroll
    for (int kf = 0; kf < 4; ++kf)
        #pragma unroll
        for (int cf = 0; cf < 2; ++cf)
            bfr[kf][cf] = *(const s16x8*)(W2b + (size_t)(w*32 + cf*16 + l15)*128 + kf*32 + l4*8);

    int el = t >> 2, q = t & 3;
    size_t n = (size_t)tile*64 + el;
    {
        const uint4* as = (const uint4*)(a + n*HD) + q*4;
        uint4 v0 = as[0], v1 = as[1], v2 = as[2], v3 = as[3];
        uint4* d = (uint4*)(sA + el*272 + q*64);
        d[0] = v0; d[1] = v1; d[2] = v2; d[3] = v3;
    }
    __syncthreads();

    f32x4 acc[4][2];
    #pragma unroll
    for (int rf = 0; rf < 4; ++rf){ acc[rf][0] = (f32x4)0.f; acc[rf][1] = (f32x4)0.f; }
    #pragma unroll
    for (int kf = 0; kf < 4; ++kf){
        s16x8 av[4];
        #pragma unroll
        for (int rf = 0; rf < 4; ++rf)
            av[rf] = *(const s16x8*)(sA + (rf*16 + l15)*272 + kf*64 + l4*16);
        #pragma unroll
        for (int rf = 0; rf < 4; ++rf){
            acc[rf][0] = MFMA16(av[rf], bfr[kf][0], acc[rf][0]);
            acc[rf][1] = MFMA16(av[rf], bfr[kf][1], acc[rf][1]);
        }
    }
    float b0 = bc[w*32 + l15], b1 = bc[w*32 + 16 + l15];
    #pragma unroll
    for (int rf = 0; rf < 4; ++rf)
        #pragma unroll
        for (int r = 0; r < 4; ++r){
            int row = rf*16 + l4*4 + r;
            *(u16*)(sO + row*272 + (w*32 + l15)*2)      = f32_to_bf16(eluf_(acc[rf][0][r] + b0));
            *(u16*)(sO + row*272 + (w*32 + 16 + l15)*2) = f32_to_bf16(eluf_(acc[rf][1][r] + b1));
        }
    __syncthreads();
    #pragma unroll
    for (int i = 0; i < 4; ++i){
        uint4 v = *(const uint4*)(sO + el*272 + q*64 + 16*i);
        ((uint4*)Ag)[n*32 + q*4 + i] = v;              // h half: byte n*512
    }
}

// ---------------- K5b (MFMA): GRU cell + fused LayerNorm -> out ----------------
// Zero-skip B-pack: gate2 (in) only K<128, gate3 (hn) only K>=128.
__global__ __launch_bounds__(512, 3) void k_gru_mfma(
    const u16* __restrict__ Ag, const u16* __restrict__ Bg,
    const float* __restrict__ bih, const float* __restrict__ bhh,
    float* __restrict__ out, int N, int ntiles)
{
    __shared__ __align__(16) u8 sA[32*528];
    __shared__ __align__(16) float sOut[32*132];     // +4 pad breaks write conflicts
    int t = threadIdx.x, w = t >> 6, lane = t & 63, l15 = lane & 15, l4 = lane >> 4;

    s16x8 bfr0[8], bfr1[8], bfr2[4], bfr3[4];        // 24 frags = 96 VGPR (was 32/128)
    {
        int jc = w*16 + l15;
        #pragma unroll
        for (int kf = 0; kf < 8; ++kf){
            bfr0[kf] = *(const s16x8*)(Bg + (size_t)(jc)*256       + kf*32 + l4*8);
            bfr1[kf] = *(const s16x8*)(Bg + (size_t)(128 + jc)*256 + kf*32 + l4*8);
        }
        #pragma unroll
        for (int kf = 0; kf < 4; ++kf){
            bfr2[kf] = *(const s16x8*)(Bg + (size_t)(256 + jc)*256 + kf*32 + l4*8);
            bfr3[kf] = *(const s16x8*)(Bg + (size_t)(384 + jc)*256 + (kf+4)*32 + l4*8);
        }
    }
    int j = w*16 + l15;
    float rb = bih[j] + bhh[j];
    float zb = bih[128 + j] + bhh[128 + j];
    float ib = bih[256 + j];
    float hb = bhh[256 + j];

    int el = t >> 4, part = t & 15;
    int stride = gridDim.x;
    int tile = blockIdx.x;
    uint4 pv0, pv1;               // prefetched A chunk
    if (tile < ntiles){
        const uint4* gsrc = (const uint4*)Ag + ((size_t)tile*32 + el)*32 + part*2;
        pv0 = gsrc[0]; pv1 = gsrc[1];
    }

    for (; tile < ntiles; tile += stride){
        {
            uint4* d = (uint4*)(sA + el*528 + part*32);
            d[0] = pv0; d[1] = pv1;
        }
        __syncthreads();

        int nt = tile + stride;
        if (nt < ntiles){
            const uint4* gsrc = (const uint4*)Ag + ((size_t)nt*32 + el)*32 + part*2;
            pv0 = gsrc[0]; pv1 = gsrc[1];
        }

        f32x4 acc[2][4];
        #pragma unroll
        for (int rf = 0; rf < 2; ++rf)
            #pragma unroll
            for (int g = 0; g < 4; ++g) acc[rf][g] = (f32x4)0.f;
        #pragma unroll
        for (int kf = 0; kf < 8; ++kf){
            s16x8 a0 = *(const s16x8*)(sA + l15*528 + kf*64 + l4*16);
            s16x8 a1 = *(const s16x8*)(sA + (16 + l15)*528 + kf*64 + l4*16);
            acc[0][0] = MFMA16(a0, bfr0[kf], acc[0][0]);
            acc[1][0] = MFMA16(a1, bfr0[kf], acc[1][0]);
            acc[0][1] = MFMA16(a0, bfr1[kf], acc[0][1]);
            acc[1][1] = MFMA16(a1, bfr1[kf], acc[1][1]);
            if (kf < 4){
                acc[0][2] = MFMA16(a0, bfr2[kf], acc[0][2]);
                acc[1][2] = MFMA16(a1, bfr2[kf], acc[1][2]);
            } else {
                acc[0][3] = MFMA16(a0, bfr3[kf-4], acc[0][3]);
                acc[1][3] = MFMA16(a1, bfr3[kf-4], acc[1][3]);
            }
        }
        #pragma unroll
        for (int rf = 0; rf < 2; ++rf)
            #pragma unroll
            for (int r = 0; r < 4; ++r){
                int rl = rf*16 + l4*4 + r;
                float rr = sigmoidf_(acc[rf][0][r] + rb);
                float zz = sigmoidf_(acc[rf][1][r] + zb);
                float iv = acc[rf][2][r] + ib;
                float hv = acc[rf][3][r] + hb;
                float nc = tanhf_(iv + rr*hv);
                float xej = bf16f(*(const u16*)(sA + rl*528 + 256 + 2*j));
                float v = (1.f - zz)*nc + zz*xej;
                v = fmaxf(v, 0.f);
                sOut[rl*132 + j] = v;
            }
        __syncthreads();
        {
            int row = t >> 4, sub = t & 15;          // 16 threads/row, same wave
            const float* rp = sOut + row*132 + sub*8;
            float v0 = rp[0], v1 = rp[1], v2 = rp[2], v3 = rp[3];
            float v4 = rp[4], v5 = rp[5], v6 = rp[6], v7 = rp[7];
            float s1 = v0+v1+v2+v3+v4+v5+v6+v7;
            float s2 = v0*v0+v1*v1+v2*v2+v3*v3+v4*v4+v5*v5+v6*v6+v7*v7;
            #pragma unroll
            for (int o = 1; o < 16; o <<= 1){ s1 += __shfl_xor(s1, o); s2 += __shfl_xor(s2, o); }
            float mu  = s1 * (1.f/128.f);
            float var = s2 * (1.f/128.f) - mu*mu;
            var = fmaxf(var, 0.f);
            float rsd = rsqrtf(var + 1e-5f);
            float* op = out + ((size_t)tile*32 + row)*128 + sub*8;
            float4 o0, o1;
            o0.x = (v0-mu)*rsd; o0.y = (v1-mu)*rsd; o0.z = (v2-mu)*rsd; o0.w = (v3-mu)*rsd;
            o1.x = (v4-mu)*rsd; o1.y = (v5-mu)*rsd; o1.z = (v6-mu)*rsd; o1.w = (v7-mu)*rsd;
            ((float4*)op)[0] = o0; ((float4*)op)[1] = o1;
        }
        __syncthreads();
    }
}

// ---------------- host ----------------
extern "C" void kernel_launch(void* const* d_in, const int* in_sizes, int n_in,
                              void* d_out, int out_size, void* d_ws, size_t ws_size,
                              hipStream_t stream)
{
    const float* x       = (const float*)d_in[0];
    const float* ea      = (const float*)d_in[1];
    const float* W_enter = (const float*)d_in[2];
    const float* b_enter = (const float*)d_in[3];
    const float* W1      = (const float*)d_in[4];
    const float* att_l   = (const float*)d_in[5];
    const float* att_r   = (const float*)d_in[6];
    const float* W2      = (const float*)d_in[7];
    const float* b_conv  = (const float*)d_in[8];
    const float* W_ih    = (const float*)d_in[9];
    const float* W_hh    = (const float*)d_in[10];
    const float* b_ih    = (const float*)d_in[11];
    const float* b_hh    = (const float*)d_in[12];
    const int*   eidx    = (const int*)d_in[13];

    int N = in_sizes[0] / DIN;
    int E = in_sizes[13] / 2;
    const int* src = eidx;
    const int* dst = eidx + E;
    float* out = (float*)d_out;

    size_t off = 0;
    char* base = (char*)d_ws;
    auto alloc = [&](size_t bytes) -> char* {
        char* p = base + off;
        off = (off + bytes + 255) & ~(size_t)255;
        return p;
    };
    u16*   Ag    = (u16*)  alloc((size_t)N*256*2);   // [h | xe] bf16
    float* r_dst = (float*)alloc((size_t)N*4);
    float* alpha = (float*)alloc((size_t)E*4);
    int*   deg   = (int*)  alloc((size_t)N*4);
    int*   rs    = (int*)  alloc((size_t)(N+1)*4);
    int*   cnt   = (int*)  alloc((size_t)N*4);
    int*   epos  = (int*)  alloc((size_t)E*4);
    int*   btot  = (int*)  alloc(1024);
    int*   bbase = (int*)  alloc(1024);
    u16*   W1b   = (u16*)  alloc(20480*2);
    u16*   W2b   = (u16*)  alloc(16384*2);
    u16*   Wentb = (u16*)  alloc(8192*2);
    u16*   Bg    = (u16*)  alloc(131072*2);
    u8*    mbuf  = (u8*)   alloc((size_t)E*HD);      // fp8 m, CSR-sorted

    u16* a_agg = (u16*)out;   // d_out reused as bf16 a_agg (dead before k_gru writes)

    int ntiles_n64 = N/64, ntiles_e = (E + 63)/64, ntiles_g = N/32;

    k_prep   <<<(176128+255)/256, 256, 0, stream>>>(W1, W2, W_enter, W_ih, W_hh, W1b, W2b, Wentb, Bg);
    k_zero2  <<<(N+255)/256, 256, 0, stream>>>(deg, cnt, N);
    k_enter_mfma<<<ntiles_n64, 256, 0, stream>>>(x, Wentb, b_enter, att_r, Ag, r_dst, N);
    k_hist   <<<(E+255)/256, 256, 0, stream>>>(dst, deg, E);
    k_scan_a <<<N/1024, 256, 0, stream>>>(deg, rs, btot, N);
    k_scan_b <<<1, 256, 0, stream>>>(btot, bbase);
    k_scan_c <<<(N+255)/256, 256, 0, stream>>>(rs, bbase, N, E);
    k_scatter<<<(E+255)/256, 256, 0, stream>>>(dst, rs, cnt, epos, E);
    k_edge_mfma<<<1024, 512, 0, stream>>>(Ag, ea, W1b, att_l, r_dst, src, dst, epos,
                                          mbuf, alpha, ntiles_e, E);
    k_agg    <<<(N+3)/4, 256, 0, stream>>>(rs, alpha, mbuf, a_agg, N);
    k_conv2_mfma<<<ntiles_n64, 256, 0, stream>>>(a_agg, W2b, b_conv, Ag, N);
    k_gru_mfma  <<<2048, 512, 0, stream>>>(Ag, Bg, b_ih, b_hh, out, N, ntiles_g);
}

// Round 10
// 548.889 us; speedup vs baseline: 9.6901x; 1.0881x over previous
//
#include <hip/hip_runtime.h>
#include <stdint.h>

#define HD  128
#define DIN 64
#define DE  32

typedef unsigned int u32; typedef unsigned short u16; typedef unsigned char u8;
typedef long i64_;
typedef short s16x8 __attribute__((ext_vector_type(8)));
typedef float f32x4 __attribute__((ext_vector_type(4)));
typedef float f32x2 __attribute__((ext_vector_type(2)));

#define MFMA16(a,b,c)  __builtin_amdgcn_mfma_f32_16x16x32_bf16((a),(b),(c),0,0,0)
#define MFMAF8(a,b,c)  __builtin_amdgcn_mfma_f32_16x16x32_fp8_fp8((a),(b),(c),0,0,0)

__device__ __forceinline__ float lrelu(float x){ return x > 0.f ? x : 0.01f*x; }
__device__ __forceinline__ float sigmoidf_(float x){ return 1.f/(1.f + __expf(-x)); }
__device__ __forceinline__ float tanhf_(float x){
    float t = fminf(fmaxf(x, -15.f), 15.f);
    float e = __expf(2.f*t);
    return (e - 1.f)/(e + 1.f);
}
__device__ __forceinline__ float eluf_(float x){ return x > 0.f ? x : expm1f(x); }

__device__ __forceinline__ u16 f32_to_bf16(float x){
    u32 u = __float_as_uint(x);
    u += 0x7FFFu + ((u >> 16) & 1u);
    return (u16)(u >> 16);
}
__device__ __forceinline__ float bf16lo(u32 u){ return __uint_as_float((u & 0xFFFFu) << 16); }
__device__ __forceinline__ float bf16hi(u32 u){ return __uint_as_float(u & 0xFFFF0000u); }
__device__ __forceinline__ float bf16f(u16 h){ return __uint_as_float(((u32)h) << 16); }
__device__ __forceinline__ u32 pk2(float a, float b){
    return (u32)f32_to_bf16(a) | ((u32)f32_to_bf16(b) << 16);
}
// HW OCP e4m3fn converters (gfx950)
__device__ __forceinline__ u8 hw_f8(float v){
    return (u8)__builtin_amdgcn_cvt_pk_fp8_f32(v, v, 0, false);
}
__device__ __forceinline__ u32 hw_f8x4(float a, float b, float c, float d){
    u32 r = (u32)__builtin_amdgcn_cvt_pk_fp8_f32(a, b, 0, false);
    r = (u32)__builtin_amdgcn_cvt_pk_fp8_f32(c, d, (int)r, true);
    return r;
}
__device__ __forceinline__ f32x2 hw_f8_dec2(u32 u){   // decodes bytes [0:1]
    return __builtin_amdgcn_cvt_pk_f32_fp8((int)u, false);
}
__device__ __forceinline__ f32x2 hw_f8_dec2_hi(u32 u){ // decodes bytes [2:3]
    return __builtin_amdgcn_cvt_pk_f32_fp8((int)u, true);
}

__device__ __forceinline__ float wave_max(float v){
    #pragma unroll
    for (int o = 32; o > 0; o >>= 1) v = fmaxf(v, __shfl_xor(v, o, 64));
    return v;
}
__device__ __forceinline__ float wave_sum(float v){
    #pragma unroll
    for (int o = 32; o > 0; o >>= 1) v += __shfl_xor(v, o, 64);
    return v;
}
__device__ __forceinline__ float dot8_bf16(uint4 v, const float* __restrict__ al){
    float d = 0.f;
    d = fmaf(bf16lo(v.x), al[0], d); d = fmaf(bf16hi(v.x), al[1], d);
    d = fmaf(bf16lo(v.y), al[2], d); d = fmaf(bf16hi(v.y), al[3], d);
    d = fmaf(bf16lo(v.z), al[4], d); d = fmaf(bf16hi(v.z), al[5], d);
    d = fmaf(bf16lo(v.w), al[6], d); d = fmaf(bf16hi(v.w), al[7], d);
    return d;
}

// ---------------- weight prep: fp32 -> bf16 (+ fp8 GRU B-pack) ----------------
__global__ void k_prep(const float* __restrict__ W1, const float* __restrict__ W2,
                       const float* __restrict__ Went,
                       const float* __restrict__ Wih, const float* __restrict__ Whh,
                       u16* __restrict__ W1b, u16* __restrict__ W2b,
                       u16* __restrict__ Wentb, u8* __restrict__ Bgf8)
{
    int i = blockIdx.x*256 + threadIdx.x;
    if (i < 20480){ W1b[i] = f32_to_bf16(W1[i]); return; }
    i -= 20480;
    if (i < 16384){ W2b[i] = f32_to_bf16(W2[i]); return; }
    i -= 16384;
    if (i < 8192){ Wentb[i] = f32_to_bf16(Went[i]); return; }
    i -= 8192;
    if (i < 131072){
        int col = i >> 8, k = i & 255;
        int g = col >> 7, j = col & 127;
        float v;
        if      (g == 0) v = (k < 128) ? Wih[j*128 + k]        : Whh[j*128 + k - 128];
        else if (g == 1) v = (k < 128) ? Wih[(128+j)*128 + k]  : Whh[(128+j)*128 + k - 128];
        else if (g == 2) v = (k < 128) ? Wih[(256+j)*128 + k]  : 0.f;
        else             v = (k < 128) ? 0.f                   : Whh[(256+j)*128 + k - 128];
        Bgf8[i] = hw_f8(v);
    }
}

// ---------------- init ----------------
__global__ void k_zero2(int* __restrict__ a, int* __restrict__ b, int n){
    int i = blockIdx.x*256 + threadIdx.x;
    if (i < n){ a[i] = 0; b[i] = 0; }
}

// ---------------- K1 (MFMA): xeb = bf16(lrelu(x@W^T+b)); Agru xe-half fp8; r_dst ----------------
__global__ __launch_bounds__(256, 2) void k_enter_mfma(
    const float* __restrict__ x, const u16* __restrict__ Wb, const float* __restrict__ be,
    const float* __restrict__ att_r, u16* __restrict__ xeb, u8* __restrict__ Agru,
    float* __restrict__ r_out, int N)
{
    __shared__ __align__(16) u8 sA[64*144];
    __shared__ __align__(16) u8 sO[64*272];
    int t = threadIdx.x, w = t >> 6, lane = t & 63, l15 = lane & 15, l4 = lane >> 4;
    int tile = blockIdx.x;

    s16x8 bfr[2][2];
    #pragma unroll
    for (int kf = 0; kf < 2; ++kf)
        #pragma unroll
        for (int cf = 0; cf < 2; ++cf)
            bfr[kf][cf] = *(const s16x8*)(Wb + (size_t)(w*32 + cf*16 + l15)*64 + kf*32 + l4*8);

    int el = t >> 2, q = t & 3;
    size_t n = (size_t)tile*64 + el;
    {
        const float4* xs = (const float4*)(x + n*64 + q*16);
        float4 f0 = xs[0], f1 = xs[1], f2 = xs[2], f3 = xs[3];
        uint4 o0, o1;
        o0.x = pk2(f0.x,f0.y); o0.y = pk2(f0.z,f0.w); o0.z = pk2(f1.x,f1.y); o0.w = pk2(f1.z,f1.w);
        o1.x = pk2(f2.x,f2.y); o1.y = pk2(f2.z,f2.w); o1.z = pk2(f3.x,f3.y); o1.w = pk2(f3.z,f3.w);
        *(uint4*)(sA + el*144 + q*32)      = o0;
        *(uint4*)(sA + el*144 + q*32 + 16) = o1;
    }
    __syncthreads();

    f32x4 acc[4][2];
    #pragma unroll
    for (int rf = 0; rf < 4; ++rf){ acc[rf][0] = (f32x4)0.f; acc[rf][1] = (f32x4)0.f; }
    #pragma unroll
    for (int kf = 0; kf < 2; ++kf){
        s16x8 a[4];
        #pragma unroll
        for (int rf = 0; rf < 4; ++rf)
            a[rf] = *(const s16x8*)(sA + (rf*16 + l15)*144 + kf*64 + l4*16);
        #pragma unroll
        for (int rf = 0; rf < 4; ++rf){
            acc[rf][0] = MFMA16(a[rf], bfr[kf][0], acc[rf][0]);
            acc[rf][1] = MFMA16(a[rf], bfr[kf][1], acc[rf][1]);
        }
    }
    float b0 = be[w*32 + l15], b1 = be[w*32 + 16 + l15];
    #pragma unroll
    for (int rf = 0; rf < 4; ++rf)
        #pragma unroll
        for (int r = 0; r < 4; ++r){
            int row = rf*16 + l4*4 + r;
            *(u16*)(sO + row*272 + (w*32 + l15)*2)      = f32_to_bf16(lrelu(acc[rf][0][r] + b0));
            *(u16*)(sO + row*272 + (w*32 + 16 + l15)*2) = f32_to_bf16(lrelu(acc[rf][1][r] + b1));
        }
    __syncthreads();

    float dot = 0.f;
    #pragma unroll
    for (int i = 0; i < 4; ++i){
        uint4 v = *(const uint4*)(sO + el*272 + q*64 + 16*i);
        ((uint4*)xeb)[n*16 + q*4 + i] = v;
        float f0 = bf16lo(v.x), f1 = bf16hi(v.x), f2 = bf16lo(v.y), f3 = bf16hi(v.y);
        float f4 = bf16lo(v.z), f5 = bf16hi(v.z), f6 = bf16lo(v.w), f7 = bf16hi(v.w);
        const float* al = att_r + q*32 + 8*i;
        dot = fmaf(f0, al[0], dot); dot = fmaf(f1, al[1], dot);
        dot = fmaf(f2, al[2], dot); dot = fmaf(f3, al[3], dot);
        dot = fmaf(f4, al[4], dot); dot = fmaf(f5, al[5], dot);
        dot = fmaf(f6, al[6], dot); dot = fmaf(f7, al[7], dot);
        uint2 p; p.x = hw_f8x4(f0, f1, f2, f3); p.y = hw_f8x4(f4, f5, f6, f7);
        *(uint2*)(Agru + n*256 + 128 + q*32 + i*8) = p;   // xe half (K>=128)
    }
    dot += __shfl_xor(dot, 1); dot += __shfl_xor(dot, 2);
    if (q == 0) r_out[n] = dot;
}

// ---------------- CSR build ----------------
__global__ void k_hist(const int* __restrict__ dst, int* __restrict__ deg, int E){
    int e = blockIdx.x*256 + threadIdx.x;
    if (e < E) atomicAdd(&deg[dst[e]], 1);
}
__global__ __launch_bounds__(256) void k_scan_a(
    const int* __restrict__ deg, int* __restrict__ rs, int* __restrict__ btot, int N)
{
    __shared__ int sd[256];
    int b = blockIdx.x, t = threadIdx.x;
    int base = b*1024 + t*4;
    int d0 = deg[base], d1 = deg[base+1], d2 = deg[base+2], d3 = deg[base+3];
    int s = d0 + d1 + d2 + d3;
    sd[t] = s; __syncthreads();
    for (int o = 1; o < 256; o <<= 1){
        int v = (t >= o) ? sd[t-o] : 0;
        __syncthreads();
        sd[t] += v;
        __syncthreads();
    }
    int ex = sd[t] - s;
    rs[base]   = ex;
    rs[base+1] = ex + d0;
    rs[base+2] = ex + d0 + d1;
    rs[base+3] = ex + d0 + d1 + d2;
    if (t == 0) btot[b] = sd[255];
}
__global__ __launch_bounds__(256) void k_scan_b(const int* __restrict__ btot, int* __restrict__ bbase){
    __shared__ int sd[256];
    int t = threadIdx.x;
    int s = btot[t];
    sd[t] = s; __syncthreads();
    for (int o = 1; o < 256; o <<= 1){
        int v = (t >= o) ? sd[t-o] : 0;
        __syncthreads();
        sd[t] += v;
        __syncthreads();
    }
    bbase[t] = sd[t] - s;
}
__global__ void k_scan_c(int* __restrict__ rs, const int* __restrict__ bbase, int N, int E){
    int i = blockIdx.x*256 + threadIdx.x;
    if (i < N) rs[i] += bbase[i >> 10];
    if (i == 0) rs[N] = E;
}
__global__ void k_scatter(const int* __restrict__ dst, const int* __restrict__ rs,
                          int* __restrict__ cnt, int* __restrict__ epos, int E){
    int e = blockIdx.x*256 + threadIdx.x;
    if (e >= E) return;
    int d = dst[e];
    int pos = rs[d] + atomicAdd(&cnt[d], 1);
    epos[e] = pos;
}

// ---------------- K2 (MFMA, 8-wave, 2-barrier pipeline, HW fp8) ----------------
__global__ __launch_bounds__(512, 4) void k_edge_mfma(
    const u16* __restrict__ xeb, const float* __restrict__ ea,
    const u16* __restrict__ W1b, const float* __restrict__ att_l,
    const float* __restrict__ r_dst, const int* __restrict__ src, const int* __restrict__ dst,
    const int* __restrict__ epos,
    u8* __restrict__ m, float* __restrict__ alpha, int ntiles, int E)
{
    __shared__ __align__(16) u8 sA[64*336];
    __shared__ __align__(16) u8 sM[64*144];
    int t = threadIdx.x, w = t >> 6, lane = t & 63, l15 = lane & 15, l4 = lane >> 4;

    s16x8 bfr[5];                 // wave w owns cols [w*16, w*16+16)
    #pragma unroll
    for (int kf = 0; kf < 5; ++kf)
        bfr[kf] = *(const s16x8*)(W1b + (size_t)(w*16 + l15)*160 + kf*32 + l4*8);

    int el = t >> 3, q = t & 7;   // 64 edges/tile, 8 threads/edge
    int stride = gridDim.x;
    int tile = blockIdx.x;

    uint4 cx0, cx1;               // prefetched 32B of xe[src[e]]
    u32 ce0, ce1;                 // prefetched 8B packed edge_attr
    int   pe = 0;                 // prefetched epos[e]
    float rdv = 0.f;              // prefetched r_dst[dst[e]]
    {
        int e = tile*64 + el;
        if (tile < ntiles && e < E){
            int sn = src[e];
            const uint4* xs = (const uint4*)xeb + (size_t)sn*16 + q*2;
            cx0 = xs[0]; cx1 = xs[1];
            float4 f = *(const float4*)(ea + (size_t)e*32 + q*4);
            ce0 = pk2(f.x, f.y); ce1 = pk2(f.z, f.w);
            pe  = epos[e];
            rdv = r_dst[dst[e]];
        }
    }

    int   ptile = -1;
    int   pe_prev = 0;
    float rdv_prev = 0.f;

    for (; tile < ntiles; tile += stride){
        int e = tile*64 + el;
        if (e < E){
            uint4* d = (uint4*)(sA + el*336 + q*32);
            d[0] = cx0; d[1] = cx1;
            *(u32*)(sA + el*336 + 256 + q*8)     = ce0;
            *(u32*)(sA + el*336 + 256 + q*8 + 4) = ce1;
        }
        int pe_cur = pe; float rdv_cur = rdv;

        int nt = tile + stride;
        if (nt < ntiles){
            int e2 = nt*64 + el;
            if (e2 < E){
                int sn = src[e2];
                const uint4* xs = (const uint4*)xeb + (size_t)sn*16 + q*2;
                cx0 = xs[0]; cx1 = xs[1];
                float4 f = *(const float4*)(ea + (size_t)e2*32 + q*4);
                ce0 = pk2(f.x, f.y); ce1 = pk2(f.z, f.w);
                pe  = epos[e2];
                rdv = r_dst[dst[e2]];
            }
        }

        // epilogue for previous tile (reads sM written last iteration)
        if (ptile >= 0){
            int ep = ptile*64 + el;
            if (ep < E){
                uint4 v = *(const uint4*)(sM + el*144 + q*16);
                ((uint4*)m)[(size_t)pe_prev*8 + q] = v;
                u32 ws[4] = {v.x, v.y, v.z, v.w};
                float dotv = 0.f;
                #pragma unroll
                for (int i = 0; i < 4; ++i){
                    f32x2 fa = hw_f8_dec2(ws[i]);
                    f32x2 fb = hw_f8_dec2_hi(ws[i]);
                    const float* al = att_l + q*16 + i*4;
                    dotv = fmaf(fa.x, al[0], dotv); dotv = fmaf(fa.y, al[1], dotv);
                    dotv = fmaf(fb.x, al[2], dotv); dotv = fmaf(fb.y, al[3], dotv);
                }
                dotv += __shfl_xor(dotv, 1); dotv += __shfl_xor(dotv, 2); dotv += __shfl_xor(dotv, 4);
                if (q == 0) alpha[pe_prev] = lrelu(dotv + rdv_prev);
            }
        }
        __syncthreads();

        f32x4 acc[4];
        #pragma unroll
        for (int rf = 0; rf < 4; ++rf) acc[rf] = (f32x4)0.f;
        #pragma unroll
        for (int kf = 0; kf < 5; ++kf){
            s16x8 a[4];
            #pragma unroll
            for (int rf = 0; rf < 4; ++rf)
                a[rf] = *(const s16x8*)(sA + (rf*16 + l15)*336 + kf*64 + l4*16);
            #pragma unroll
            for (int rf = 0; rf < 4; ++rf)
                acc[rf] = MFMA16(a[rf], bfr[kf], acc[rf]);
        }

        int col = w*16 + l15;
        #pragma unroll
        for (int rf = 0; rf < 4; ++rf)
            #pragma unroll
            for (int r = 0; r < 4; ++r){
                int row = rf*16 + l4*4 + r;
                sM[row*144 + col] = hw_f8(lrelu(acc[rf][r]));
            }
        __syncthreads();

        ptile = tile; pe_prev = pe_cur; rdv_prev = rdv_cur;
    }

    if (ptile >= 0){
        int ep = ptile*64 + el;
        if (ep < E){
            uint4 v = *(const uint4*)(sM + el*144 + q*16);
            ((uint4*)m)[(size_t)pe_prev*8 + q] = v;
            u32 ws[4] = {v.x, v.y, v.z, v.w};
            float dotv = 0.f;
            #pragma unroll
            for (int i = 0; i < 4; ++i){
                f32x2 fa = hw_f8_dec2(ws[i]);
                f32x2 fb = hw_f8_dec2_hi(ws[i]);
                const float* al = att_l + q*16 + i*4;
                dotv = fmaf(fa.x, al[0], dotv); dotv = fmaf(fa.y, al[1], dotv);
                dotv = fmaf(fb.x, al[2], dotv); dotv = fmaf(fb.y, al[3], dotv);
            }
            dotv += __shfl_xor(dotv, 1); dotv += __shfl_xor(dotv, 2); dotv += __shfl_xor(dotv, 4);
            if (q == 0) alpha[pe_prev] = lrelu(dotv + rdv_prev);
        }
    }
}

// ---------------- K4: streaming segment softmax + weighted sum (fp8 m, HW dec) -> bf16 a_agg ----------------
__global__ __launch_bounds__(256) void k_agg(
    const int* __restrict__ rs,
    const float* __restrict__ alpha, const u8* __restrict__ m,
    u16* __restrict__ a_out, int N)
{
    int wid  = (blockIdx.x*256 + threadIdx.x) >> 6;
    int lane = threadIdx.x & 63;
    if (wid >= N) return;
    int s = rs[wid], t = rs[wid+1];
    int deg = t - s;
    float ax = 0.f, ay = 0.f;
    if (deg > 0 && deg <= 64){
        float av = -1e38f;
        if (lane < deg) av = alpha[s + lane];
        float mx = wave_max(av);
        float ev = (lane < deg) ? __expf(av - mx) : 0.f;
        float ssum = wave_sum(ev);
        float wreg = ev / ssum;
        int k = 0;
        for (; k + 2 <= deg; k += 2){
            float w0 = __shfl(wreg, k);
            float w1 = __shfl(wreg, k + 1);
            u32 u0 = *(const u16*)(m + (size_t)(s + k)*HD + 2*lane);
            u32 u1 = *(const u16*)(m + (size_t)(s + k + 1)*HD + 2*lane);
            f32x2 f0 = hw_f8_dec2(u0);
            f32x2 f1 = hw_f8_dec2(u1);
            ax = fmaf(w0, f0.x, ax); ay = fmaf(w0, f0.y, ay);
            ax = fmaf(w1, f1.x, ax); ay = fmaf(w1, f1.y, ay);
        }
        if (k < deg){
            float w0 = __shfl(wreg, k);
            u32 u0 = *(const u16*)(m + (size_t)(s + k)*HD + 2*lane);
            f32x2 f0 = hw_f8_dec2(u0);
            ax = fmaf(w0, f0.x, ax); ay = fmaf(w0, f0.y, ay);
        }
    } else if (deg > 64){
        float mx = -1e38f;
        for (int k = lane; k < deg; k += 64) mx = fmaxf(mx, alpha[s + k]);
        mx = wave_max(mx);
        float ssum = 0.f;
        for (int k = lane; k < deg; k += 64) ssum += __expf(alpha[s + k] - mx);
        ssum = wave_sum(ssum);
        float inv = 1.f / ssum;
        for (int k = 0; k < deg; ++k){
            float wgt = __expf(alpha[s + k] - mx) * inv;
            u32 u0 = *(const u16*)(m + (size_t)(s + k)*HD + 2*lane);
            f32x2 f0 = hw_f8_dec2(u0);
            ax = fmaf(wgt, f0.x, ax);
            ay = fmaf(wgt, f0.y, ay);
        }
    }
    *(u32*)(a_out + (size_t)wid*HD + 2*lane) = pk2(ax, ay);
}

// ---------------- K5a (MFMA): Agru h-half = fp8(elu(W2@a + bc)), a in bf16 ----------------
__global__ __launch_bounds__(256, 2) void k_conv2_mfma(
    const u16* __restrict__ a, const u16* __restrict__ W2b, const float* __restrict__ bc,
    u8* __restrict__ Agru, int N)
{
    __shared__ __align__(16) u8 sA[64*272];
    __shared__ __align__(16) u8 sO[64*272];
    int t = threadIdx.x, w = t >> 6, lane = t & 63, l15 = lane & 15, l4 = lane >> 4;
    int tile = blockIdx.x;

    s16x8 bfr[4][2];
    #pragma unroll
    for (int kf = 0; kf < 4; ++kf)
        #pragma unroll
        for (int cf = 0; cf < 2; ++cf)
            bfr[kf][cf] = *(const s16x8*)(W2b + (size_t)(w*32 + cf*16 + l15)*128 + kf*32 + l4*8);

    int el = t >> 2, q = t & 3;
    size_t n = (size_t)tile*64 + el;
    {
        const uint4* as = (const uint4*)(a + n*HD) + q*4;
        uint4 v0 = as[0], v1 = as[1], v2 = as[2], v3 = as[3];
        uint4* d = (uint4*)(sA + el*272 + q*64);
        d[0] = v0; d[1] = v1; d[2] = v2; d[3] = v3;
    }
    __syncthreads();

    f32x4 acc[4][2];
    #pragma unroll
    for (int rf = 0; rf < 4; ++rf){ acc[rf][0] = (f32x4)0.f; acc[rf][1] = (f32x4)0.f; }
    #pragma unroll
    for (int kf = 0; kf < 4; ++kf){
        s16x8 av[4];
        #pragma unroll
        for (int rf = 0; rf < 4; ++rf)
            av[rf] = *(const s16x8*)(sA + (rf*16 + l15)*272 + kf*64 + l4*16);
        #pragma unroll
        for (int rf = 0; rf < 4; ++rf){
            acc[rf][0] = MFMA16(av[rf], bfr[kf][0], acc[rf][0]);
            acc[rf][1] = MFMA16(av[rf], bfr[kf][1], acc[rf][1]);
        }
    }
    float b0 = bc[w*32 + l15], b1 = bc[w*32 + 16 + l15];
    #pragma unroll
    for (int rf = 0; rf < 4; ++rf)
        #pragma unroll
        for (int r = 0; r < 4; ++r){
            int row = rf*16 + l4*4 + r;
            *(u16*)(sO + row*272 + (w*32 + l15)*2)      = f32_to_bf16(eluf_(acc[rf][0][r] + b0));
            *(u16*)(sO + row*272 + (w*32 + 16 + l15)*2) = f32_to_bf16(eluf_(acc[rf][1][r] + b1));
        }
    __syncthreads();
    #pragma unroll
    for (int i = 0; i < 4; ++i){
        uint4 v = *(const uint4*)(sO + el*272 + q*64 + 16*i);
        float f0 = bf16lo(v.x), f1 = bf16hi(v.x), f2 = bf16lo(v.y), f3 = bf16hi(v.y);
        float f4 = bf16lo(v.z), f5 = bf16hi(v.z), f6 = bf16lo(v.w), f7 = bf16hi(v.w);
        uint2 p; p.x = hw_f8x4(f0, f1, f2, f3); p.y = hw_f8x4(f4, f5, f6, f7);
        *(uint2*)(Agru + n*256 + q*32 + i*8) = p;      // h half (K<128)
    }
}

// ---------------- K5b (fp8 MFMA): GRU cell + fused LayerNorm -> out ----------------
// Zero-skip B-pack: gate2 (in) only K<128, gate3 (hn) only K>=128. B resident in 48 VGPRs.
__global__ __launch_bounds__(512, 4) void k_gru_mfma(
    const u8* __restrict__ Agru, const u16* __restrict__ xeb, const u8* __restrict__ Bgf8,
    const float* __restrict__ bih, const float* __restrict__ bhh,
    float* __restrict__ out, int N, int ntiles)
{
    __shared__ __align__(16) u8 sA[32*272];          // fp8 [h|xe] rows, +16 pad
    __shared__ __align__(16) u8 sX[32*272];          // bf16 xe rows (residual), +16 pad
    __shared__ __align__(16) float sOut[32*132];
    int t = threadIdx.x, w = t >> 6, lane = t & 63, l15 = lane & 15, l4 = lane >> 4;

    i64_ bfr0[8], bfr1[8], bfr2[4], bfr3[4];         // 24 frags x 2 VGPR = 48
    {
        int jc = w*16 + l15;
        #pragma unroll
        for (int kf = 0; kf < 8; ++kf){
            bfr0[kf] = *(const i64_*)(Bgf8 + (size_t)(jc)*256       + kf*32 + l4*8);
            bfr1[kf] = *(const i64_*)(Bgf8 + (size_t)(128 + jc)*256 + kf*32 + l4*8);
        }
        #pragma unroll
        for (int kf = 0; kf < 4; ++kf){
            bfr2[kf] = *(const i64_*)(Bgf8 + (size_t)(256 + jc)*256 + kf*32 + l4*8);
            bfr3[kf] = *(const i64_*)(Bgf8 + (size_t)(384 + jc)*256 + (kf+4)*32 + l4*8);
        }
    }
    int j = w*16 + l15;
    float rb = bih[j] + bhh[j];
    float zb = bih[128 + j] + bhh[128 + j];
    float ib = bih[256 + j];
    float hb = bhh[256 + j];

    int el = t >> 4, part = t & 15;
    int stride = gridDim.x;
    int tile = blockIdx.x;
    uint4 pa, px;                  // prefetched fp8 row chunk + bf16 xe chunk
    if (tile < ntiles){
        pa = *((const uint4*)Agru + ((size_t)tile*32 + el)*16 + part);
        px = *((const uint4*)xeb  + ((size_t)tile*32 + el)*16 + part);
    }

    for (; tile < ntiles; tile += stride){
        *(uint4*)(sA + el*272 + part*16) = pa;
        *(uint4*)(sX + el*272 + part*16) = px;
        __syncthreads();

        int nt = tile + stride;
        if (nt < ntiles){
            pa = *((const uint4*)Agru + ((size_t)nt*32 + el)*16 + part);
            px = *((const uint4*)xeb  + ((size_t)nt*32 + el)*16 + part);
        }

        f32x4 acc[2][4];
        #pragma unroll
        for (int rf = 0; rf < 2; ++rf)
            #pragma unroll
            for (int g = 0; g < 4; ++g) acc[rf][g] = (f32x4)0.f;
        #pragma unroll
        for (int kf = 0; kf < 8; ++kf){
            i64_ a0 = *(const i64_*)(sA + l15*272 + kf*32 + l4*8);
            i64_ a1 = *(const i64_*)(sA + (16 + l15)*272 + kf*32 + l4*8);
            acc[0][0] = MFMAF8(a0, bfr0[kf], acc[0][0]);
            acc[1][0] = MFMAF8(a1, bfr0[kf], acc[1][0]);
            acc[0][1] = MFMAF8(a0, bfr1[kf], acc[0][1]);
            acc[1][1] = MFMAF8(a1, bfr1[kf], acc[1][1]);
            if (kf < 4){
                acc[0][2] = MFMAF8(a0, bfr2[kf], acc[0][2]);
                acc[1][2] = MFMAF8(a1, bfr2[kf], acc[1][2]);
            } else {
                acc[0][3] = MFMAF8(a0, bfr3[kf-4], acc[0][3]);
                acc[1][3] = MFMAF8(a1, bfr3[kf-4], acc[1][3]);
            }
        }
        #pragma unroll
        for (int rf = 0; rf < 2; ++rf)
            #pragma unroll
            for (int r = 0; r < 4; ++r){
                int rl = rf*16 + l4*4 + r;
                float rr = sigmoidf_(acc[rf][0][r] + rb);
                float zz = sigmoidf_(acc[rf][1][r] + zb);
                float iv = acc[rf][2][r] + ib;
                float hv = acc[rf][3][r] + hb;
                float nc = tanhf_(iv + rr*hv);
                float xej = bf16f(*(const u16*)(sX + rl*272 + 2*j));
                float v = (1.f - zz)*nc + zz*xej;
                v = fmaxf(v, 0.f);
                sOut[rl*132 + j] = v;
            }
        __syncthreads();
        {
            int row = t >> 4, sub = t & 15;
            const float* rp = sOut + row*132 + sub*8;
            float v0 = rp[0], v1 = rp[1], v2 = rp[2], v3 = rp[3];
            float v4 = rp[4], v5 = rp[5], v6 = rp[6], v7 = rp[7];
            float s1 = v0+v1+v2+v3+v4+v5+v6+v7;
            float s2 = v0*v0+v1*v1+v2*v2+v3*v3+v4*v4+v5*v5+v6*v6+v7*v7;
            #pragma unroll
            for (int o = 1; o < 16; o <<= 1){ s1 += __shfl_xor(s1, o); s2 += __shfl_xor(s2, o); }
            float mu  = s1 * (1.f/128.f);
            float var = s2 * (1.f/128.f) - mu*mu;
            var = fmaxf(var, 0.f);
            float rsd = rsqrtf(var + 1e-5f);
            float* op = out + ((size_t)tile*32 + row)*128 + sub*8;
            float4 o0, o1;
            o0.x = (v0-mu)*rsd; o0.y = (v1-mu)*rsd; o0.z = (v2-mu)*rsd; o0.w = (v3-mu)*rsd;
            o1.x = (v4-mu)*rsd; o1.y = (v5-mu)*rsd; o1.z = (v6-mu)*rsd; o1.w = (v7-mu)*rsd;
            ((float4*)op)[0] = o0; ((float4*)op)[1] = o1;
        }
        __syncthreads();
    }
}

// ---------------- host ----------------
extern "C" void kernel_launch(void* const* d_in, const int* in_sizes, int n_in,
                              void* d_out, int out_size, void* d_ws, size_t ws_size,
                              hipStream_t stream)
{
    const float* x       = (const float*)d_in[0];
    const float* ea      = (const float*)d_in[1];
    const float* W_enter = (const float*)d_in[2];
    const float* b_enter = (const float*)d_in[3];
    const float* W1      = (const float*)d_in[4];
    const float* att_l   = (const float*)d_in[5];
    const float* att_r   = (const float*)d_in[6];
    const float* W2      = (const float*)d_in[7];
    const float* b_conv  = (const float*)d_in[8];
    const float* W_ih    = (const float*)d_in[9];
    const float* W_hh    = (const float*)d_in[10];
    const float* b_ih    = (const float*)d_in[11];
    const float* b_hh    = (const float*)d_in[12];
    const int*   eidx    = (const int*)d_in[13];

    int N = in_sizes[0] / DIN;
    int E = in_sizes[13] / 2;
    const int* src = eidx;
    const int* dst = eidx + E;
    float* out = (float*)d_out;

    size_t off = 0;
    char* base = (char*)d_ws;
    auto alloc = [&](size_t bytes) -> char* {
        char* p = base + off;
        off = (off + bytes + 255) & ~(size_t)255;
        return p;
    };
    u16*   xeb   = (u16*)  alloc((size_t)N*HD*2);    // xe bf16 (k_edge gather + GRU residual)
    u8*    Agru  = (u8*)   alloc((size_t)N*256);     // [h | xe] fp8 (GRU A)
    float* r_dst = (float*)alloc((size_t)N*4);
    float* alpha = (float*)alloc((size_t)E*4);
    int*   deg   = (int*)  alloc((size_t)N*4);
    int*   rs    = (int*)  alloc((size_t)(N+1)*4);
    int*   cnt   = (int*)  alloc((size_t)N*4);
    int*   epos  = (int*)  alloc((size_t)E*4);
    int*   btot  = (int*)  alloc(1024);
    int*   bbase = (int*)  alloc(1024);
    u16*   W1b   = (u16*)  alloc(20480*2);
    u16*   W2b   = (u16*)  alloc(16384*2);
    u16*   Wentb = (u16*)  alloc(8192*2);
    u8*    Bgf8  = (u8*)   alloc(131072);
    u8*    mbuf  = (u8*)   alloc((size_t)E*HD);      // fp8 m, CSR-sorted

    u16* a_agg = (u16*)out;   // d_out reused as bf16 a_agg (dead before k_gru writes)

    int ntiles_n64 = N/64, ntiles_e = (E + 63)/64, ntiles_g = N/32;

    k_prep   <<<(176128+255)/256, 256, 0, stream>>>(W1, W2, W_enter, W_ih, W_hh, W1b, W2b, Wentb, Bgf8);
    k_zero2  <<<(N+255)/256, 256, 0, stream>>>(deg, cnt, N);
    k_enter_mfma<<<ntiles_n64, 256, 0, stream>>>(x, Wentb, b_enter, att_r, xeb, Agru, r_dst, N);
    k_hist   <<<(E+255)/256, 256, 0, stream>>>(dst, deg, E);
    k_scan_a <<<N/1024, 256, 0, stream>>>(deg, rs, btot, N);
    k_scan_b <<<1, 256, 0, stream>>>(btot, bbase);
    k_scan_c <<<(N+255)/256, 256, 0, stream>>>(rs, bbase, N, E);
    k_scatter<<<(E+255)/256, 256, 0, stream>>>(dst, rs, cnt, epos, E);
    k_edge_mfma<<<1024, 512, 0, stream>>>(xeb, ea, W1b, att_l, r_dst, src, dst, epos,
                                          mbuf, alpha, ntiles_e, E);
    k_agg    <<<(N+3)/4, 256, 0, stream>>>(rs, alpha, mbuf, a_agg, N);
    k_conv2_mfma<<<ntiles_n64, 256, 0, stream>>>(a_agg, W2b, b_conv, Agru, N);
    k_gru_mfma  <<<2048, 512, 0, stream>>>(Agru, xeb, Bgf8, b_ih, b_hh, out, N, ntiles_g);
}

// Round 11
// 524.660 us; speedup vs baseline: 10.1376x; 1.0462x over previous
//
#include <hip/hip_runtime.h>
#include <stdint.h>

#define HD  128
#define DIN 64
#define DE  32

typedef unsigned int u32; typedef unsigned short u16; typedef unsigned char u8;
typedef long i64_;
typedef short s16x8 __attribute__((ext_vector_type(8)));
typedef float f32x4 __attribute__((ext_vector_type(4)));
typedef float f32x2 __attribute__((ext_vector_type(2)));

#define MFMA16(a,b,c)  __builtin_amdgcn_mfma_f32_16x16x32_bf16((a),(b),(c),0,0,0)
#define MFMAF8(a,b,c)  __builtin_amdgcn_mfma_f32_16x16x32_fp8_fp8((a),(b),(c),0,0,0)

__device__ __forceinline__ float lrelu(float x){ return x > 0.f ? x : 0.01f*x; }
__device__ __forceinline__ float sigmoidf_(float x){ return 1.f/(1.f + __expf(-x)); }
__device__ __forceinline__ float tanhf_(float x){
    float t = fminf(fmaxf(x, -15.f), 15.f);
    float e = __expf(2.f*t);
    return (e - 1.f)/(e + 1.f);
}
__device__ __forceinline__ float eluf_(float x){ return x > 0.f ? x : expm1f(x); }

__device__ __forceinline__ u16 f32_to_bf16(float x){
    u32 u = __float_as_uint(x);
    u += 0x7FFFu + ((u >> 16) & 1u);
    return (u16)(u >> 16);
}
__device__ __forceinline__ float bf16lo(u32 u){ return __uint_as_float((u & 0xFFFFu) << 16); }
__device__ __forceinline__ float bf16hi(u32 u){ return __uint_as_float(u & 0xFFFF0000u); }
__device__ __forceinline__ float bf16f(u16 h){ return __uint_as_float(((u32)h) << 16); }
__device__ __forceinline__ u32 pk2(float a, float b){
    return (u32)f32_to_bf16(a) | ((u32)f32_to_bf16(b) << 16);
}
// HW OCP e4m3fn converters (gfx950)
__device__ __forceinline__ u8 hw_f8(float v){
    return (u8)__builtin_amdgcn_cvt_pk_fp8_f32(v, v, 0, false);
}
__device__ __forceinline__ u32 hw_f8x4(float a, float b, float c, float d){
    u32 r = (u32)__builtin_amdgcn_cvt_pk_fp8_f32(a, b, 0, false);
    r = (u32)__builtin_amdgcn_cvt_pk_fp8_f32(c, d, (int)r, true);
    return r;
}
__device__ __forceinline__ f32x2 hw_f8_dec2(u32 u){   // decodes bytes [0:1]
    return __builtin_amdgcn_cvt_pk_f32_fp8((int)u, false);
}
__device__ __forceinline__ f32x2 hw_f8_dec2_hi(u32 u){ // decodes bytes [2:3]
    return __builtin_amdgcn_cvt_pk_f32_fp8((int)u, true);
}

__device__ __forceinline__ float wave_max(float v){
    #pragma unroll
    for (int o = 32; o > 0; o >>= 1) v = fmaxf(v, __shfl_xor(v, o, 64));
    return v;
}
__device__ __forceinline__ float wave_sum(float v){
    #pragma unroll
    for (int o = 32; o > 0; o >>= 1) v += __shfl_xor(v, o, 64);
    return v;
}
__device__ __forceinline__ float dot8_bf16(uint4 v, const float* __restrict__ al){
    float d = 0.f;
    d = fmaf(bf16lo(v.x), al[0], d); d = fmaf(bf16hi(v.x), al[1], d);
    d = fmaf(bf16lo(v.y), al[2], d); d = fmaf(bf16hi(v.y), al[3], d);
    d = fmaf(bf16lo(v.z), al[4], d); d = fmaf(bf16hi(v.z), al[5], d);
    d = fmaf(bf16lo(v.w), al[6], d); d = fmaf(bf16hi(v.w), al[7], d);
    return d;
}

// ---------------- weight prep: fp32 -> bf16 (+ fp8 GRU B-pack) ----------------
__global__ void k_prep(const float* __restrict__ W1, const float* __restrict__ W2,
                       const float* __restrict__ Went,
                       const float* __restrict__ Wih, const float* __restrict__ Whh,
                       u16* __restrict__ W1b, u16* __restrict__ W2b,
                       u16* __restrict__ Wentb, u8* __restrict__ Bgf8)
{
    int i = blockIdx.x*256 + threadIdx.x;
    if (i < 20480){ W1b[i] = f32_to_bf16(W1[i]); return; }
    i -= 20480;
    if (i < 16384){ W2b[i] = f32_to_bf16(W2[i]); return; }
    i -= 16384;
    if (i < 8192){ Wentb[i] = f32_to_bf16(Went[i]); return; }
    i -= 8192;
    if (i < 131072){
        int col = i >> 8, k = i & 255;
        int g = col >> 7, j = col & 127;
        float v;
        if      (g == 0) v = (k < 128) ? Wih[j*128 + k]        : Whh[j*128 + k - 128];
        else if (g == 1) v = (k < 128) ? Wih[(128+j)*128 + k]  : Whh[(128+j)*128 + k - 128];
        else if (g == 2) v = (k < 128) ? Wih[(256+j)*128 + k]  : 0.f;
        else             v = (k < 128) ? 0.f                   : Whh[(256+j)*128 + k - 128];
        Bgf8[i] = hw_f8(v);
    }
}

// ---------------- K1 (MFMA): xeb = bf16(lrelu(x@W^T+b)); Agru xe-half fp8; r_dst ----------------
__global__ __launch_bounds__(256, 2) void k_enter_mfma(
    const float* __restrict__ x, const u16* __restrict__ Wb, const float* __restrict__ be,
    const float* __restrict__ att_r, u16* __restrict__ xeb, u8* __restrict__ Agru,
    float* __restrict__ r_out, int N)
{
    __shared__ __align__(16) u8 sA[64*144];
    __shared__ __align__(16) u8 sO[64*272];
    int t = threadIdx.x, w = t >> 6, lane = t & 63, l15 = lane & 15, l4 = lane >> 4;
    int tile = blockIdx.x;

    s16x8 bfr[2][2];
    #pragma unroll
    for (int kf = 0; kf < 2; ++kf)
        #pragma unroll
        for (int cf = 0; cf < 2; ++cf)
            bfr[kf][cf] = *(const s16x8*)(Wb + (size_t)(w*32 + cf*16 + l15)*64 + kf*32 + l4*8);

    int el = t >> 2, q = t & 3;
    size_t n = (size_t)tile*64 + el;
    {
        const float4* xs = (const float4*)(x + n*64 + q*16);
        float4 f0 = xs[0], f1 = xs[1], f2 = xs[2], f3 = xs[3];
        uint4 o0, o1;
        o0.x = pk2(f0.x,f0.y); o0.y = pk2(f0.z,f0.w); o0.z = pk2(f1.x,f1.y); o0.w = pk2(f1.z,f1.w);
        o1.x = pk2(f2.x,f2.y); o1.y = pk2(f2.z,f2.w); o1.z = pk2(f3.x,f3.y); o1.w = pk2(f3.z,f3.w);
        *(uint4*)(sA + el*144 + q*32)      = o0;
        *(uint4*)(sA + el*144 + q*32 + 16) = o1;
    }
    __syncthreads();

    f32x4 acc[4][2];
    #pragma unroll
    for (int rf = 0; rf < 4; ++rf){ acc[rf][0] = (f32x4)0.f; acc[rf][1] = (f32x4)0.f; }
    #pragma unroll
    for (int kf = 0; kf < 2; ++kf){
        s16x8 a[4];
        #pragma unroll
        for (int rf = 0; rf < 4; ++rf)
            a[rf] = *(const s16x8*)(sA + (rf*16 + l15)*144 + kf*64 + l4*16);
        #pragma unroll
        for (int rf = 0; rf < 4; ++rf){
            acc[rf][0] = MFMA16(a[rf], bfr[kf][0], acc[rf][0]);
            acc[rf][1] = MFMA16(a[rf], bfr[kf][1], acc[rf][1]);
        }
    }
    float b0 = be[w*32 + l15], b1 = be[w*32 + 16 + l15];
    #pragma unroll
    for (int rf = 0; rf < 4; ++rf)
        #pragma unroll
        for (int r = 0; r < 4; ++r){
            int row = rf*16 + l4*4 + r;
            *(u16*)(sO + row*272 + (w*32 + l15)*2)      = f32_to_bf16(lrelu(acc[rf][0][r] + b0));
            *(u16*)(sO + row*272 + (w*32 + 16 + l15)*2) = f32_to_bf16(lrelu(acc[rf][1][r] + b1));
        }
    __syncthreads();

    float dot = 0.f;
    #pragma unroll
    for (int i = 0; i < 4; ++i){
        uint4 v = *(const uint4*)(sO + el*272 + q*64 + 16*i);
        ((uint4*)xeb)[n*16 + q*4 + i] = v;
        float f0 = bf16lo(v.x), f1 = bf16hi(v.x), f2 = bf16lo(v.y), f3 = bf16hi(v.y);
        float f4 = bf16lo(v.z), f5 = bf16hi(v.z), f6 = bf16lo(v.w), f7 = bf16hi(v.w);
        const float* al = att_r + q*32 + 8*i;
        dot = fmaf(f0, al[0], dot); dot = fmaf(f1, al[1], dot);
        dot = fmaf(f2, al[2], dot); dot = fmaf(f3, al[3], dot);
        dot = fmaf(f4, al[4], dot); dot = fmaf(f5, al[5], dot);
        dot = fmaf(f6, al[6], dot); dot = fmaf(f7, al[7], dot);
        uint2 p; p.x = hw_f8x4(f0, f1, f2, f3); p.y = hw_f8x4(f4, f5, f6, f7);
        *(uint2*)(Agru + n*256 + 128 + q*32 + i*8) = p;   // xe half (K>=128)
    }
    dot += __shfl_xor(dot, 1); dot += __shfl_xor(dot, 2);
    if (q == 0) r_out[n] = dot;
}

// ---------------- CSR build ----------------
__global__ void k_hist(const int* __restrict__ dst, int* __restrict__ deg, int E){
    int e = blockIdx.x*256 + threadIdx.x;
    if (e < E) atomicAdd(&deg[dst[e]], 1);
}
__global__ __launch_bounds__(256) void k_scan_a(
    const int* __restrict__ deg, int* __restrict__ rs, int* __restrict__ btot, int N)
{
    __shared__ int sd[256];
    int b = blockIdx.x, t = threadIdx.x;
    int base = b*1024 + t*4;
    int d0 = deg[base], d1 = deg[base+1], d2 = deg[base+2], d3 = deg[base+3];
    int s = d0 + d1 + d2 + d3;
    sd[t] = s; __syncthreads();
    for (int o = 1; o < 256; o <<= 1){
        int v = (t >= o) ? sd[t-o] : 0;
        __syncthreads();
        sd[t] += v;
        __syncthreads();
    }
    int ex = sd[t] - s;
    rs[base]   = ex;
    rs[base+1] = ex + d0;
    rs[base+2] = ex + d0 + d1;
    rs[base+3] = ex + d0 + d1 + d2;
    if (t == 0) btot[b] = sd[255];
}
__global__ __launch_bounds__(256) void k_scan_b(const int* __restrict__ btot, int* __restrict__ bbase){
    __shared__ int sd[256];
    int t = threadIdx.x;
    int s = btot[t];
    sd[t] = s; __syncthreads();
    for (int o = 1; o < 256; o <<= 1){
        int v = (t >= o) ? sd[t-o] : 0;
        __syncthreads();
        sd[t] += v;
        __syncthreads();
    }
    bbase[t] = sd[t] - s;
}
__global__ void k_scan_c(int* __restrict__ rs, const int* __restrict__ bbase, int N, int E){
    int i = blockIdx.x*256 + threadIdx.x;
    if (i < N) rs[i] += bbase[i >> 10];
    if (i == 0) rs[N] = E;
}
__global__ void k_scatter(const int* __restrict__ dst, const int* __restrict__ rs,
                          int* __restrict__ cnt, int* __restrict__ epos, int E){
    int e = blockIdx.x*256 + threadIdx.x;
    if (e >= E) return;
    int d = dst[e];
    int pos = rs[d] + atomicAdd(&cnt[d], 1);
    epos[e] = pos;
}

// ---------------- K2 (MFMA, 8-wave, 2-barrier pipeline, HW fp8) ----------------
__global__ __launch_bounds__(512, 4) void k_edge_mfma(
    const u16* __restrict__ xeb, const float* __restrict__ ea,
    const u16* __restrict__ W1b, const float* __restrict__ att_l,
    const float* __restrict__ r_dst, const int* __restrict__ src, const int* __restrict__ dst,
    const int* __restrict__ epos,
    u8* __restrict__ m, float* __restrict__ alpha, int ntiles, int E)
{
    __shared__ __align__(16) u8 sA[64*336];
    __shared__ __align__(16) u8 sM[64*144];
    int t = threadIdx.x, w = t >> 6, lane = t & 63, l15 = lane & 15, l4 = lane >> 4;

    s16x8 bfr[5];                 // wave w owns cols [w*16, w*16+16)
    #pragma unroll
    for (int kf = 0; kf < 5; ++kf)
        bfr[kf] = *(const s16x8*)(W1b + (size_t)(w*16 + l15)*160 + kf*32 + l4*8);

    int el = t >> 3, q = t & 7;   // 64 edges/tile, 8 threads/edge
    int stride = gridDim.x;
    int tile = blockIdx.x;

    uint4 cx0, cx1;
    u32 ce0, ce1;
    int   pe = 0;
    float rdv = 0.f;
    {
        int e = tile*64 + el;
        if (tile < ntiles && e < E){
            int sn = src[e];
            const uint4* xs = (const uint4*)xeb + (size_t)sn*16 + q*2;
            cx0 = xs[0]; cx1 = xs[1];
            float4 f = *(const float4*)(ea + (size_t)e*32 + q*4);
            ce0 = pk2(f.x, f.y); ce1 = pk2(f.z, f.w);
            pe  = epos[e];
            rdv = r_dst[dst[e]];
        }
    }

    int   ptile = -1;
    int   pe_prev = 0;
    float rdv_prev = 0.f;

    for (; tile < ntiles; tile += stride){
        int e = tile*64 + el;
        if (e < E){
            uint4* d = (uint4*)(sA + el*336 + q*32);
            d[0] = cx0; d[1] = cx1;
            *(u32*)(sA + el*336 + 256 + q*8)     = ce0;
            *(u32*)(sA + el*336 + 256 + q*8 + 4) = ce1;
        }
        int pe_cur = pe; float rdv_cur = rdv;

        int nt = tile + stride;
        if (nt < ntiles){
            int e2 = nt*64 + el;
            if (e2 < E){
                int sn = src[e2];
                const uint4* xs = (const uint4*)xeb + (size_t)sn*16 + q*2;
                cx0 = xs[0]; cx1 = xs[1];
                float4 f = *(const float4*)(ea + (size_t)e2*32 + q*4);
                ce0 = pk2(f.x, f.y); ce1 = pk2(f.z, f.w);
                pe  = epos[e2];
                rdv = r_dst[dst[e2]];
            }
        }

        if (ptile >= 0){
            int ep = ptile*64 + el;
            if (ep < E){
                uint4 v = *(const uint4*)(sM + el*144 + q*16);
                ((uint4*)m)[(size_t)pe_prev*8 + q] = v;
                u32 ws[4] = {v.x, v.y, v.z, v.w};
                float dotv = 0.f;
                #pragma unroll
                for (int i = 0; i < 4; ++i){
                    f32x2 fa = hw_f8_dec2(ws[i]);
                    f32x2 fb = hw_f8_dec2_hi(ws[i]);
                    const float* al = att_l + q*16 + i*4;
                    dotv = fmaf(fa.x, al[0], dotv); dotv = fmaf(fa.y, al[1], dotv);
                    dotv = fmaf(fb.x, al[2], dotv); dotv = fmaf(fb.y, al[3], dotv);
                }
                dotv += __shfl_xor(dotv, 1); dotv += __shfl_xor(dotv, 2); dotv += __shfl_xor(dotv, 4);
                if (q == 0) alpha[pe_prev] = lrelu(dotv + rdv_prev);
            }
        }
        __syncthreads();

        f32x4 acc[4];
        #pragma unroll
        for (int rf = 0; rf < 4; ++rf) acc[rf] = (f32x4)0.f;
        #pragma unroll
        for (int kf = 0; kf < 5; ++kf){
            s16x8 a[4];
            #pragma unroll
            for (int rf = 0; rf < 4; ++rf)
                a[rf] = *(const s16x8*)(sA + (rf*16 + l15)*336 + kf*64 + l4*16);
            #pragma unroll
            for (int rf = 0; rf < 4; ++rf)
                acc[rf] = MFMA16(a[rf], bfr[kf], acc[rf]);
        }

        int col = w*16 + l15;
        #pragma unroll
        for (int rf = 0; rf < 4; ++rf)
            #pragma unroll
            for (int r = 0; r < 4; ++r){
                int row = rf*16 + l4*4 + r;
                sM[row*144 + col] = hw_f8(lrelu(acc[rf][r]));
            }
        __syncthreads();

        ptile = tile; pe_prev = pe_cur; rdv_prev = rdv_cur;
    }

    if (ptile >= 0){
        int ep = ptile*64 + el;
        if (ep < E){
            uint4 v = *(const uint4*)(sM + el*144 + q*16);
            ((uint4*)m)[(size_t)pe_prev*8 + q] = v;
            u32 ws[4] = {v.x, v.y, v.z, v.w};
            float dotv = 0.f;
            #pragma unroll
            for (int i = 0; i < 4; ++i){
                f32x2 fa = hw_f8_dec2(ws[i]);
                f32x2 fb = hw_f8_dec2_hi(ws[i]);
                const float* al = att_l + q*16 + i*4;
                dotv = fmaf(fa.x, al[0], dotv); dotv = fmaf(fa.y, al[1], dotv);
                dotv = fmaf(fb.x, al[2], dotv); dotv = fmaf(fb.y, al[3], dotv);
            }
            dotv += __shfl_xor(dotv, 1); dotv += __shfl_xor(dotv, 2); dotv += __shfl_xor(dotv, 4);
            if (q == 0) alpha[pe_prev] = lrelu(dotv + rdv_prev);
        }
    }
}

// ---------------- K4+K5a fused: segment softmax-aggregate (fp8 m) -> LDS -> W2 MFMA -> fp8 Agru ----------------
__global__ __launch_bounds__(512, 2) void k_aggconv(
    const int* __restrict__ rs, const float* __restrict__ alpha, const u8* __restrict__ m,
    const u16* __restrict__ W2b, const float* __restrict__ bc,
    u8* __restrict__ Agru, int N)
{
    __shared__ __align__(16) u8 sA[64*272];   // bf16 aggregated rows (+16B pad)
    __shared__ __align__(16) u8 sO[64*272];   // bf16 conv output rows
    int t = threadIdx.x, w = t >> 6, lane = t & 63, l15 = lane & 15, l4 = lane >> 4;
    int tile = blockIdx.x;

    s16x8 bfr[4];                 // wave w owns cols [w*16, w*16+16)
    #pragma unroll
    for (int kf = 0; kf < 4; ++kf)
        bfr[kf] = *(const s16x8*)(W2b + (size_t)(w*16 + l15)*128 + kf*32 + l4*8);

    // ---- phase 1: each wave aggregates 8 nodes into sA ----
    #pragma unroll 1
    for (int i = 0; i < 8; ++i){
        int nloc = w*8 + i;
        int n = tile*64 + nloc;
        int s = rs[n], tend = rs[n+1];
        int deg = tend - s;
        float ax = 0.f, ay = 0.f;
        if (deg > 0 && deg <= 64){
            float av = -1e38f;
            if (lane < deg) av = alpha[s + lane];
            float mx = wave_max(av);
            float ev = (lane < deg) ? __expf(av - mx) : 0.f;
            float ssum = wave_sum(ev);
            float wreg = ev / ssum;
            int k = 0;
            for (; k + 2 <= deg; k += 2){
                float w0 = __shfl(wreg, k);
                float w1 = __shfl(wreg, k + 1);
                u32 u0 = *(const u16*)(m + (size_t)(s + k)*HD + 2*lane);
                u32 u1 = *(const u16*)(m + (size_t)(s + k + 1)*HD + 2*lane);
                f32x2 f0 = hw_f8_dec2(u0);
                f32x2 f1 = hw_f8_dec2(u1);
                ax = fmaf(w0, f0.x, ax); ay = fmaf(w0, f0.y, ay);
                ax = fmaf(w1, f1.x, ax); ay = fmaf(w1, f1.y, ay);
            }
            if (k < deg){
                float w0 = __shfl(wreg, k);
                u32 u0 = *(const u16*)(m + (size_t)(s + k)*HD + 2*lane);
                f32x2 f0 = hw_f8_dec2(u0);
                ax = fmaf(w0, f0.x, ax); ay = fmaf(w0, f0.y, ay);
            }
        } else if (deg > 64){
            float mx = -1e38f;
            for (int k = lane; k < deg; k += 64) mx = fmaxf(mx, alpha[s + k]);
            mx = wave_max(mx);
            float ssum = 0.f;
            for (int k = lane; k < deg; k += 64) ssum += __expf(alpha[s + k] - mx);
            ssum = wave_sum(ssum);
            float inv = 1.f / ssum;
            for (int k = 0; k < deg; ++k){
                float wgt = __expf(alpha[s + k] - mx) * inv;
                u32 u0 = *(const u16*)(m + (size_t)(s + k)*HD + 2*lane);
                f32x2 f0 = hw_f8_dec2(u0);
                ax = fmaf(wgt, f0.x, ax);
                ay = fmaf(wgt, f0.y, ay);
            }
        }
        *(u32*)(sA + nloc*272 + lane*4) = pk2(ax, ay);
    }
    __syncthreads();

    // ---- phase 2: W2 @ sA + bias, elu, -> sO ----
    f32x4 acc[4];
    #pragma unroll
    for (int rf = 0; rf < 4; ++rf) acc[rf] = (f32x4)0.f;
    #pragma unroll
    for (int kf = 0; kf < 4; ++kf){
        s16x8 av[4];
        #pragma unroll
        for (int rf = 0; rf < 4; ++rf)
            av[rf] = *(const s16x8*)(sA + (rf*16 + l15)*272 + kf*64 + l4*16);
        #pragma unroll
        for (int rf = 0; rf < 4; ++rf)
            acc[rf] = MFMA16(av[rf], bfr[kf], acc[rf]);
    }
    float b0 = bc[w*16 + l15];
    #pragma unroll
    for (int rf = 0; rf < 4; ++rf)
        #pragma unroll
        for (int r = 0; r < 4; ++r){
            int row = rf*16 + l4*4 + r;
            *(u16*)(sO + row*272 + (w*16 + l15)*2) = f32_to_bf16(eluf_(acc[rf][r] + b0));
        }
    __syncthreads();

    // ---- write Agru h-half fp8 (8 threads/row, 16 cols each) ----
    {
        int el = t >> 3, q = t & 7;
        size_t n = (size_t)tile*64 + el;
        uint4 v0 = *(const uint4*)(sO + el*272 + q*32);
        uint4 v1 = *(const uint4*)(sO + el*272 + q*32 + 16);
        uint4 p;
        p.x = hw_f8x4(bf16lo(v0.x), bf16hi(v0.x), bf16lo(v0.y), bf16hi(v0.y));
        p.y = hw_f8x4(bf16lo(v0.z), bf16hi(v0.z), bf16lo(v0.w), bf16hi(v0.w));
        p.z = hw_f8x4(bf16lo(v1.x), bf16hi(v1.x), bf16lo(v1.y), bf16hi(v1.y));
        p.w = hw_f8x4(bf16lo(v1.z), bf16hi(v1.z), bf16lo(v1.w), bf16hi(v1.w));
        *(uint4*)(Agru + n*256 + q*16) = p;            // h half (K<128)
    }
}

// ---------------- K5b (fp8 MFMA): GRU cell + fused LayerNorm -> out ----------------
__global__ __launch_bounds__(512, 4) void k_gru_mfma(
    const u8* __restrict__ Agru, const u16* __restrict__ xeb, const u8* __restrict__ Bgf8,
    const float* __restrict__ bih, const float* __restrict__ bhh,
    float* __restrict__ out, int N, int ntiles)
{
    __shared__ __align__(16) u8 sA[32*272];
    __shared__ __align__(16) u8 sX[32*272];
    __shared__ __align__(16) float sOut[32*132];
    int t = threadIdx.x, w = t >> 6, lane = t & 63, l15 = lane & 15, l4 = lane >> 4;

    i64_ bfr0[8], bfr1[8], bfr2[4], bfr3[4];
    {
        int jc = w*16 + l15;
        #pragma unroll
        for (int kf = 0; kf < 8; ++kf){
            bfr0[kf] = *(const i64_*)(Bgf8 + (size_t)(jc)*256       + kf*32 + l4*8);
            bfr1[kf] = *(const i64_*)(Bgf8 + (size_t)(128 + jc)*256 + kf*32 + l4*8);
        }
        #pragma unroll
        for (int kf = 0; kf < 4; ++kf){
            bfr2[kf] = *(const i64_*)(Bgf8 + (size_t)(256 + jc)*256 + kf*32 + l4*8);
            bfr3[kf] = *(const i64_*)(Bgf8 + (size_t)(384 + jc)*256 + (kf+4)*32 + l4*8);
        }
    }
    int j = w*16 + l15;
    float rb = bih[j] + bhh[j];
    float zb = bih[128 + j] + bhh[128 + j];
    float ib = bih[256 + j];
    float hb = bhh[256 + j];

    int el = t >> 4, part = t & 15;
    int stride = gridDim.x;
    int tile = blockIdx.x;
    uint4 pa, px;
    if (tile < ntiles){
        pa = *((const uint4*)Agru + ((size_t)tile*32 + el)*16 + part);
        px = *((const uint4*)xeb  + ((size_t)tile*32 + el)*16 + part);
    }

    for (; tile < ntiles; tile += stride){
        *(uint4*)(sA + el*272 + part*16) = pa;
        *(uint4*)(sX + el*272 + part*16) = px;
        __syncthreads();

        int nt = tile + stride;
        if (nt < ntiles){
            pa = *((const uint4*)Agru + ((size_t)nt*32 + el)*16 + part);
            px = *((const uint4*)xeb  + ((size_t)nt*32 + el)*16 + part);
        }

        f32x4 acc[2][4];
        #pragma unroll
        for (int rf = 0; rf < 2; ++rf)
            #pragma unroll
            for (int g = 0; g < 4; ++g) acc[rf][g] = (f32x4)0.f;
        #pragma unroll
        for (int kf = 0; kf < 8; ++kf){
            i64_ a0 = *(const i64_*)(sA + l15*272 + kf*32 + l4*8);
            i64_ a1 = *(const i64_*)(sA + (16 + l15)*272 + kf*32 + l4*8);
            acc[0][0] = MFMAF8(a0, bfr0[kf], acc[0][0]);
            acc[1][0] = MFMAF8(a1, bfr0[kf], acc[1][0]);
            acc[0][1] = MFMAF8(a0, bfr1[kf], acc[0][1]);
            acc[1][1] = MFMAF8(a1, bfr1[kf], acc[1][1]);
            if (kf < 4){
                acc[0][2] = MFMAF8(a0, bfr2[kf], acc[0][2]);
                acc[1][2] = MFMAF8(a1, bfr2[kf], acc[1][2]);
            } else {
                acc[0][3] = MFMAF8(a0, bfr3[kf-4], acc[0][3]);
                acc[1][3] = MFMAF8(a1, bfr3[kf-4], acc[1][3]);
            }
        }
        #pragma unroll
        for (int rf = 0; rf < 2; ++rf)
            #pragma unroll
            for (int r = 0; r < 4; ++r){
                int rl = rf*16 + l4*4 + r;
                float rr = sigmoidf_(acc[rf][0][r] + rb);
                float zz = sigmoidf_(acc[rf][1][r] + zb);
                float iv = acc[rf][2][r] + ib;
                float hv = acc[rf][3][r] + hb;
                float nc = tanhf_(iv + rr*hv);
                float xej = bf16f(*(const u16*)(sX + rl*272 + 2*j));
                float v = (1.f - zz)*nc + zz*xej;
                v = fmaxf(v, 0.f);
                sOut[rl*132 + j] = v;
            }
        __syncthreads();
        {
            int row = t >> 4, sub = t & 15;
            const float* rp = sOut + row*132 + sub*8;
            float v0 = rp[0], v1 = rp[1], v2 = rp[2], v3 = rp[3];
            float v4 = rp[4], v5 = rp[5], v6 = rp[6], v7 = rp[7];
            float s1 = v0+v1+v2+v3+v4+v5+v6+v7;
            float s2 = v0*v0+v1*v1+v2*v2+v3*v3+v4*v4+v5*v5+v6*v6+v7*v7;
            #pragma unroll
            for (int o = 1; o < 16; o <<= 1){ s1 += __shfl_xor(s1, o); s2 += __shfl_xor(s2, o); }
            float mu  = s1 * (1.f/128.f);
            float var = s2 * (1.f/128.f) - mu*mu;
            var = fmaxf(var, 0.f);
            float rsd = rsqrtf(var + 1e-5f);
            float* op = out + ((size_t)tile*32 + row)*128 + sub*8;
            float4 o0, o1;
            o0.x = (v0-mu)*rsd; o0.y = (v1-mu)*rsd; o0.z = (v2-mu)*rsd; o0.w = (v3-mu)*rsd;
            o1.x = (v4-mu)*rsd; o1.y = (v5-mu)*rsd; o1.z = (v6-mu)*rsd; o1.w = (v7-mu)*rsd;
            ((float4*)op)[0] = o0; ((float4*)op)[1] = o1;
        }
        __syncthreads();
    }
}

// ---------------- host ----------------
extern "C" void kernel_launch(void* const* d_in, const int* in_sizes, int n_in,
                              void* d_out, int out_size, void* d_ws, size_t ws_size,
                              hipStream_t stream)
{
    const float* x       = (const float*)d_in[0];
    const float* ea      = (const float*)d_in[1];
    const float* W_enter = (const float*)d_in[2];
    const float* b_enter = (const float*)d_in[3];
    const float* W1      = (const float*)d_in[4];
    const float* att_l   = (const float*)d_in[5];
    const float* att_r   = (const float*)d_in[6];
    const float* W2      = (const float*)d_in[7];
    const float* b_conv  = (const float*)d_in[8];
    const float* W_ih    = (const float*)d_in[9];
    const float* W_hh    = (const float*)d_in[10];
    const float* b_ih    = (const float*)d_in[11];
    const float* b_hh    = (const float*)d_in[12];
    const int*   eidx    = (const int*)d_in[13];

    int N = in_sizes[0] / DIN;
    int E = in_sizes[13] / 2;
    const int* src = eidx;
    const int* dst = eidx + E;
    float* out = (float*)d_out;

    size_t off = 0;
    char* base = (char*)d_ws;
    auto alloc = [&](size_t bytes) -> char* {
        char* p = base + off;
        off = (off + bytes + 255) & ~(size_t)255;
        return p;
    };
    u16*   xeb   = (u16*)  alloc((size_t)N*HD*2);
    u8*    Agru  = (u8*)   alloc((size_t)N*256);
    float* r_dst = (float*)alloc((size_t)N*4);
    float* alpha = (float*)alloc((size_t)E*4);
    int*   deg   = (int*)  alloc((size_t)N*4);
    int*   rs    = (int*)  alloc((size_t)(N+1)*4);
    int*   cnt   = (int*)  alloc((size_t)N*4);
    int*   epos  = (int*)  alloc((size_t)E*4);
    int*   btot  = (int*)  alloc(1024);
    int*   bbase = (int*)  alloc(1024);
    u16*   W1b   = (u16*)  alloc(20480*2);
    u16*   W2b   = (u16*)  alloc(16384*2);
    u16*   Wentb = (u16*)  alloc(8192*2);
    u8*    Bgf8  = (u8*)   alloc(131072);
    u8*    mbuf  = (u8*)   alloc((size_t)E*HD);

    int ntiles_n64 = N/64, ntiles_e = (E + 63)/64, ntiles_g = N/32;

    k_prep   <<<(176128+255)/256, 256, 0, stream>>>(W1, W2, W_enter, W_ih, W_hh, W1b, W2b, Wentb, Bgf8);
    hipMemsetAsync(deg, 0, (size_t)N*4, stream);
    hipMemsetAsync(cnt, 0, (size_t)N*4, stream);
    k_enter_mfma<<<ntiles_n64, 256, 0, stream>>>(x, Wentb, b_enter, att_r, xeb, Agru, r_dst, N);
    k_hist   <<<(E+255)/256, 256, 0, stream>>>(dst, deg, E);
    k_scan_a <<<N/1024, 256, 0, stream>>>(deg, rs, btot, N);
    k_scan_b <<<1, 256, 0, stream>>>(btot, bbase);
    k_scan_c <<<(N+255)/256, 256, 0, stream>>>(rs, bbase, N, E);
    k_scatter<<<(E+255)/256, 256, 0, stream>>>(dst, rs, cnt, epos, E);
    k_edge_mfma<<<1024, 512, 0, stream>>>(xeb, ea, W1b, att_l, r_dst, src, dst, epos,
                                          mbuf, alpha, ntiles_e, E);
    k_aggconv<<<ntiles_n64, 512, 0, stream>>>(rs, alpha, mbuf, W2b, b_conv, Agru, N);
    k_gru_mfma  <<<2048, 512, 0, stream>>>(Agru, xeb, Bgf8, b_ih, b_hh, out, N, ntiles_g);
}